// Round 6
// baseline (473.098 us; speedup 1.0000x reference)
//
#include <hip/hip_runtime.h>

#define BB 16
#define TT 1024
#define DD 512
#define VV 256
#define MM (BB*TT)

#define DPINF 1e30f

// DPP min-reduce step; old = same reg -> identity for lanes with no source
#define DPP_MIN_STEP(m, CTRL) { \
  int _t = __builtin_amdgcn_update_dpp(__float_as_int(m), __float_as_int(m), CTRL, 0xF, 0xF, false); \
  m = fminf(m, __int_as_float(_t)); }

// full 64-lane min into lane 63: row_shr 1,2,4,8 then row_bcast15, row_bcast31
#define DPP_MIN_REDUCE(m) \
  DPP_MIN_STEP(m, 0x111); DPP_MIN_STEP(m, 0x112); DPP_MIN_STEP(m, 0x114); \
  DPP_MIN_STEP(m, 0x118); DPP_MIN_STEP(m, 0x142); DPP_MIN_STEP(m, 0x143);

// ---------------------------------------------------------------------------
// Kernel 1: row norms of reps (r2[16384]) and codebook (c2[256]); 1 wave/row
// ---------------------------------------------------------------------------
__global__ __launch_bounds__(256) void norms_k(const float* __restrict__ reps,
                                               const float* __restrict__ cb,
                                               float* __restrict__ r2,
                                               float* __restrict__ c2) {
  int row = blockIdx.x * 4 + (threadIdx.x >> 6);
  int lane = threadIdx.x & 63;
  const float* src;
  float* dst;
  if (row < MM) {
    src = reps + (size_t)row * DD;
    dst = r2 + row;
  } else {
    int r = row - MM;
    if (r >= VV) return;
    src = cb + (size_t)r * DD;
    dst = c2 + r;
  }
  const float4* s4 = (const float4*)src;
  float4 a = s4[lane];
  float4 b = s4[lane + 64];
  float s = a.x*a.x + a.y*a.y + a.z*a.z + a.w*a.w
          + b.x*b.x + b.y*b.y + b.z*b.z + b.w*b.w;
#pragma unroll
  for (int off = 1; off < 64; off <<= 1) s += __shfl_xor(s, off);
  if (lane == 0) *dst = s;
}

// ---------------------------------------------------------------------------
// Kernel 2: d[m][v] = r2[m] - 2*dot(reps[m], cb[v]) + c2[v]
// fp32 tiled GEMM: 64x64 tile, BK=32, 256 threads, 4x4 micro-tile
// ---------------------------------------------------------------------------
__global__ __launch_bounds__(256) void gemm_k(const float* __restrict__ reps,
                                              const float* __restrict__ cb,
                                              const float* __restrict__ r2,
                                              const float* __restrict__ c2,
                                              float* __restrict__ dmat) {
  __shared__ __align__(16) float As[32][68];
  __shared__ __align__(16) float Bs[32][68];
  int tid = threadIdx.x;
  int m0 = blockIdx.y * 64, n0 = blockIdx.x * 64;
  int tx = tid & 15, ty = tid >> 4;
  int lrow = tid >> 3, lcol = tid & 7;
  float acc[4][4] = {{0.f}};
  const float* arow0 = reps + (size_t)(m0 + lrow) * DD + lcol * 4;
  const float* arow1 = arow0 + (size_t)32 * DD;
  const float* brow0 = cb + (size_t)(n0 + lrow) * DD + lcol * 4;
  const float* brow1 = brow0 + (size_t)32 * DD;

  for (int k0 = 0; k0 < DD; k0 += 32) {
    float4 a0 = *(const float4*)(arow0 + k0);
    float4 a1 = *(const float4*)(arow1 + k0);
    float4 b0 = *(const float4*)(brow0 + k0);
    float4 b1 = *(const float4*)(brow1 + k0);
    __syncthreads();
    int kc = lcol * 4;
    As[kc+0][lrow] = a0.x; As[kc+1][lrow] = a0.y; As[kc+2][lrow] = a0.z; As[kc+3][lrow] = a0.w;
    As[kc+0][lrow+32] = a1.x; As[kc+1][lrow+32] = a1.y; As[kc+2][lrow+32] = a1.z; As[kc+3][lrow+32] = a1.w;
    Bs[kc+0][lrow] = b0.x; Bs[kc+1][lrow] = b0.y; Bs[kc+2][lrow] = b0.z; Bs[kc+3][lrow] = b0.w;
    Bs[kc+0][lrow+32] = b1.x; Bs[kc+1][lrow+32] = b1.y; Bs[kc+2][lrow+32] = b1.z; Bs[kc+3][lrow+32] = b1.w;
    __syncthreads();
#pragma unroll
    for (int kk = 0; kk < 32; ++kk) {
      float4 av = *(const float4*)&As[kk][ty * 4];
      float4 bv = *(const float4*)&Bs[kk][tx * 4];
      float aa[4] = {av.x, av.y, av.z, av.w};
      float bb[4] = {bv.x, bv.y, bv.z, bv.w};
#pragma unroll
      for (int i = 0; i < 4; ++i)
#pragma unroll
        for (int j = 0; j < 4; ++j)
          acc[i][j] += aa[i] * bb[j];
    }
  }

  int gm = m0 + ty * 4, gn = n0 + tx * 4;
  float cc[4] = {c2[gn], c2[gn+1], c2[gn+2], c2[gn+3]};
#pragma unroll
  for (int i = 0; i < 4; ++i) {
    float rv = r2[gm + i];
    float4 o;
    o.x = fmaf(-2.f, acc[i][0], rv + cc[0]);
    o.y = fmaf(-2.f, acc[i][1], rv + cc[1]);
    o.z = fmaf(-2.f, acc[i][2], rv + cc[2]);
    o.w = fmaf(-2.f, acc[i][3], rv + cc[3]);
    *(float4*)&dmat[(size_t)(gm + i) * VV + gn] = o;
  }
}

// ---------------------------------------------------------------------------
// Kernel 3: W[t][i] = min_v sum_{f=s+1..t} d[f][v], s = t-64+i.
// One block per (batch, 64-t chunk, v-half-of-128). Grid 512.
// Phase 1: parallel window cumsum build (reg chunks + LDS prefix).
// Phase 2: lane-private v-scan.
// Phase 3: diagonal restage WT[s][j] = W[s+1+j][i=63-j] (float2 slot [half])
//   feeding dp_seq's scatter-form recurrence with coalesced row loads.
//   Wv2/WI2 (per-t layout) kept for prev_k.
// ---------------------------------------------------------------------------
__global__ __launch_bounds__(256) void w_k(const float* __restrict__ dmat,
                                           float* __restrict__ Wv2,
                                           unsigned char* __restrict__ WI2,
                                           float2* __restrict__ WT2) {
  __shared__ __align__(16) float CL[128 * 128];
  __shared__ __align__(16) float TOT[8 * 128];
  int bx = blockIdx.x;
  int b = bx >> 5;
  int chunk = (bx >> 1) & 15;
  int half = bx & 1;
  int t1 = 1 + (chunk << 6);             // block covers t in [t1, t1+63]
  int tid = threadIdx.x;
  int wv = tid >> 6, lane = tid & 63;

  // ---- Phase 1: parallel cumsum build ----
  {
    int c = tid >> 5;          // 16-frame chunk 0..7
    int g = tid & 31;          // float4 group within half
    const float* base = dmat + (size_t)b * TT * VV + (half << 7) + (g << 2);
    float4 rr[16];
    float4 run = make_float4(0.f, 0.f, 0.f, 0.f);
#pragma unroll
    for (int j = 1; j <= 16; ++j) {
      int k = (c << 4) + j;
      int f = t1 - 64 + k;                 // frame for cumsum row k
      bool valid = (k <= 127) && (f >= 1) && (f <= TT);
      int fc = valid ? f : 1;
      float4 dv = *(const float4*)(base + (size_t)(fc - 1) * VV);
      if (!valid) dv = make_float4(0.f, 0.f, 0.f, 0.f);
      run.x += dv.x; run.y += dv.y; run.z += dv.z; run.w += dv.w;
      rr[j - 1] = run;
    }
    *(float4*)&TOT[c * 128 + (g << 2)] = run;
    if (c == 0) *(float4*)&CL[0 * 128 + (g << 2)] = make_float4(0.f, 0.f, 0.f, 0.f);
    __syncthreads();
    float4 off = make_float4(0.f, 0.f, 0.f, 0.f);
#pragma unroll
    for (int cc = 0; cc < 7; ++cc) {
      if (cc < c) {
        float4 tv = *(const float4*)&TOT[cc * 128 + (g << 2)];
        off.x += tv.x; off.y += tv.y; off.z += tv.z; off.w += tv.w;
      }
    }
#pragma unroll
    for (int j = 1; j <= 16; ++j) {
      int k = (c << 4) + j;
      if (k <= 127) {
        float4 s = rr[j - 1];
        s.x += off.x; s.y += off.y; s.z += off.z; s.w += off.w;
        *(float4*)&CL[k * 128 + ((g ^ (k & 31)) << 2)] = s;
      }
    }
  }
  __syncthreads();

  // ---- Phase 2: lane-private scan over this half's 128 v ----
  float bw[16];
  int ba[16];
#pragma unroll
  for (int j = 0; j < 16; ++j) { bw[j] = 1e38f; ba[j] = 0; }

#pragma unroll
  for (int j = 0; j < 16; ++j) {
    int dt = (j << 2) + wv;           // 0..63
    int ks = dt + lane;               // row of C_s (s = t-64+lane)
    int kt = dt + 64;                 // row of C_t
    const float* rs = &CL[ks * 128];
    const float* rt = &CL[kt * 128];
    int ksm = ks & 31, ktm = kt & 31;
    float bv = bw[j];
    int bi = ba[j];
#pragma unroll 4
    for (int g = 0; g < 32; ++g) {
      float4 a = *(const float4*)&rs[(g ^ ksm) << 2];
      float4 t4 = *(const float4*)&rt[(g ^ ktm) << 2];
      int v0 = (g << 2);
      float s0 = t4.x - a.x; if (s0 < bv) { bv = s0; bi = v0; }
      float s1 = t4.y - a.y; if (s1 < bv) { bv = s1; bi = v0 + 1; }
      float s2 = t4.z - a.z; if (s2 < bv) { bv = s2; bi = v0 + 2; }
      float s3 = t4.w - a.w; if (s3 < bv) { bv = s3; bi = v0 + 3; }
    }
    bw[j] = bv; ba[j] = bi;
  }

  // per-t layout for prev_k
#pragma unroll
  for (int j = 0; j < 16; ++j) {
    int t = t1 + (j << 2) + wv;
    size_t idx = (((size_t)b * TT + (t - 1)) * 64 + lane) * 2 + half;
    Wv2[idx] = bw[j];
    WI2[idx] = (unsigned char)ba[j];   // v within half; half1 adds 128 at use
  }

  // ---- Phase 3: diagonal restage (reuse CL as ST[127][66]) ----
  __syncthreads();                     // all CL reads of phase 2 done
  float* ST = CL;
#pragma unroll
  for (int j = 0; j < 16; ++j) {
    int t_local = (j << 2) + wv;
    int srow = t_local + lane;         // 0..126 ; s = t1-64+srow
    ST[srow * 66 + (63 - lane)] = bw[j];
  }
  __syncthreads();
  {
    float* WTf = (float*)WT2;
    for (int q = 0; q < 32; ++q) {
      int rr = wv * 32 + q;
      if (rr > 126) break;             // row 127 doesn't exist
      int s = t1 - 64 + rr;
      if (s < 0) continue;
      int jlo = 63 - rr; if (jlo < 0) jlo = 0;
      int jhi = 126 - rr; if (jhi > 63) jhi = 63;
      int j = lane;
      if (j >= jlo && j <= jhi)
        WTf[(((size_t)b * TT + s) * 64 + j) * 2 + half] = ST[rr * 66 + j];
    }
  }
}

// ---------------------------------------------------------------------------
// Kernel 4a: sequential DP, scatter form, PINNED prefetch. One wave/batch.
// Lane j accumulates acc = min(acc, costs[tau] + WT[tau][(j - tau) & 63]);
// at step tau, lane (tau & 63) finalizes costs[tau+1] (readlane broadcast).
// Critical chain: readlane -> v_add -> v_min. The asm memory clobbers after
// each bank refill make load-sinking illegal, so the 16 refill loads issue
// 48 steps before consumption and their values stay in VGPRs (round-5
// post-mortem: VGPR=40 proved LLVM sank all loads to use, 656 cyc/step).
// ---------------------------------------------------------------------------
__global__ __launch_bounds__(64) void dp_seq(const float* __restrict__ WT,
                                             float* __restrict__ cg) {
  int b = blockIdx.x;
  int lane = threadIdx.x;
  const float2* Wb = (const float2*)WT + (size_t)b * TT * 64;
  float* cgb = cg + (size_t)b * (TT + 1);
  if (lane == 0) cgb[0] = 0.f;

  auto ldrow = [&](int row) -> float {
    int r = (row < TT) ? row : (TT - 1);   // clamped rows are never consumed
    float2 w2 = Wb[(size_t)r * 64 + ((lane - r) & 63)];
    return fminf(w2.x, w2.y);
  };

  float bank0[16], bank1[16], bank2[16], bank3[16];
#pragma unroll
  for (int m = 0; m < 16; ++m) bank0[m] = ldrow(m);
#pragma unroll
  for (int m = 0; m < 16; ++m) bank1[m] = ldrow(16 + m);
#pragma unroll
  for (int m = 0; m < 16; ++m) bank2[m] = ldrow(32 + m);
#pragma unroll
  for (int m = 0; m < 16; ++m) bank3[m] = ldrow(48 + m);
  asm volatile("" ::: "memory");   // pin prologue loads here

  float c = 0.f;            // costs[tau], uniform across lanes
  float acc = DPINF;        // lane's running min for its pending t
  float ckeep = 0.f;        // lane l holds costs[.] for the periodic store

#define STEP(TAU, W) { \
    float cand = c + (W); \
    acc = fminf(acc, cand); \
    int fl = (TAU) & 63; \
    float cnew = __int_as_float(__builtin_amdgcn_readlane(__float_as_int(acc), fl)); \
    bool me = (lane == fl); \
    ckeep = me ? cnew : ckeep; \
    acc = me ? DPINF : acc; \
    c = cnew; }

#define CHUNK(BK, G) { \
    _Pragma("unroll") \
    for (int m = 0; m < 16; ++m) STEP((G) * 16 + m, BK[m]); \
    _Pragma("unroll") \
    for (int m = 0; m < 16; ++m) BK[m] = ldrow(((G) + 4) * 16 + m); \
    asm volatile("" ::: "memory"); }

  for (int gg = 0; gg < 16; ++gg) {
    int g0 = gg * 4;
    CHUNK(bank0, g0);
    CHUNK(bank1, g0 + 1);
    CHUNK(bank2, g0 + 2);
    CHUNK(bank3, g0 + 3);
    cgb[gg * 64 + 1 + lane] = ckeep;   // costs[gg*64+1 .. gg*64+64]
  }
#undef STEP
#undef CHUNK
}

// ---------------------------------------------------------------------------
// Kernel 4b: parallel argmin. One wave per t: recompute total = cg[s]+W[t][i]
// (bit-identical to dp_seq's sums), find first-min -> prev, tok.
// Half-combine: value = min, token = half0 on tie (lowest v wins).
// ---------------------------------------------------------------------------
__global__ __launch_bounds__(256) void prev_k(const float* __restrict__ Wv2,
                                              const unsigned char* __restrict__ WI2,
                                              const float* __restrict__ cg,
                                              int* __restrict__ pk) {
  int row = blockIdx.x * 4 + (threadIdx.x >> 6);   // row in [0, BB*TT)
  int lane = threadIdx.x & 63;
  int b = row >> 10;
  int t = (row & 1023) + 1;
  int s = t - 64 + lane;
  size_t idx = (size_t)row * 64 + lane;
  float2 w2 = ((const float2*)Wv2)[idx];
  uchar2 i2 = ((const uchar2*)WI2)[idx];
  bool h0 = (w2.x <= w2.y);
  float w = h0 ? w2.x : w2.y;
  int wi = h0 ? (int)i2.x : ((int)i2.y + 128);
  int sc = (s < 0) ? 0 : s;
  float c = cg[(size_t)b * (TT + 1) + sc];
  float total = (s >= 0) ? (c + w) : DPINF;
  float m = total;
  DPP_MIN_REDUCE(m);
  float mf = __int_as_float(__builtin_amdgcn_readlane(__float_as_int(m), 63));
  unsigned long long msk = __ballot(total == mf);
  int iwin = __builtin_ctzll(msk);                 // smallest i = smallest s (ref tie-break)
  int tok = __builtin_amdgcn_readlane(wi, iwin) & 255;
  int prev = t - 64 + iwin;
  if (lane == 0) pk[(size_t)b * (TT + 1) + t] = (prev << 8) | tok;
}

// ---------------------------------------------------------------------------
// Kernel 4c: backtrack + outputs. One wave per batch; packed prev/tok walk
// in LDS; float32-encoded outputs (harness reads whole d_out as float32).
// ---------------------------------------------------------------------------
__global__ __launch_bounds__(64) void bt_k(const int* __restrict__ pk,
                                           const float* __restrict__ cg,
                                           const int* __restrict__ lengths,
                                           float* __restrict__ out) {
  int b = blockIdx.x;
  int lane = threadIdx.x;
  __shared__ int pks[TT + 1];
  __shared__ int bs[TT];
  __shared__ int ts[TT];

  const int* pb = pk + (size_t)b * (TT + 1);
  for (int k = lane; k <= TT; k += 64) pks[k] = pb[k];
  __syncthreads();

  int len = lengths[b];
  len = (len > TT) ? TT : (len < 0 ? 0 : len);
  int cnt = 0;
  if (lane == 0) {
    int st = len;
    while (st > 0 && cnt < TT) {
      int e = pks[st];
      bs[cnt] = st;
      ts[cnt] = e & 255;
      st = e >> 8;            // prev < st, strictly decreasing
      ++cnt;
    }
  }
  cnt = __shfl(cnt, 0);
  __syncthreads();

  float* bout = out + b * TT;
  float* tout = out + MM + b * TT;
  for (int k = lane; k < TT; k += 64) {
    bout[k] = (k < cnt) ? (float)bs[cnt - 1 - k] : 0.f;
    tout[k] = (k < cnt) ? (float)ts[cnt - 1 - k] : 0.f;
  }
  if (lane == 0) {
    out[2 * MM + b] = (float)cnt;                          // counts
    out[2 * MM + BB + b] = cg[(size_t)b * (TT + 1) + len]; // final cost
  }
}

// ---------------------------------------------------------------------------
extern "C" void kernel_launch(void* const* d_in, const int* in_sizes, int n_in,
                              void* d_out, int out_size, void* d_ws, size_t ws_size,
                              hipStream_t stream) {
  const float* reps = (const float*)d_in[0];
  const float* cb   = (const float*)d_in[1];
  const int* lengths = (const int*)d_in[2];
  float* out = (float*)d_out;

  char* ws = (char*)d_ws;
  float* r2 = (float*)ws;                                    // 64 KB
  float* c2 = (float*)(ws + 65536);                          // 4 KB slot
  char* p = ws + 69632;
  float* dmat = (float*)p;               p += (size_t)MM * VV * 4;       // 16 MB
  float* Wv2  = (float*)p;               p += (size_t)MM * 128 * 4;      // 8 MB
  unsigned char* WI2 = (unsigned char*)p; p += (size_t)MM * 128;         // 2 MB
  float2* WT2 = (float2*)p;              p += (size_t)MM * 64 * 8;       // 8 MB
  float* cg   = (float*)p;               p += (size_t)BB * (TT + 1) * 4; // 65.6 KB
  int* pk     = (int*)p;                                                 // 65.6 KB

  norms_k<<<(MM + VV) / 4, 256, 0, stream>>>(reps, cb, r2, c2);
  gemm_k<<<dim3(VV / 64, MM / 64), 256, 0, stream>>>(reps, cb, r2, c2, dmat);
  w_k<<<BB * (TT / 64) * 2, 256, 0, stream>>>(dmat, Wv2, WI2, WT2);
  dp_seq<<<BB, 64, 0, stream>>>((const float*)WT2, cg);
  prev_k<<<MM / 4, 256, 0, stream>>>(Wv2, WI2, cg, pk);
  bt_k<<<BB, 64, 0, stream>>>(pk, cg, lengths, out);
}

// Round 7
// 247.135 us; speedup vs baseline: 1.9143x; 1.9143x over previous
//
#include <hip/hip_runtime.h>

#define BB 16
#define TT 1024
#define DD 512
#define VV 256
#define MM (BB*TT)

#define DPINF 1e30f

// DPP min-reduce step; old = same reg -> identity for lanes with no source
#define DPP_MIN_STEP(m, CTRL) { \
  int _t = __builtin_amdgcn_update_dpp(__float_as_int(m), __float_as_int(m), CTRL, 0xF, 0xF, false); \
  m = fminf(m, __int_as_float(_t)); }

// full 64-lane min into lane 63: row_shr 1,2,4,8 then row_bcast15, row_bcast31
#define DPP_MIN_REDUCE(m) \
  DPP_MIN_STEP(m, 0x111); DPP_MIN_STEP(m, 0x112); DPP_MIN_STEP(m, 0x114); \
  DPP_MIN_STEP(m, 0x118); DPP_MIN_STEP(m, 0x142); DPP_MIN_STEP(m, 0x143);

// ---------------------------------------------------------------------------
// Kernel 1: row norms of reps (r2[16384]) and codebook (c2[256]); 1 wave/row
// ---------------------------------------------------------------------------
__global__ __launch_bounds__(256) void norms_k(const float* __restrict__ reps,
                                               const float* __restrict__ cb,
                                               float* __restrict__ r2,
                                               float* __restrict__ c2) {
  int row = blockIdx.x * 4 + (threadIdx.x >> 6);
  int lane = threadIdx.x & 63;
  const float* src;
  float* dst;
  if (row < MM) {
    src = reps + (size_t)row * DD;
    dst = r2 + row;
  } else {
    int r = row - MM;
    if (r >= VV) return;
    src = cb + (size_t)r * DD;
    dst = c2 + r;
  }
  const float4* s4 = (const float4*)src;
  float4 a = s4[lane];
  float4 b = s4[lane + 64];
  float s = a.x*a.x + a.y*a.y + a.z*a.z + a.w*a.w
          + b.x*b.x + b.y*b.y + b.z*b.z + b.w*b.w;
#pragma unroll
  for (int off = 1; off < 64; off <<= 1) s += __shfl_xor(s, off);
  if (lane == 0) *dst = s;
}

// ---------------------------------------------------------------------------
// Kernel 2: d[m][v] = r2[m] - 2*dot(reps[m], cb[v]) + c2[v]
// fp32 tiled GEMM: 64x64 tile, BK=32, 256 threads, 4x4 micro-tile
// ---------------------------------------------------------------------------
__global__ __launch_bounds__(256) void gemm_k(const float* __restrict__ reps,
                                              const float* __restrict__ cb,
                                              const float* __restrict__ r2,
                                              const float* __restrict__ c2,
                                              float* __restrict__ dmat) {
  __shared__ __align__(16) float As[32][68];
  __shared__ __align__(16) float Bs[32][68];
  int tid = threadIdx.x;
  int m0 = blockIdx.y * 64, n0 = blockIdx.x * 64;
  int tx = tid & 15, ty = tid >> 4;
  int lrow = tid >> 3, lcol = tid & 7;
  float acc[4][4] = {{0.f}};
  const float* arow0 = reps + (size_t)(m0 + lrow) * DD + lcol * 4;
  const float* arow1 = arow0 + (size_t)32 * DD;
  const float* brow0 = cb + (size_t)(n0 + lrow) * DD + lcol * 4;
  const float* brow1 = brow0 + (size_t)32 * DD;

  for (int k0 = 0; k0 < DD; k0 += 32) {
    float4 a0 = *(const float4*)(arow0 + k0);
    float4 a1 = *(const float4*)(arow1 + k0);
    float4 b0 = *(const float4*)(brow0 + k0);
    float4 b1 = *(const float4*)(brow1 + k0);
    __syncthreads();
    int kc = lcol * 4;
    As[kc+0][lrow] = a0.x; As[kc+1][lrow] = a0.y; As[kc+2][lrow] = a0.z; As[kc+3][lrow] = a0.w;
    As[kc+0][lrow+32] = a1.x; As[kc+1][lrow+32] = a1.y; As[kc+2][lrow+32] = a1.z; As[kc+3][lrow+32] = a1.w;
    Bs[kc+0][lrow] = b0.x; Bs[kc+1][lrow] = b0.y; Bs[kc+2][lrow] = b0.z; Bs[kc+3][lrow] = b0.w;
    Bs[kc+0][lrow+32] = b1.x; Bs[kc+1][lrow+32] = b1.y; Bs[kc+2][lrow+32] = b1.z; Bs[kc+3][lrow+32] = b1.w;
    __syncthreads();
#pragma unroll
    for (int kk = 0; kk < 32; ++kk) {
      float4 av = *(const float4*)&As[kk][ty * 4];
      float4 bv = *(const float4*)&Bs[kk][tx * 4];
      float aa[4] = {av.x, av.y, av.z, av.w};
      float bb[4] = {bv.x, bv.y, bv.z, bv.w};
#pragma unroll
      for (int i = 0; i < 4; ++i)
#pragma unroll
        for (int j = 0; j < 4; ++j)
          acc[i][j] += aa[i] * bb[j];
    }
  }

  int gm = m0 + ty * 4, gn = n0 + tx * 4;
  float cc[4] = {c2[gn], c2[gn+1], c2[gn+2], c2[gn+3]};
#pragma unroll
  for (int i = 0; i < 4; ++i) {
    float rv = r2[gm + i];
    float4 o;
    o.x = fmaf(-2.f, acc[i][0], rv + cc[0]);
    o.y = fmaf(-2.f, acc[i][1], rv + cc[1]);
    o.z = fmaf(-2.f, acc[i][2], rv + cc[2]);
    o.w = fmaf(-2.f, acc[i][3], rv + cc[3]);
    *(float4*)&dmat[(size_t)(gm + i) * VV + gn] = o;
  }
}

// ---------------------------------------------------------------------------
// Kernel 3: W[t][i] = min_v sum_{f=s+1..t} d[f][v], s = t-64+i.
// One block per (batch, 64-t chunk, v-half-of-128). Grid 512.
// Phase 1: parallel window cumsum build (reg chunks + LDS prefix).
// Phase 2: lane-private v-scan.
// Phase 3: diagonal restage WT[s][j] = W[s+1+j][i=63-j] (float2 slot [half])
//   feeding dp_seq's scatter-form recurrence with coalesced row loads.
//   Wv2/WI2 (per-t layout) kept for prev_k.
// ---------------------------------------------------------------------------
__global__ __launch_bounds__(256) void w_k(const float* __restrict__ dmat,
                                           float* __restrict__ Wv2,
                                           unsigned char* __restrict__ WI2,
                                           float2* __restrict__ WT2) {
  __shared__ __align__(16) float CL[128 * 128];
  __shared__ __align__(16) float TOT[8 * 128];
  int bx = blockIdx.x;
  int b = bx >> 5;
  int chunk = (bx >> 1) & 15;
  int half = bx & 1;
  int t1 = 1 + (chunk << 6);             // block covers t in [t1, t1+63]
  int tid = threadIdx.x;
  int wv = tid >> 6, lane = tid & 63;

  // ---- Phase 1: parallel cumsum build ----
  {
    int c = tid >> 5;          // 16-frame chunk 0..7
    int g = tid & 31;          // float4 group within half
    const float* base = dmat + (size_t)b * TT * VV + (half << 7) + (g << 2);
    float4 rr[16];
    float4 run = make_float4(0.f, 0.f, 0.f, 0.f);
#pragma unroll
    for (int j = 1; j <= 16; ++j) {
      int k = (c << 4) + j;
      int f = t1 - 64 + k;                 // frame for cumsum row k
      bool valid = (k <= 127) && (f >= 1) && (f <= TT);
      int fc = valid ? f : 1;
      float4 dv = *(const float4*)(base + (size_t)(fc - 1) * VV);
      if (!valid) dv = make_float4(0.f, 0.f, 0.f, 0.f);
      run.x += dv.x; run.y += dv.y; run.z += dv.z; run.w += dv.w;
      rr[j - 1] = run;
    }
    *(float4*)&TOT[c * 128 + (g << 2)] = run;
    if (c == 0) *(float4*)&CL[0 * 128 + (g << 2)] = make_float4(0.f, 0.f, 0.f, 0.f);
    __syncthreads();
    float4 off = make_float4(0.f, 0.f, 0.f, 0.f);
#pragma unroll
    for (int cc = 0; cc < 7; ++cc) {
      if (cc < c) {
        float4 tv = *(const float4*)&TOT[cc * 128 + (g << 2)];
        off.x += tv.x; off.y += tv.y; off.z += tv.z; off.w += tv.w;
      }
    }
#pragma unroll
    for (int j = 1; j <= 16; ++j) {
      int k = (c << 4) + j;
      if (k <= 127) {
        float4 s = rr[j - 1];
        s.x += off.x; s.y += off.y; s.z += off.z; s.w += off.w;
        *(float4*)&CL[k * 128 + ((g ^ (k & 31)) << 2)] = s;
      }
    }
  }
  __syncthreads();

  // ---- Phase 2: lane-private scan over this half's 128 v ----
  float bw[16];
  int ba[16];
#pragma unroll
  for (int j = 0; j < 16; ++j) { bw[j] = 1e38f; ba[j] = 0; }

#pragma unroll
  for (int j = 0; j < 16; ++j) {
    int dt = (j << 2) + wv;           // 0..63
    int ks = dt + lane;               // row of C_s (s = t-64+lane)
    int kt = dt + 64;                 // row of C_t
    const float* rs = &CL[ks * 128];
    const float* rt = &CL[kt * 128];
    int ksm = ks & 31, ktm = kt & 31;
    float bv = bw[j];
    int bi = ba[j];
#pragma unroll 4
    for (int g = 0; g < 32; ++g) {
      float4 a = *(const float4*)&rs[(g ^ ksm) << 2];
      float4 t4 = *(const float4*)&rt[(g ^ ktm) << 2];
      int v0 = (g << 2);
      float s0 = t4.x - a.x; if (s0 < bv) { bv = s0; bi = v0; }
      float s1 = t4.y - a.y; if (s1 < bv) { bv = s1; bi = v0 + 1; }
      float s2 = t4.z - a.z; if (s2 < bv) { bv = s2; bi = v0 + 2; }
      float s3 = t4.w - a.w; if (s3 < bv) { bv = s3; bi = v0 + 3; }
    }
    bw[j] = bv; ba[j] = bi;
  }

  // per-t layout for prev_k
#pragma unroll
  for (int j = 0; j < 16; ++j) {
    int t = t1 + (j << 2) + wv;
    size_t idx = (((size_t)b * TT + (t - 1)) * 64 + lane) * 2 + half;
    Wv2[idx] = bw[j];
    WI2[idx] = (unsigned char)ba[j];   // v within half; half1 adds 128 at use
  }

  // ---- Phase 3: diagonal restage (reuse CL as ST[127][66]) ----
  __syncthreads();                     // all CL reads of phase 2 done
  float* ST = CL;
#pragma unroll
  for (int j = 0; j < 16; ++j) {
    int t_local = (j << 2) + wv;
    int srow = t_local + lane;         // 0..126 ; s = t1-64+srow
    ST[srow * 66 + (63 - lane)] = bw[j];
  }
  __syncthreads();
  {
    float* WTf = (float*)WT2;
    for (int q = 0; q < 32; ++q) {
      int rr = wv * 32 + q;
      if (rr > 126) break;             // row 127 doesn't exist
      int s = t1 - 64 + rr;
      if (s < 0) continue;
      int jlo = 63 - rr; if (jlo < 0) jlo = 0;
      int jhi = 126 - rr; if (jhi > 63) jhi = 63;
      int j = lane;
      if (j >= jlo && j <= jhi)
        WTf[(((size_t)b * TT + s) * 64 + j) * 2 + half] = ST[rr * 66 + j];
    }
  }
}

// ---------------------------------------------------------------------------
// Kernel 4a: sequential DP, scatter form, LDS-ring DMA pipeline. 1 wave/batch.
// Round-6 post-mortem: register banks were demoted to scratch (VGPR=40),
// each STEP ate a dependent scratch/HBM load (~650cy). Now: 128-row LDS ring
// (64KB) filled by global_load_lds DMA (no dest reg -> cannot be sunk),
// 120-row lead, counted s_waitcnt vmcnt(52) per 8 steps; ds_read prefetch
// 8 rows ahead into NAMED float2s (worst case one ~120cy LDS latency / 8
// steps). Chain per step: v_add -> v_min -> v_readlane -> cndmask.
// Semantics identical to rounds 5/6 (validated).
// ---------------------------------------------------------------------------
__global__ __launch_bounds__(64) void dp_seq(const float* __restrict__ WT,
                                             float* __restrict__ cg) {
  __shared__ __align__(16) float2 ring[128 * 64];   // 64 KB, 128 rows x 512B
  int b = blockIdx.x;
  int lane = threadIdx.x;
  const char* Wb = (const char*)WT + (size_t)b * TT * 512;  // 512B per row
  float* cgb = cg + (size_t)b * (TT + 1);
  if (lane == 0) cgb[0] = 0.f;

  // stage rows {row, row+1} (row even): 64 lanes x 16B = 1024B, linear dest
  auto stage2 = [&](int row) {
    const char* g = Wb + ((size_t)row << 9) + (lane << 4);
    float2* l = &ring[(row & 127) << 6];
    __builtin_amdgcn_global_load_lds((const unsigned int*)g, (unsigned int*)l, 16, 0, 0);
  };
  // lane's rotated element of row r (clamped; clamp rows never consumed)
  auto ldring = [&](int r) -> float2 {
    int rc = (r > TT - 1) ? (TT - 1) : r;
    return ring[((rc & 127) << 6) | ((lane - rc) & 63)];
  };

  // prologue: 60 DMAs = rows 0..119
  for (int k = 0; k < 60; ++k) stage2(2 * k);
  asm volatile("s_waitcnt vmcnt(56)" ::: "memory");   // rows 0..7 ready
  float2 p0 = ldring(0), p1 = ldring(1), p2 = ldring(2), p3 = ldring(3);
  float2 p4 = ldring(4), p5 = ldring(5), p6 = ldring(6), p7 = ldring(7);

  float c = 0.f;            // costs[tau] (uniform, SGPR via readlane)
  float acc = DPINF;        // lane's running min for its pending t
  float ckeep = 0.f;        // lane l holds costs[.] for the periodic store

#define STEP(TAU, P) { \
    float wm = fminf((P).x, (P).y); \
    float cand = c + wm; \
    acc = fminf(acc, cand); \
    int fl = (TAU) & 63; \
    float cnew = __int_as_float(__builtin_amdgcn_readlane(__float_as_int(acc), fl)); \
    bool me = (lane == fl); \
    ckeep = me ? cnew : ckeep; \
    acc = me ? DPINF : acc; \
    c = cnew; }

  for (int gg = 0; gg < 16; ++gg) {
#pragma unroll
    for (int ii = 0; ii < 8; ++ii) {
      int tb = gg * 64 + ii * 8;
      if (tb <= 896) {
        // completed >= tb/2+8 (rows <= tb+15): issued = 60+tb/2 -> wait 52
        asm volatile("s_waitcnt vmcnt(52)" ::: "memory");
        stage2(tb + 120); stage2(tb + 122); stage2(tb + 124); stage2(tb + 126);
      } else if (tb == 904) {
        asm volatile("s_waitcnt vmcnt(0)" ::: "memory");  // all 512 DMAs done
      }
      STEP(tb + 0, p0); p0 = ldring(tb + 8);
      STEP(tb + 1, p1); p1 = ldring(tb + 9);
      STEP(tb + 2, p2); p2 = ldring(tb + 10);
      STEP(tb + 3, p3); p3 = ldring(tb + 11);
      STEP(tb + 4, p4); p4 = ldring(tb + 12);
      STEP(tb + 5, p5); p5 = ldring(tb + 13);
      STEP(tb + 6, p6); p6 = ldring(tb + 14);
      STEP(tb + 7, p7); p7 = ldring(tb + 15);
    }
    cgb[gg * 64 + 1 + lane] = ckeep;   // costs[gg*64+1 .. gg*64+64]
  }
#undef STEP
}

// ---------------------------------------------------------------------------
// Kernel 4b: parallel argmin. One wave per t: recompute total = cg[s]+W[t][i]
// (bit-identical to dp_seq's sums), find first-min -> prev, tok.
// Half-combine: value = min, token = half0 on tie (lowest v wins).
// ---------------------------------------------------------------------------
__global__ __launch_bounds__(256) void prev_k(const float* __restrict__ Wv2,
                                              const unsigned char* __restrict__ WI2,
                                              const float* __restrict__ cg,
                                              int* __restrict__ pk) {
  int row = blockIdx.x * 4 + (threadIdx.x >> 6);   // row in [0, BB*TT)
  int lane = threadIdx.x & 63;
  int b = row >> 10;
  int t = (row & 1023) + 1;
  int s = t - 64 + lane;
  size_t idx = (size_t)row * 64 + lane;
  float2 w2 = ((const float2*)Wv2)[idx];
  uchar2 i2 = ((const uchar2*)WI2)[idx];
  bool h0 = (w2.x <= w2.y);
  float w = h0 ? w2.x : w2.y;
  int wi = h0 ? (int)i2.x : ((int)i2.y + 128);
  int sc = (s < 0) ? 0 : s;
  float c = cg[(size_t)b * (TT + 1) + sc];
  float total = (s >= 0) ? (c + w) : DPINF;
  float m = total;
  DPP_MIN_REDUCE(m);
  float mf = __int_as_float(__builtin_amdgcn_readlane(__float_as_int(m), 63));
  unsigned long long msk = __ballot(total == mf);
  int iwin = __builtin_ctzll(msk);                 // smallest i = smallest s (ref tie-break)
  int tok = __builtin_amdgcn_readlane(wi, iwin) & 255;
  int prev = t - 64 + iwin;
  if (lane == 0) pk[(size_t)b * (TT + 1) + t] = (prev << 8) | tok;
}

// ---------------------------------------------------------------------------
// Kernel 4c: backtrack + outputs. One wave per batch; packed prev/tok walk
// in LDS; float32-encoded outputs (harness reads whole d_out as float32).
// ---------------------------------------------------------------------------
__global__ __launch_bounds__(64) void bt_k(const int* __restrict__ pk,
                                           const float* __restrict__ cg,
                                           const int* __restrict__ lengths,
                                           float* __restrict__ out) {
  int b = blockIdx.x;
  int lane = threadIdx.x;
  __shared__ int pks[TT + 1];
  __shared__ int bs[TT];
  __shared__ int ts[TT];

  const int* pb = pk + (size_t)b * (TT + 1);
  for (int k = lane; k <= TT; k += 64) pks[k] = pb[k];
  __syncthreads();

  int len = lengths[b];
  len = (len > TT) ? TT : (len < 0 ? 0 : len);
  int cnt = 0;
  if (lane == 0) {
    int st = len;
    while (st > 0 && cnt < TT) {
      int e = pks[st];
      bs[cnt] = st;
      ts[cnt] = e & 255;
      st = e >> 8;            // prev < st, strictly decreasing
      ++cnt;
    }
  }
  cnt = __shfl(cnt, 0);
  __syncthreads();

  float* bout = out + b * TT;
  float* tout = out + MM + b * TT;
  for (int k = lane; k < TT; k += 64) {
    bout[k] = (k < cnt) ? (float)bs[cnt - 1 - k] : 0.f;
    tout[k] = (k < cnt) ? (float)ts[cnt - 1 - k] : 0.f;
  }
  if (lane == 0) {
    out[2 * MM + b] = (float)cnt;                          // counts
    out[2 * MM + BB + b] = cg[(size_t)b * (TT + 1) + len]; // final cost
  }
}

// ---------------------------------------------------------------------------
extern "C" void kernel_launch(void* const* d_in, const int* in_sizes, int n_in,
                              void* d_out, int out_size, void* d_ws, size_t ws_size,
                              hipStream_t stream) {
  const float* reps = (const float*)d_in[0];
  const float* cb   = (const float*)d_in[1];
  const int* lengths = (const int*)d_in[2];
  float* out = (float*)d_out;

  char* ws = (char*)d_ws;
  float* r2 = (float*)ws;                                    // 64 KB
  float* c2 = (float*)(ws + 65536);                          // 4 KB slot
  char* p = ws + 69632;
  float* dmat = (float*)p;               p += (size_t)MM * VV * 4;       // 16 MB
  float* Wv2  = (float*)p;               p += (size_t)MM * 128 * 4;      // 8 MB
  unsigned char* WI2 = (unsigned char*)p; p += (size_t)MM * 128;         // 2 MB
  float2* WT2 = (float2*)p;              p += (size_t)MM * 64 * 8;       // 8 MB
  float* cg   = (float*)p;               p += (size_t)BB * (TT + 1) * 4; // 65.6 KB
  int* pk     = (int*)p;                                                 // 65.6 KB

  norms_k<<<(MM + VV) / 4, 256, 0, stream>>>(reps, cb, r2, c2);
  gemm_k<<<dim3(VV / 64, MM / 64), 256, 0, stream>>>(reps, cb, r2, c2, dmat);
  w_k<<<BB * (TT / 64) * 2, 256, 0, stream>>>(dmat, Wv2, WI2, WT2);
  dp_seq<<<BB, 64, 0, stream>>>((const float*)WT2, cg);
  prev_k<<<MM / 4, 256, 0, stream>>>(Wv2, WI2, cg, pk);
  bt_k<<<BB, 64, 0, stream>>>(pk, cg, lengths, out);
}

// Round 8
// 197.087 us; speedup vs baseline: 2.4005x; 1.2539x over previous
//
#include <hip/hip_runtime.h>

#define BB 16
#define TT 1024
#define DD 512
#define VV 256
#define MM (BB*TT)

#define DPINF 1e30f

typedef __attribute__((ext_vector_type(8))) short bf16x8;
typedef __attribute__((ext_vector_type(4))) float f32x4;

// DPP min-reduce step; old = same reg -> identity for lanes with no source
#define DPP_MIN_STEP(m, CTRL) { \
  int _t = __builtin_amdgcn_update_dpp(__float_as_int(m), __float_as_int(m), CTRL, 0xF, 0xF, false); \
  m = fminf(m, __int_as_float(_t)); }

// full 64-lane min into lane 63: row_shr 1,2,4,8 then row_bcast15, row_bcast31
#define DPP_MIN_REDUCE(m) \
  DPP_MIN_STEP(m, 0x111); DPP_MIN_STEP(m, 0x112); DPP_MIN_STEP(m, 0x114); \
  DPP_MIN_STEP(m, 0x118); DPP_MIN_STEP(m, 0x142); DPP_MIN_STEP(m, 0x143);

// ---------------------------------------------------------------------------
// Kernel 1: row norms of reps/codebook + RNE fp32->bf16 conversion of both
// (repsb aliases the Wv2/WI2/WT2 region: dead before w_k writes it).
// ---------------------------------------------------------------------------
__global__ __launch_bounds__(256) void norms_k(const float* __restrict__ reps,
                                               const float* __restrict__ cb,
                                               float* __restrict__ r2,
                                               float* __restrict__ c2,
                                               ushort* __restrict__ repsb,
                                               ushort* __restrict__ cbb) {
  int row = blockIdx.x * 4 + (threadIdx.x >> 6);
  int lane = threadIdx.x & 63;
  const float* src;
  float* dst;
  ushort* bdst;
  if (row < MM) {
    src = reps + (size_t)row * DD;
    dst = r2 + row;
    bdst = repsb + (size_t)row * DD;
  } else {
    int r = row - MM;
    if (r >= VV) return;
    src = cb + (size_t)r * DD;
    dst = c2 + r;
    bdst = cbb + (size_t)r * DD;
  }
  const float4* s4 = (const float4*)src;
  float4 a = s4[lane];
  float4 b = s4[lane + 64];

  auto cvt = [](float x) -> ushort {
    unsigned u = __float_as_uint(x);
    return (ushort)((u + 0x7FFFu + ((u >> 16) & 1u)) >> 16);   // RNE
  };
  ushort4 ua = make_ushort4(cvt(a.x), cvt(a.y), cvt(a.z), cvt(a.w));
  ushort4 ub = make_ushort4(cvt(b.x), cvt(b.y), cvt(b.z), cvt(b.w));
  *(ushort4*)&bdst[lane * 4] = ua;
  *(ushort4*)&bdst[256 + lane * 4] = ub;

  float s = a.x*a.x + a.y*a.y + a.z*a.z + a.w*a.w
          + b.x*b.x + b.y*b.y + b.z*b.z + b.w*b.w;
#pragma unroll
  for (int off = 1; off < 64; off <<= 1) s += __shfl_xor(s, off);
  if (lane == 0) *dst = s;
}

// ---------------------------------------------------------------------------
// Kernel 2: d[m][v] = r2[m] - 2*dot(reps[m],cb[v]) + c2[v] via bf16 MFMA.
// 64x64 tile, 4 waves, BK=64, double-buffered LDS (32KB), global_load_lds
// staging with pre-swizzled global source (col ^= (row&7)<<4) and matching
// swizzled ds_read_b128 fragment reads. Counted vmcnt(4): next chunk's loads
// stay in flight across the barrier. 8 mfma_f32_16x16x32_bf16 / wave / chunk.
// C/D map: col=lane&15, row=(lane>>4)*4+reg (m89-verified).
// ---------------------------------------------------------------------------
__global__ __launch_bounds__(256) void gemm_k(const ushort* __restrict__ repsb,
                                              const ushort* __restrict__ cbb,
                                              const float* __restrict__ r2,
                                              const float* __restrict__ c2,
                                              float* __restrict__ dmat) {
  __shared__ short Ab[2][4096];   // [64 rows][64 k] bf16, xor-swizzled
  __shared__ short Bb[2][4096];
  int tid = threadIdx.x;
  int w = tid >> 6, l = tid & 63;
  int m0 = blockIdx.x * 64, v0 = blockIdx.y * 64;

  int srow = l >> 3;                          // row within 8-row store group
  int scol = ((l & 7) << 4) ^ (srow << 4);    // pre-swizzled col byte (0..127)

  auto stage = [&](int buf, int kc) {
#pragma unroll
    for (int ii = 0; ii < 2; ++ii) {
      int instr = w + ii * 4;                 // 8 rows per instruction
      int row = instr * 8 + srow;
      const char* ga = (const char*)repsb + ((size_t)(m0 + row) * DD + kc * 64) * 2 + scol;
      __builtin_amdgcn_global_load_lds((const unsigned int*)ga,
                                       (unsigned int*)&Ab[buf][instr * 512], 16, 0, 0);
      const char* gb = (const char*)cbb + ((size_t)(v0 + row) * DD + kc * 64) * 2 + scol;
      __builtin_amdgcn_global_load_lds((const unsigned int*)gb,
                                       (unsigned int*)&Bb[buf][instr * 512], 16, 0, 0);
    }
  };

  int fr = l & 15;       // A row / B col within 16-tile
  int fq = l >> 4;       // k-quarter (8 bf16 each)
  int swz = (fr & 7) << 3;                    // short-index xor

  f32x4 acc0 = {0.f,0.f,0.f,0.f}, acc1 = {0.f,0.f,0.f,0.f};
  f32x4 acc2 = {0.f,0.f,0.f,0.f}, acc3 = {0.f,0.f,0.f,0.f};

  stage(0, 0);
  int cur = 0;
  for (int kc = 0; kc < 8; ++kc) {
    if (kc < 7) {
      stage(cur ^ 1, kc + 1);
      asm volatile("s_waitcnt vmcnt(4)" ::: "memory");
    } else {
      asm volatile("s_waitcnt vmcnt(0)" ::: "memory");
    }
    __syncthreads();
#pragma unroll
    for (int ks = 0; ks < 2; ++ks) {
      int koff = (ks * 32 + fq * 8) ^ swz;
      bf16x8 av = *(const bf16x8*)&Ab[cur][(w * 16 + fr) * 64 + koff];
      bf16x8 b0 = *(const bf16x8*)&Bb[cur][(0 * 16 + fr) * 64 + koff];
      bf16x8 b1 = *(const bf16x8*)&Bb[cur][(1 * 16 + fr) * 64 + koff];
      bf16x8 b2 = *(const bf16x8*)&Bb[cur][(2 * 16 + fr) * 64 + koff];
      bf16x8 b3 = *(const bf16x8*)&Bb[cur][(3 * 16 + fr) * 64 + koff];
      acc0 = __builtin_amdgcn_mfma_f32_16x16x32_bf16(av, b0, acc0, 0, 0, 0);
      acc1 = __builtin_amdgcn_mfma_f32_16x16x32_bf16(av, b1, acc1, 0, 0, 0);
      acc2 = __builtin_amdgcn_mfma_f32_16x16x32_bf16(av, b2, acc2, 0, 0, 0);
      acc3 = __builtin_amdgcn_mfma_f32_16x16x32_bf16(av, b3, acc3, 0, 0, 0);
    }
    __syncthreads();
    cur ^= 1;
  }

  // epilogue: dmat[m][v] = r2[m] + c2[v] - 2*acc
  float rv[4];
#pragma unroll
  for (int r = 0; r < 4; ++r) rv[r] = r2[m0 + w * 16 + fq * 4 + r];
#pragma unroll
  for (int vt = 0; vt < 4; ++vt) {
    f32x4 a = (vt == 0) ? acc0 : (vt == 1) ? acc1 : (vt == 2) ? acc2 : acc3;
    int v = v0 + vt * 16 + fr;
    float cc = c2[v];
#pragma unroll
    for (int r = 0; r < 4; ++r) {
      int m = m0 + w * 16 + fq * 4 + r;
      dmat[(size_t)m * VV + v] = fmaf(-2.f, a[r], rv[r] + cc);
    }
  }
}

// ---------------------------------------------------------------------------
// Kernel 3: W[t][i] = min_v sum_{f=s+1..t} d[f][v], s = t-64+i.
// One block per (batch, 64-t chunk, v-half-of-128). Grid 512.
// Phase 1: parallel window cumsum build (reg chunks + LDS prefix).
// Phase 2: lane-private v-scan.
// Phase 3: diagonal restage WT[s][j] = W[s+1+j][i=63-j] (float2 slot [half]).
// ---------------------------------------------------------------------------
__global__ __launch_bounds__(256) void w_k(const float* __restrict__ dmat,
                                           float* __restrict__ Wv2,
                                           unsigned char* __restrict__ WI2,
                                           float2* __restrict__ WT2) {
  __shared__ __align__(16) float CL[128 * 128];
  __shared__ __align__(16) float TOT[8 * 128];
  int bx = blockIdx.x;
  int b = bx >> 5;
  int chunk = (bx >> 1) & 15;
  int half = bx & 1;
  int t1 = 1 + (chunk << 6);             // block covers t in [t1, t1+63]
  int tid = threadIdx.x;
  int wv = tid >> 6, lane = tid & 63;

  // ---- Phase 1: parallel cumsum build ----
  {
    int c = tid >> 5;          // 16-frame chunk 0..7
    int g = tid & 31;          // float4 group within half
    const float* base = dmat + (size_t)b * TT * VV + (half << 7) + (g << 2);
    float4 rr[16];
    float4 run = make_float4(0.f, 0.f, 0.f, 0.f);
#pragma unroll
    for (int j = 1; j <= 16; ++j) {
      int k = (c << 4) + j;
      int f = t1 - 64 + k;                 // frame for cumsum row k
      bool valid = (k <= 127) && (f >= 1) && (f <= TT);
      int fc = valid ? f : 1;
      float4 dv = *(const float4*)(base + (size_t)(fc - 1) * VV);
      if (!valid) dv = make_float4(0.f, 0.f, 0.f, 0.f);
      run.x += dv.x; run.y += dv.y; run.z += dv.z; run.w += dv.w;
      rr[j - 1] = run;
    }
    *(float4*)&TOT[c * 128 + (g << 2)] = run;
    if (c == 0) *(float4*)&CL[0 * 128 + (g << 2)] = make_float4(0.f, 0.f, 0.f, 0.f);
    __syncthreads();
    float4 off = make_float4(0.f, 0.f, 0.f, 0.f);
#pragma unroll
    for (int cc = 0; cc < 7; ++cc) {
      if (cc < c) {
        float4 tv = *(const float4*)&TOT[cc * 128 + (g << 2)];
        off.x += tv.x; off.y += tv.y; off.z += tv.z; off.w += tv.w;
      }
    }
#pragma unroll
    for (int j = 1; j <= 16; ++j) {
      int k = (c << 4) + j;
      if (k <= 127) {
        float4 s = rr[j - 1];
        s.x += off.x; s.y += off.y; s.z += off.z; s.w += off.w;
        *(float4*)&CL[k * 128 + ((g ^ (k & 31)) << 2)] = s;
      }
    }
  }
  __syncthreads();

  // ---- Phase 2: lane-private scan over this half's 128 v ----
  float bw[16];
  int ba[16];
#pragma unroll
  for (int j = 0; j < 16; ++j) { bw[j] = 1e38f; ba[j] = 0; }

#pragma unroll
  for (int j = 0; j < 16; ++j) {
    int dt = (j << 2) + wv;           // 0..63
    int ks = dt + lane;               // row of C_s (s = t-64+lane)
    int kt = dt + 64;                 // row of C_t
    const float* rs = &CL[ks * 128];
    const float* rt = &CL[kt * 128];
    int ksm = ks & 31, ktm = kt & 31;
    float bv = bw[j];
    int bi = ba[j];
#pragma unroll 4
    for (int g = 0; g < 32; ++g) {
      float4 a = *(const float4*)&rs[(g ^ ksm) << 2];
      float4 t4 = *(const float4*)&rt[(g ^ ktm) << 2];
      int v0 = (g << 2);
      float s0 = t4.x - a.x; if (s0 < bv) { bv = s0; bi = v0; }
      float s1 = t4.y - a.y; if (s1 < bv) { bv = s1; bi = v0 + 1; }
      float s2 = t4.z - a.z; if (s2 < bv) { bv = s2; bi = v0 + 2; }
      float s3 = t4.w - a.w; if (s3 < bv) { bv = s3; bi = v0 + 3; }
    }
    bw[j] = bv; ba[j] = bi;
  }

  // per-t layout for prev_k
#pragma unroll
  for (int j = 0; j < 16; ++j) {
    int t = t1 + (j << 2) + wv;
    size_t idx = (((size_t)b * TT + (t - 1)) * 64 + lane) * 2 + half;
    Wv2[idx] = bw[j];
    WI2[idx] = (unsigned char)ba[j];   // v within half; half1 adds 128 at use
  }

  // ---- Phase 3: diagonal restage (reuse CL as ST[127][66]) ----
  __syncthreads();                     // all CL reads of phase 2 done
  float* ST = CL;
#pragma unroll
  for (int j = 0; j < 16; ++j) {
    int t_local = (j << 2) + wv;
    int srow = t_local + lane;         // 0..126 ; s = t1-64+srow
    ST[srow * 66 + (63 - lane)] = bw[j];
  }
  __syncthreads();
  {
    float* WTf = (float*)WT2;
    for (int q = 0; q < 32; ++q) {
      int rr = wv * 32 + q;
      if (rr > 126) break;             // row 127 doesn't exist
      int s = t1 - 64 + rr;
      if (s < 0) continue;
      int jlo = 63 - rr; if (jlo < 0) jlo = 0;
      int jhi = 126 - rr; if (jhi > 63) jhi = 63;
      int j = lane;
      if (j >= jlo && j <= jhi)
        WTf[(((size_t)b * TT + s) * 64 + j) * 2 + half] = ST[rr * 66 + j];
    }
  }
}

// ---------------------------------------------------------------------------
// Kernel 4a: sequential DP, scatter form, LDS-ring DMA pipeline. 1 wave/batch.
// 128-row LDS ring (64KB) filled by global_load_lds DMA, 120-row lead,
// counted s_waitcnt vmcnt(52) per 8 steps; ds_read prefetch 8 rows ahead
// into NAMED float2s. Chain/step: v_add -> v_min -> v_readlane -> cndmask.
// ---------------------------------------------------------------------------
__global__ __launch_bounds__(64) void dp_seq(const float* __restrict__ WT,
                                             float* __restrict__ cg) {
  __shared__ __align__(16) float2 ring[128 * 64];   // 64 KB, 128 rows x 512B
  int b = blockIdx.x;
  int lane = threadIdx.x;
  const char* Wb = (const char*)WT + (size_t)b * TT * 512;  // 512B per row
  float* cgb = cg + (size_t)b * (TT + 1);
  if (lane == 0) cgb[0] = 0.f;

  auto stage2 = [&](int row) {
    const char* g = Wb + ((size_t)row << 9) + (lane << 4);
    float2* l = &ring[(row & 127) << 6];
    __builtin_amdgcn_global_load_lds((const unsigned int*)g, (unsigned int*)l, 16, 0, 0);
  };
  auto ldring = [&](int r) -> float2 {
    int rc = (r > TT - 1) ? (TT - 1) : r;
    return ring[((rc & 127) << 6) | ((lane - rc) & 63)];
  };

  for (int k = 0; k < 60; ++k) stage2(2 * k);
  asm volatile("s_waitcnt vmcnt(56)" ::: "memory");   // rows 0..7 ready
  float2 p0 = ldring(0), p1 = ldring(1), p2 = ldring(2), p3 = ldring(3);
  float2 p4 = ldring(4), p5 = ldring(5), p6 = ldring(6), p7 = ldring(7);

  float c = 0.f;
  float acc = DPINF;
  float ckeep = 0.f;

#define STEP(TAU, P) { \
    float wm = fminf((P).x, (P).y); \
    float cand = c + wm; \
    acc = fminf(acc, cand); \
    int fl = (TAU) & 63; \
    float cnew = __int_as_float(__builtin_amdgcn_readlane(__float_as_int(acc), fl)); \
    bool me = (lane == fl); \
    ckeep = me ? cnew : ckeep; \
    acc = me ? DPINF : acc; \
    c = cnew; }

  for (int gg = 0; gg < 16; ++gg) {
#pragma unroll
    for (int ii = 0; ii < 8; ++ii) {
      int tb = gg * 64 + ii * 8;
      if (tb <= 896) {
        asm volatile("s_waitcnt vmcnt(52)" ::: "memory");
        stage2(tb + 120); stage2(tb + 122); stage2(tb + 124); stage2(tb + 126);
      } else if (tb == 904) {
        asm volatile("s_waitcnt vmcnt(0)" ::: "memory");
      }
      STEP(tb + 0, p0); p0 = ldring(tb + 8);
      STEP(tb + 1, p1); p1 = ldring(tb + 9);
      STEP(tb + 2, p2); p2 = ldring(tb + 10);
      STEP(tb + 3, p3); p3 = ldring(tb + 11);
      STEP(tb + 4, p4); p4 = ldring(tb + 12);
      STEP(tb + 5, p5); p5 = ldring(tb + 13);
      STEP(tb + 6, p6); p6 = ldring(tb + 14);
      STEP(tb + 7, p7); p7 = ldring(tb + 15);
    }
    cgb[gg * 64 + 1 + lane] = ckeep;
  }
#undef STEP
}

// ---------------------------------------------------------------------------
// Kernel 4b: parallel argmin. One wave per t: recompute total = cg[s]+W[t][i],
// find first-min -> prev, tok. Half-combine: min value, half0 wins ties.
// ---------------------------------------------------------------------------
__global__ __launch_bounds__(256) void prev_k(const float* __restrict__ Wv2,
                                              const unsigned char* __restrict__ WI2,
                                              const float* __restrict__ cg,
                                              int* __restrict__ pk) {
  int row = blockIdx.x * 4 + (threadIdx.x >> 6);   // row in [0, BB*TT)
  int lane = threadIdx.x & 63;
  int b = row >> 10;
  int t = (row & 1023) + 1;
  int s = t - 64 + lane;
  size_t idx = (size_t)row * 64 + lane;
  float2 w2 = ((const float2*)Wv2)[idx];
  uchar2 i2 = ((const uchar2*)WI2)[idx];
  bool h0 = (w2.x <= w2.y);
  float w = h0 ? w2.x : w2.y;
  int wi = h0 ? (int)i2.x : ((int)i2.y + 128);
  int sc = (s < 0) ? 0 : s;
  float c = cg[(size_t)b * (TT + 1) + sc];
  float total = (s >= 0) ? (c + w) : DPINF;
  float m = total;
  DPP_MIN_REDUCE(m);
  float mf = __int_as_float(__builtin_amdgcn_readlane(__float_as_int(m), 63));
  unsigned long long msk = __ballot(total == mf);
  int iwin = __builtin_ctzll(msk);                 // smallest i = smallest s
  int tok = __builtin_amdgcn_readlane(wi, iwin) & 255;
  int prev = t - 64 + iwin;
  if (lane == 0) pk[(size_t)b * (TT + 1) + t] = (prev << 8) | tok;
}

// ---------------------------------------------------------------------------
// Kernel 4c: backtrack + outputs (float32-encoded d_out).
// ---------------------------------------------------------------------------
__global__ __launch_bounds__(64) void bt_k(const int* __restrict__ pk,
                                           const float* __restrict__ cg,
                                           const int* __restrict__ lengths,
                                           float* __restrict__ out) {
  int b = blockIdx.x;
  int lane = threadIdx.x;
  __shared__ int pks[TT + 1];
  __shared__ int bs[TT];
  __shared__ int ts[TT];

  const int* pb = pk + (size_t)b * (TT + 1);
  for (int k = lane; k <= TT; k += 64) pks[k] = pb[k];
  __syncthreads();

  int len = lengths[b];
  len = (len > TT) ? TT : (len < 0 ? 0 : len);
  int cnt = 0;
  if (lane == 0) {
    int st = len;
    while (st > 0 && cnt < TT) {
      int e = pks[st];
      bs[cnt] = st;
      ts[cnt] = e & 255;
      st = e >> 8;
      ++cnt;
    }
  }
  cnt = __shfl(cnt, 0);
  __syncthreads();

  float* bout = out + b * TT;
  float* tout = out + MM + b * TT;
  for (int k = lane; k < TT; k += 64) {
    bout[k] = (k < cnt) ? (float)bs[cnt - 1 - k] : 0.f;
    tout[k] = (k < cnt) ? (float)ts[cnt - 1 - k] : 0.f;
  }
  if (lane == 0) {
    out[2 * MM + b] = (float)cnt;
    out[2 * MM + BB + b] = cg[(size_t)b * (TT + 1) + len];
  }
}

// ---------------------------------------------------------------------------
extern "C" void kernel_launch(void* const* d_in, const int* in_sizes, int n_in,
                              void* d_out, int out_size, void* d_ws, size_t ws_size,
                              hipStream_t stream) {
  const float* reps = (const float*)d_in[0];
  const float* cb   = (const float*)d_in[1];
  const int* lengths = (const int*)d_in[2];
  float* out = (float*)d_out;

  char* ws = (char*)d_ws;
  float* r2 = (float*)ws;                                    // 64 KB
  float* c2 = (float*)(ws + 65536);                          // 4 KB slot
  char* p = ws + 69632;
  float* dmat = (float*)p;               p += (size_t)MM * VV * 4;       // 16 MB
  float* Wv2  = (float*)p;               p += (size_t)MM * 128 * 4;      // 8 MB
  unsigned char* WI2 = (unsigned char*)p; p += (size_t)MM * 128;         // 2 MB
  float2* WT2 = (float2*)p;              p += (size_t)MM * 64 * 8;       // 8 MB
  float* cg   = (float*)p;               p += (size_t)BB * (TT + 1) * 4; // 65.6 KB
  int* pk     = (int*)p;                 p += (size_t)BB * (TT + 1) * 4; // 65.6 KB
  ushort* cbb = (ushort*)p;                                              // 256 KB
  // repsb (16.8 MB) aliases Wv2/WI2 region: dead before w_k writes them
  ushort* repsb = (ushort*)Wv2;

  norms_k<<<(MM + VV) / 4, 256, 0, stream>>>(reps, cb, r2, c2, repsb, cbb);
  gemm_k<<<dim3(MM / 64, VV / 64), 256, 0, stream>>>(repsb, cbb, r2, c2, dmat);
  w_k<<<BB * (TT / 64) * 2, 256, 0, stream>>>(dmat, Wv2, WI2, WT2);
  dp_seq<<<BB, 64, 0, stream>>>((const float*)WT2, cg);
  prev_k<<<MM / 4, 256, 0, stream>>>(Wv2, WI2, cg, pk);
  bt_k<<<BB, 64, 0, stream>>>(pk, cg, lengths, out);
}

// Round 9
// 157.794 us; speedup vs baseline: 2.9982x; 1.2490x over previous
//
#include <hip/hip_runtime.h>

#define BB 16
#define TT 1024
#define DD 512
#define VV 256
#define MM (BB*TT)

#define DPINF 1e30f

typedef __attribute__((ext_vector_type(8))) short bf16x8;
typedef __attribute__((ext_vector_type(4))) float f32x4;

// DPP min-reduce step; old = same reg -> identity for lanes with no source
#define DPP_MIN_STEP(m, CTRL) { \
  int _t = __builtin_amdgcn_update_dpp(__float_as_int(m), __float_as_int(m), CTRL, 0xF, 0xF, false); \
  m = fminf(m, __int_as_float(_t)); }

// full 64-lane min into lane 63: row_shr 1,2,4,8 then row_bcast15, row_bcast31
#define DPP_MIN_REDUCE(m) \
  DPP_MIN_STEP(m, 0x111); DPP_MIN_STEP(m, 0x112); DPP_MIN_STEP(m, 0x114); \
  DPP_MIN_STEP(m, 0x118); DPP_MIN_STEP(m, 0x142); DPP_MIN_STEP(m, 0x143);

// ---------------------------------------------------------------------------
// Kernel 1: row norms of reps/codebook + RNE fp32->bf16 conversion of both
// (repsb aliases the Wv2/WI2/WT2 region: dead before w_k writes it).
// ---------------------------------------------------------------------------
__global__ __launch_bounds__(256) void norms_k(const float* __restrict__ reps,
                                               const float* __restrict__ cb,
                                               float* __restrict__ r2,
                                               float* __restrict__ c2,
                                               ushort* __restrict__ repsb,
                                               ushort* __restrict__ cbb) {
  int row = blockIdx.x * 4 + (threadIdx.x >> 6);
  int lane = threadIdx.x & 63;
  const float* src;
  float* dst;
  ushort* bdst;
  if (row < MM) {
    src = reps + (size_t)row * DD;
    dst = r2 + row;
    bdst = repsb + (size_t)row * DD;
  } else {
    int r = row - MM;
    if (r >= VV) return;
    src = cb + (size_t)r * DD;
    dst = c2 + r;
    bdst = cbb + (size_t)r * DD;
  }
  const float4* s4 = (const float4*)src;
  float4 a = s4[lane];
  float4 b = s4[lane + 64];

  auto cvt = [](float x) -> ushort {
    unsigned u = __float_as_uint(x);
    return (ushort)((u + 0x7FFFu + ((u >> 16) & 1u)) >> 16);   // RNE
  };
  ushort4 ua = make_ushort4(cvt(a.x), cvt(a.y), cvt(a.z), cvt(a.w));
  ushort4 ub = make_ushort4(cvt(b.x), cvt(b.y), cvt(b.z), cvt(b.w));
  *(ushort4*)&bdst[lane * 4] = ua;
  *(ushort4*)&bdst[256 + lane * 4] = ub;

  float s = a.x*a.x + a.y*a.y + a.z*a.z + a.w*a.w
          + b.x*b.x + b.y*b.y + b.z*b.z + b.w*b.w;
#pragma unroll
  for (int off = 1; off < 64; off <<= 1) s += __shfl_xor(s, off);
  if (lane == 0) *dst = s;
}

// ---------------------------------------------------------------------------
// Kernel 2: d[m][v] = r2[m] - 2*dot(reps[m],cb[v]) + c2[v] via bf16 MFMA.
// 64x64 tile, 4 waves, BK=64, double-buffered LDS (32KB), global_load_lds
// staging with pre-swizzled global source and matching swizzled ds_read_b128.
// Counted vmcnt(4). C/D map: col=lane&15, row=(lane>>4)*4+reg.
// ---------------------------------------------------------------------------
__global__ __launch_bounds__(256) void gemm_k(const ushort* __restrict__ repsb,
                                              const ushort* __restrict__ cbb,
                                              const float* __restrict__ r2,
                                              const float* __restrict__ c2,
                                              float* __restrict__ dmat) {
  __shared__ short Ab[2][4096];   // [64 rows][64 k] bf16, xor-swizzled
  __shared__ short Bb[2][4096];
  int tid = threadIdx.x;
  int w = tid >> 6, l = tid & 63;
  int m0 = blockIdx.x * 64, v0 = blockIdx.y * 64;

  int srow = l >> 3;                          // row within 8-row store group
  int scol = ((l & 7) << 4) ^ (srow << 4);    // pre-swizzled col byte (0..127)

  auto stage = [&](int buf, int kc) {
#pragma unroll
    for (int ii = 0; ii < 2; ++ii) {
      int instr = w + ii * 4;                 // 8 rows per instruction
      int row = instr * 8 + srow;
      const char* ga = (const char*)repsb + ((size_t)(m0 + row) * DD + kc * 64) * 2 + scol;
      __builtin_amdgcn_global_load_lds((const unsigned int*)ga,
                                       (unsigned int*)&Ab[buf][instr * 512], 16, 0, 0);
      const char* gb = (const char*)cbb + ((size_t)(v0 + row) * DD + kc * 64) * 2 + scol;
      __builtin_amdgcn_global_load_lds((const unsigned int*)gb,
                                       (unsigned int*)&Bb[buf][instr * 512], 16, 0, 0);
    }
  };

  int fr = l & 15;       // A row / B col within 16-tile
  int fq = l >> 4;       // k-quarter (8 bf16 each)
  int swz = (fr & 7) << 3;                    // short-index xor

  f32x4 acc0 = {0.f,0.f,0.f,0.f}, acc1 = {0.f,0.f,0.f,0.f};
  f32x4 acc2 = {0.f,0.f,0.f,0.f}, acc3 = {0.f,0.f,0.f,0.f};

  stage(0, 0);
  int cur = 0;
  for (int kc = 0; kc < 8; ++kc) {
    if (kc < 7) {
      stage(cur ^ 1, kc + 1);
      asm volatile("s_waitcnt vmcnt(4)" ::: "memory");
    } else {
      asm volatile("s_waitcnt vmcnt(0)" ::: "memory");
    }
    __syncthreads();
#pragma unroll
    for (int ks = 0; ks < 2; ++ks) {
      int koff = (ks * 32 + fq * 8) ^ swz;
      bf16x8 av = *(const bf16x8*)&Ab[cur][(w * 16 + fr) * 64 + koff];
      bf16x8 b0 = *(const bf16x8*)&Bb[cur][(0 * 16 + fr) * 64 + koff];
      bf16x8 b1 = *(const bf16x8*)&Bb[cur][(1 * 16 + fr) * 64 + koff];
      bf16x8 b2 = *(const bf16x8*)&Bb[cur][(2 * 16 + fr) * 64 + koff];
      bf16x8 b3 = *(const bf16x8*)&Bb[cur][(3 * 16 + fr) * 64 + koff];
      acc0 = __builtin_amdgcn_mfma_f32_16x16x32_bf16(av, b0, acc0, 0, 0, 0);
      acc1 = __builtin_amdgcn_mfma_f32_16x16x32_bf16(av, b1, acc1, 0, 0, 0);
      acc2 = __builtin_amdgcn_mfma_f32_16x16x32_bf16(av, b2, acc2, 0, 0, 0);
      acc3 = __builtin_amdgcn_mfma_f32_16x16x32_bf16(av, b3, acc3, 0, 0, 0);
    }
    __syncthreads();
    cur ^= 1;
  }

  // epilogue: dmat[m][v] = r2[m] + c2[v] - 2*acc
  float rv[4];
#pragma unroll
  for (int r = 0; r < 4; ++r) rv[r] = r2[m0 + w * 16 + fq * 4 + r];
#pragma unroll
  for (int vt = 0; vt < 4; ++vt) {
    f32x4 a = (vt == 0) ? acc0 : (vt == 1) ? acc1 : (vt == 2) ? acc2 : acc3;
    int v = v0 + vt * 16 + fr;
    float cc = c2[v];
#pragma unroll
    for (int r = 0; r < 4; ++r) {
      int m = m0 + w * 16 + fq * 4 + r;
      dmat[(size_t)m * VV + v] = fmaf(-2.f, a[r], rv[r] + cc);
    }
  }
}

// ---------------------------------------------------------------------------
// Kernel 3: W[t][i] = min_v sum_{f=s+1..t} d[f][v], s = t-64+i.
// One block per (batch, 64-t chunk, v-half-of-128). Grid 512.
// Phase 1: parallel window cumsum build. Phase 2: lane-private v-scan.
// Phase 3: diagonal restage WT[s][j] = W[s+1+j][i=63-j] (float2 slot [half]).
// ---------------------------------------------------------------------------
__global__ __launch_bounds__(256) void w_k(const float* __restrict__ dmat,
                                           float* __restrict__ Wv2,
                                           unsigned char* __restrict__ WI2,
                                           float2* __restrict__ WT2) {
  __shared__ __align__(16) float CL[128 * 128];
  __shared__ __align__(16) float TOT[8 * 128];
  int bx = blockIdx.x;
  int b = bx >> 5;
  int chunk = (bx >> 1) & 15;
  int half = bx & 1;
  int t1 = 1 + (chunk << 6);             // block covers t in [t1, t1+63]
  int tid = threadIdx.x;
  int wv = tid >> 6, lane = tid & 63;

  // ---- Phase 1: parallel cumsum build ----
  {
    int c = tid >> 5;          // 16-frame chunk 0..7
    int g = tid & 31;          // float4 group within half
    const float* base = dmat + (size_t)b * TT * VV + (half << 7) + (g << 2);
    float4 rr[16];
    float4 run = make_float4(0.f, 0.f, 0.f, 0.f);
#pragma unroll
    for (int j = 1; j <= 16; ++j) {
      int k = (c << 4) + j;
      int f = t1 - 64 + k;                 // frame for cumsum row k
      bool valid = (k <= 127) && (f >= 1) && (f <= TT);
      int fc = valid ? f : 1;
      float4 dv = *(const float4*)(base + (size_t)(fc - 1) * VV);
      if (!valid) dv = make_float4(0.f, 0.f, 0.f, 0.f);
      run.x += dv.x; run.y += dv.y; run.z += dv.z; run.w += dv.w;
      rr[j - 1] = run;
    }
    *(float4*)&TOT[c * 128 + (g << 2)] = run;
    if (c == 0) *(float4*)&CL[0 * 128 + (g << 2)] = make_float4(0.f, 0.f, 0.f, 0.f);
    __syncthreads();
    float4 off = make_float4(0.f, 0.f, 0.f, 0.f);
#pragma unroll
    for (int cc = 0; cc < 7; ++cc) {
      if (cc < c) {
        float4 tv = *(const float4*)&TOT[cc * 128 + (g << 2)];
        off.x += tv.x; off.y += tv.y; off.z += tv.z; off.w += tv.w;
      }
    }
#pragma unroll
    for (int j = 1; j <= 16; ++j) {
      int k = (c << 4) + j;
      if (k <= 127) {
        float4 s = rr[j - 1];
        s.x += off.x; s.y += off.y; s.z += off.z; s.w += off.w;
        *(float4*)&CL[k * 128 + ((g ^ (k & 31)) << 2)] = s;
      }
    }
  }
  __syncthreads();

  // ---- Phase 2: lane-private scan over this half's 128 v ----
  float bw[16];
  int ba[16];
#pragma unroll
  for (int j = 0; j < 16; ++j) { bw[j] = 1e38f; ba[j] = 0; }

#pragma unroll
  for (int j = 0; j < 16; ++j) {
    int dt = (j << 2) + wv;           // 0..63
    int ks = dt + lane;               // row of C_s (s = t-64+lane)
    int kt = dt + 64;                 // row of C_t
    const float* rs = &CL[ks * 128];
    const float* rt = &CL[kt * 128];
    int ksm = ks & 31, ktm = kt & 31;
    float bv = bw[j];
    int bi = ba[j];
#pragma unroll 4
    for (int g = 0; g < 32; ++g) {
      float4 a = *(const float4*)&rs[(g ^ ksm) << 2];
      float4 t4 = *(const float4*)&rt[(g ^ ktm) << 2];
      int v0 = (g << 2);
      float s0 = t4.x - a.x; if (s0 < bv) { bv = s0; bi = v0; }
      float s1 = t4.y - a.y; if (s1 < bv) { bv = s1; bi = v0 + 1; }
      float s2 = t4.z - a.z; if (s2 < bv) { bv = s2; bi = v0 + 2; }
      float s3 = t4.w - a.w; if (s3 < bv) { bv = s3; bi = v0 + 3; }
    }
    bw[j] = bv; ba[j] = bi;
  }

  // per-t layout for prev_k
#pragma unroll
  for (int j = 0; j < 16; ++j) {
    int t = t1 + (j << 2) + wv;
    size_t idx = (((size_t)b * TT + (t - 1)) * 64 + lane) * 2 + half;
    Wv2[idx] = bw[j];
    WI2[idx] = (unsigned char)ba[j];   // v within half; half1 adds 128 at use
  }

  // ---- Phase 3: diagonal restage (reuse CL as ST[127][66]) ----
  __syncthreads();                     // all CL reads of phase 2 done
  float* ST = CL;
#pragma unroll
  for (int j = 0; j < 16; ++j) {
    int t_local = (j << 2) + wv;
    int srow = t_local + lane;         // 0..126 ; s = t1-64+srow
    ST[srow * 66 + (63 - lane)] = bw[j];
  }
  __syncthreads();
  {
    float* WTf = (float*)WT2;
    for (int q = 0; q < 32; ++q) {
      int rr = wv * 32 + q;
      if (rr > 126) break;             // row 127 doesn't exist
      int s = t1 - 64 + rr;
      if (s < 0) continue;
      int jlo = 63 - rr; if (jlo < 0) jlo = 0;
      int jhi = 126 - rr; if (jhi > 63) jhi = 63;
      int j = lane;
      if (j >= jlo && j <= jhi)
        WTf[(((size_t)b * TT + s) * 64 + j) * 2 + half] = ST[rr * 66 + j];
    }
  }
}

// ---------------------------------------------------------------------------
// Kernel 4a: sequential DP, scatter form, LDS-ring DMA pipeline. 1 wave/batch.
// ---------------------------------------------------------------------------
__global__ __launch_bounds__(64) void dp_seq(const float* __restrict__ WT,
                                             float* __restrict__ cg) {
  __shared__ __align__(16) float2 ring[128 * 64];   // 64 KB, 128 rows x 512B
  int b = blockIdx.x;
  int lane = threadIdx.x;
  const char* Wb = (const char*)WT + (size_t)b * TT * 512;  // 512B per row
  float* cgb = cg + (size_t)b * (TT + 1);
  if (lane == 0) cgb[0] = 0.f;

  auto stage2 = [&](int row) {
    const char* g = Wb + ((size_t)row << 9) + (lane << 4);
    float2* l = &ring[(row & 127) << 6];
    __builtin_amdgcn_global_load_lds((const unsigned int*)g, (unsigned int*)l, 16, 0, 0);
  };
  auto ldring = [&](int r) -> float2 {
    int rc = (r > TT - 1) ? (TT - 1) : r;
    return ring[((rc & 127) << 6) | ((lane - rc) & 63)];
  };

  for (int k = 0; k < 60; ++k) stage2(2 * k);
  asm volatile("s_waitcnt vmcnt(56)" ::: "memory");   // rows 0..7 ready
  float2 p0 = ldring(0), p1 = ldring(1), p2 = ldring(2), p3 = ldring(3);
  float2 p4 = ldring(4), p5 = ldring(5), p6 = ldring(6), p7 = ldring(7);

  float c = 0.f;
  float acc = DPINF;
  float ckeep = 0.f;

#define STEP(TAU, P) { \
    float wm = fminf((P).x, (P).y); \
    float cand = c + wm; \
    acc = fminf(acc, cand); \
    int fl = (TAU) & 63; \
    float cnew = __int_as_float(__builtin_amdgcn_readlane(__float_as_int(acc), fl)); \
    bool me = (lane == fl); \
    ckeep = me ? cnew : ckeep; \
    acc = me ? DPINF : acc; \
    c = cnew; }

  for (int gg = 0; gg < 16; ++gg) {
#pragma unroll
    for (int ii = 0; ii < 8; ++ii) {
      int tb = gg * 64 + ii * 8;
      if (tb <= 896) {
        asm volatile("s_waitcnt vmcnt(52)" ::: "memory");
        stage2(tb + 120); stage2(tb + 122); stage2(tb + 124); stage2(tb + 126);
      } else if (tb == 904) {
        asm volatile("s_waitcnt vmcnt(0)" ::: "memory");
      }
      STEP(tb + 0, p0); p0 = ldring(tb + 8);
      STEP(tb + 1, p1); p1 = ldring(tb + 9);
      STEP(tb + 2, p2); p2 = ldring(tb + 10);
      STEP(tb + 3, p3); p3 = ldring(tb + 11);
      STEP(tb + 4, p4); p4 = ldring(tb + 12);
      STEP(tb + 5, p5); p5 = ldring(tb + 13);
      STEP(tb + 6, p6); p6 = ldring(tb + 14);
      STEP(tb + 7, p7); p7 = ldring(tb + 15);
    }
    cgb[gg * 64 + 1 + lane] = ckeep;
  }
#undef STEP
}

// ---------------------------------------------------------------------------
// Kernel 4b: parallel argmin. One wave per t: recompute total = cg[s]+W[t][i],
// find first-min -> prev, tok. Half-combine: min value, half0 wins ties.
// ---------------------------------------------------------------------------
__global__ __launch_bounds__(256) void prev_k(const float* __restrict__ Wv2,
                                              const unsigned char* __restrict__ WI2,
                                              const float* __restrict__ cg,
                                              int* __restrict__ pk) {
  int row = blockIdx.x * 4 + (threadIdx.x >> 6);   // row in [0, BB*TT)
  int lane = threadIdx.x & 63;
  int b = row >> 10;
  int t = (row & 1023) + 1;
  int s = t - 64 + lane;
  size_t idx = (size_t)row * 64 + lane;
  float2 w2 = ((const float2*)Wv2)[idx];
  uchar2 i2 = ((const uchar2*)WI2)[idx];
  bool h0 = (w2.x <= w2.y);
  float w = h0 ? w2.x : w2.y;
  int wi = h0 ? (int)i2.x : ((int)i2.y + 128);
  int sc = (s < 0) ? 0 : s;
  float c = cg[(size_t)b * (TT + 1) + sc];
  float total = (s >= 0) ? (c + w) : DPINF;
  float m = total;
  DPP_MIN_REDUCE(m);
  float mf = __int_as_float(__builtin_amdgcn_readlane(__float_as_int(m), 63));
  unsigned long long msk = __ballot(total == mf);
  int iwin = __builtin_ctzll(msk);                 // smallest i = smallest s
  int tok = __builtin_amdgcn_readlane(wi, iwin) & 255;
  int prev = t - 64 + iwin;
  if (lane == 0) pk[(size_t)b * (TT + 1) + t] = (prev << 8) | tok;
}

// ---------------------------------------------------------------------------
// Kernel 4c: backtrack via parallel pointer-doubling (binary lifting).
// Round-8 post-mortem: serial lane-0 walk = up to 1024 dependent ~120cy LDS
// reads = 60us. Now: J[k][t] = f^(2^k)(t) built in 10 parallel levels
// (1025 independent lookups each, 64-lane pipelined); cnt via one 10-hop
// binary descent; each output position j computes f^(cnt-1-j)(len) with
// <=10 hops, 64 parallel chains, ILP across 4 positions/lane.
// Outputs identical to the serial walk (same f, same indices).
// ---------------------------------------------------------------------------
__global__ __launch_bounds__(64) void bt_k(const int* __restrict__ pk,
                                           const float* __restrict__ cg,
                                           const int* __restrict__ lengths,
                                           float* __restrict__ out) {
  __shared__ ushort J[10][TT + 1];
  __shared__ unsigned char tk[TT + 1];
  int b = blockIdx.x;
  int lane = threadIdx.x;
  const int* pb = pk + (size_t)b * (TT + 1);

  // level 0 (prev) + tokens; f(0) = 0
  for (int t = lane; t <= TT; t += 64) {
    int e = (t == 0) ? 0 : pb[t];
    J[0][t] = (ushort)(e >> 8);
    tk[t] = (unsigned char)(e & 255);
  }
  __syncthreads();
#pragma unroll
  for (int k = 0; k < 9; ++k) {
    for (int t = lane; t <= TT; t += 64)
      J[k + 1][t] = J[k][J[k][t]];
    __syncthreads();
  }

  int len = lengths[b];
  len = (len > TT) ? TT : (len < 0 ? 0 : len);

  // cnt = depth(len): largest m with f^m(len)!=0, then cnt = m+1; len==0 -> 0
  int cnt = 0;
  if (len > 0) {
    int cur = len, m = 0;
#pragma unroll
    for (int k = 9; k >= 0; --k) {
      int nxt = J[k][cur];
      if (nxt != 0) { cur = nxt; m += (1 << k); }
    }
    cnt = m + 1;
  }

  float* bout = out + b * TT;
  float* tout = out + MM + b * TT;
#pragma unroll 4
  for (int j0 = 0; j0 < TT; j0 += 64) {
    int j = j0 + lane;
    int node = 0;
    if (j < cnt) {
      int steps = cnt - 1 - j;          // node = f^steps(len)
      int cur = len;
#pragma unroll
      for (int k = 9; k >= 0; --k)
        if ((steps >> k) & 1) cur = J[k][cur];
      node = cur;
    }
    bout[j] = (float)node;
    tout[j] = (j < cnt) ? (float)tk[node] : 0.f;
  }
  if (lane == 0) {
    out[2 * MM + b] = (float)cnt;
    out[2 * MM + BB + b] = cg[(size_t)b * (TT + 1) + len];
  }
}

// ---------------------------------------------------------------------------
extern "C" void kernel_launch(void* const* d_in, const int* in_sizes, int n_in,
                              void* d_out, int out_size, void* d_ws, size_t ws_size,
                              hipStream_t stream) {
  const float* reps = (const float*)d_in[0];
  const float* cb   = (const float*)d_in[1];
  const int* lengths = (const int*)d_in[2];
  float* out = (float*)d_out;

  char* ws = (char*)d_ws;
  float* r2 = (float*)ws;                                    // 64 KB
  float* c2 = (float*)(ws + 65536);                          // 4 KB slot
  char* p = ws + 69632;
  float* dmat = (float*)p;               p += (size_t)MM * VV * 4;       // 16 MB
  float* Wv2  = (float*)p;               p += (size_t)MM * 128 * 4;      // 8 MB
  unsigned char* WI2 = (unsigned char*)p; p += (size_t)MM * 128;         // 2 MB
  float2* WT2 = (float2*)p;              p += (size_t)MM * 64 * 8;       // 8 MB
  float* cg   = (float*)p;               p += (size_t)BB * (TT + 1) * 4; // 65.6 KB
  int* pk     = (int*)p;                 p += (size_t)BB * (TT + 1) * 4; // 65.6 KB
  ushort* cbb = (ushort*)p;                                              // 256 KB
  // repsb (16.8 MB) aliases Wv2/WI2 region: dead before w_k writes them
  ushort* repsb = (ushort*)Wv2;

  norms_k<<<(MM + VV) / 4, 256, 0, stream>>>(reps, cb, r2, c2, repsb, cbb);
  gemm_k<<<dim3(MM / 64, VV / 64), 256, 0, stream>>>(repsb, cbb, r2, c2, dmat);
  w_k<<<BB * (TT / 64) * 2, 256, 0, stream>>>(dmat, Wv2, WI2, WT2);
  dp_seq<<<BB, 64, 0, stream>>>((const float*)WT2, cg);
  prev_k<<<MM / 4, 256, 0, stream>>>(Wv2, WI2, cg, pk);
  bt_k<<<BB, 64, 0, stream>>>(pk, cg, lengths, out);
}

// Round 10
// 156.961 us; speedup vs baseline: 3.0141x; 1.0053x over previous
//
#include <hip/hip_runtime.h>

#define BB 16
#define TT 1024
#define DD 512
#define VV 256
#define MM (BB*TT)

#define DPINF 1e30f

typedef __attribute__((ext_vector_type(8))) short bf16x8;
typedef __attribute__((ext_vector_type(4))) float f32x4;

// DPP min-reduce step; old = same reg -> identity for lanes with no source
#define DPP_MIN_STEP(m, CTRL) { \
  int _t = __builtin_amdgcn_update_dpp(__float_as_int(m), __float_as_int(m), CTRL, 0xF, 0xF, false); \
  m = fminf(m, __int_as_float(_t)); }

// full 64-lane min into lane 63: row_shr 1,2,4,8 then row_bcast15, row_bcast31
#define DPP_MIN_REDUCE(m) \
  DPP_MIN_STEP(m, 0x111); DPP_MIN_STEP(m, 0x112); DPP_MIN_STEP(m, 0x114); \
  DPP_MIN_STEP(m, 0x118); DPP_MIN_STEP(m, 0x142); DPP_MIN_STEP(m, 0x143);

// ---------------------------------------------------------------------------
// Kernel 1: row norms + RNE fp32->bf16 conversion (repsb aliases WQ region).
// ---------------------------------------------------------------------------
__global__ __launch_bounds__(256) void norms_k(const float* __restrict__ reps,
                                               const float* __restrict__ cb,
                                               float* __restrict__ r2,
                                               float* __restrict__ c2,
                                               ushort* __restrict__ repsb,
                                               ushort* __restrict__ cbb) {
  int row = blockIdx.x * 4 + (threadIdx.x >> 6);
  int lane = threadIdx.x & 63;
  const float* src;
  float* dst;
  ushort* bdst;
  if (row < MM) {
    src = reps + (size_t)row * DD;
    dst = r2 + row;
    bdst = repsb + (size_t)row * DD;
  } else {
    int r = row - MM;
    if (r >= VV) return;
    src = cb + (size_t)r * DD;
    dst = c2 + r;
    bdst = cbb + (size_t)r * DD;
  }
  const float4* s4 = (const float4*)src;
  float4 a = s4[lane];
  float4 b = s4[lane + 64];

  auto cvt = [](float x) -> ushort {
    unsigned u = __float_as_uint(x);
    return (ushort)((u + 0x7FFFu + ((u >> 16) & 1u)) >> 16);   // RNE
  };
  ushort4 ua = make_ushort4(cvt(a.x), cvt(a.y), cvt(a.z), cvt(a.w));
  ushort4 ub = make_ushort4(cvt(b.x), cvt(b.y), cvt(b.z), cvt(b.w));
  *(ushort4*)&bdst[lane * 4] = ua;
  *(ushort4*)&bdst[256 + lane * 4] = ub;

  float s = a.x*a.x + a.y*a.y + a.z*a.z + a.w*a.w
          + b.x*b.x + b.y*b.y + b.z*b.z + b.w*b.w;
#pragma unroll
  for (int off = 1; off < 64; off <<= 1) s += __shfl_xor(s, off);
  if (lane == 0) *dst = s;
}

// ---------------------------------------------------------------------------
// Kernel 2: d[m][v] via bf16 MFMA (unchanged from round 9).
// ---------------------------------------------------------------------------
__global__ __launch_bounds__(256) void gemm_k(const ushort* __restrict__ repsb,
                                              const ushort* __restrict__ cbb,
                                              const float* __restrict__ r2,
                                              const float* __restrict__ c2,
                                              float* __restrict__ dmat) {
  __shared__ short Ab[2][4096];
  __shared__ short Bb[2][4096];
  int tid = threadIdx.x;
  int w = tid >> 6, l = tid & 63;
  int m0 = blockIdx.x * 64, v0 = blockIdx.y * 64;

  int srow = l >> 3;
  int scol = ((l & 7) << 4) ^ (srow << 4);

  auto stage = [&](int buf, int kc) {
#pragma unroll
    for (int ii = 0; ii < 2; ++ii) {
      int instr = w + ii * 4;
      int row = instr * 8 + srow;
      const char* ga = (const char*)repsb + ((size_t)(m0 + row) * DD + kc * 64) * 2 + scol;
      __builtin_amdgcn_global_load_lds((const unsigned int*)ga,
                                       (unsigned int*)&Ab[buf][instr * 512], 16, 0, 0);
      const char* gb = (const char*)cbb + ((size_t)(v0 + row) * DD + kc * 64) * 2 + scol;
      __builtin_amdgcn_global_load_lds((const unsigned int*)gb,
                                       (unsigned int*)&Bb[buf][instr * 512], 16, 0, 0);
    }
  };

  int fr = l & 15;
  int fq = l >> 4;
  int swz = (fr & 7) << 3;

  f32x4 acc0 = {0.f,0.f,0.f,0.f}, acc1 = {0.f,0.f,0.f,0.f};
  f32x4 acc2 = {0.f,0.f,0.f,0.f}, acc3 = {0.f,0.f,0.f,0.f};

  stage(0, 0);
  int cur = 0;
  for (int kc = 0; kc < 8; ++kc) {
    if (kc < 7) {
      stage(cur ^ 1, kc + 1);
      asm volatile("s_waitcnt vmcnt(4)" ::: "memory");
    } else {
      asm volatile("s_waitcnt vmcnt(0)" ::: "memory");
    }
    __syncthreads();
#pragma unroll
    for (int ks = 0; ks < 2; ++ks) {
      int koff = (ks * 32 + fq * 8) ^ swz;
      bf16x8 av = *(const bf16x8*)&Ab[cur][(w * 16 + fr) * 64 + koff];
      bf16x8 b0 = *(const bf16x8*)&Bb[cur][(0 * 16 + fr) * 64 + koff];
      bf16x8 b1 = *(const bf16x8*)&Bb[cur][(1 * 16 + fr) * 64 + koff];
      bf16x8 b2 = *(const bf16x8*)&Bb[cur][(2 * 16 + fr) * 64 + koff];
      bf16x8 b3 = *(const bf16x8*)&Bb[cur][(3 * 16 + fr) * 64 + koff];
      acc0 = __builtin_amdgcn_mfma_f32_16x16x32_bf16(av, b0, acc0, 0, 0, 0);
      acc1 = __builtin_amdgcn_mfma_f32_16x16x32_bf16(av, b1, acc1, 0, 0, 0);
      acc2 = __builtin_amdgcn_mfma_f32_16x16x32_bf16(av, b2, acc2, 0, 0, 0);
      acc3 = __builtin_amdgcn_mfma_f32_16x16x32_bf16(av, b3, acc3, 0, 0, 0);
    }
    __syncthreads();
    cur ^= 1;
  }

  float rv[4];
#pragma unroll
  for (int r = 0; r < 4; ++r) rv[r] = r2[m0 + w * 16 + fq * 4 + r];
#pragma unroll
  for (int vt = 0; vt < 4; ++vt) {
    f32x4 a = (vt == 0) ? acc0 : (vt == 1) ? acc1 : (vt == 2) ? acc2 : acc3;
    int v = v0 + vt * 16 + fr;
    float cc = c2[v];
#pragma unroll
    for (int r = 0; r < 4; ++r) {
      int m = m0 + w * 16 + fq * 4 + r;
      dmat[(size_t)m * VV + v] = fmaf(-2.f, a[r], rv[r] + cc);
    }
  }
}

// ---------------------------------------------------------------------------
// Kernel 3: W computation, v-QUARTER blocks (64 v), 4 blocks/CU.
// Phase 1: parallel window cumsum (16 chunks x 8 frames) into CL (swizzled).
// Phase 2: diagonal pair scan; C_t row held in regs (1 f32/lane), values
//   broadcast via v_readlane imm -> only C_s needs ds_read_b128.
// Phase 3: pack key = (bits&~0xFF)|q<<6|v, restage via ST[jcol][srow]
//   (stride 127), write quarter-interleaved key plane WQ[s][q][j] coalesced.
// ---------------------------------------------------------------------------
__global__ __launch_bounds__(256, 4) void w_k(const float* __restrict__ dmat,
                                              float* __restrict__ WQ) {
  __shared__ __align__(16) float CL[128 * 64];   // 32KB
  __shared__ __align__(16) float TOT[16 * 64];   // 4KB
  int bx = blockIdx.x;
  int b = bx >> 6;
  int chunk = (bx >> 2) & 15;
  int q = bx & 3;
  int t1 = 1 + (chunk << 6);
  int tid = threadIdx.x;
  int wv = tid >> 6, lane = tid & 63;

  // ---- Phase 1 ----
  {
    int c = tid >> 4;          // 0..15 (8 frames each)
    int g = tid & 15;          // f4-group within quarter
    const float* base = dmat + (size_t)b * TT * VV + q * 64 + (g << 2);
    float4 rr[8];
    float4 run = make_float4(0.f, 0.f, 0.f, 0.f);
#pragma unroll
    for (int jj = 1; jj <= 8; ++jj) {
      int k = (c << 3) + jj;
      int f = t1 - 64 + k;
      bool valid = (k <= 127) && (f >= 1) && (f <= TT);
      int fc = valid ? f : 1;
      float4 dv = *(const float4*)(base + (size_t)(fc - 1) * VV);
      if (!valid) dv = make_float4(0.f, 0.f, 0.f, 0.f);
      run.x += dv.x; run.y += dv.y; run.z += dv.z; run.w += dv.w;
      rr[jj - 1] = run;
    }
    *(float4*)&TOT[(c << 6) + (g << 2)] = run;
    if (c == 0) *(float4*)&CL[(g << 2)] = make_float4(0.f, 0.f, 0.f, 0.f);  // row 0
    __syncthreads();
    float4 off = make_float4(0.f, 0.f, 0.f, 0.f);
#pragma unroll
    for (int cc = 0; cc < 15; ++cc) {
      if (cc < c) {
        float4 tv = *(const float4*)&TOT[(cc << 6) + (g << 2)];
        off.x += tv.x; off.y += tv.y; off.z += tv.z; off.w += tv.w;
      }
    }
#pragma unroll
    for (int jj = 1; jj <= 8; ++jj) {
      int k = (c << 3) + jj;
      if (k <= 127) {
        float4 s = rr[jj - 1];
        s.x += off.x; s.y += off.y; s.z += off.z; s.w += off.w;
        *(float4*)&CL[(k << 6) + ((g ^ (k & 15)) << 2)] = s;
      }
    }
  }
  __syncthreads();

  // ---- Phase 2 ----
  float bw[16];
  int ba[16];
#pragma unroll
  for (int j = 0; j < 16; ++j) { bw[j] = 1e38f; ba[j] = 0; }

#pragma unroll
  for (int j = 0; j < 16; ++j) {
    int dt = (j << 2) + wv;
    int ks = dt + lane;               // C_s row for this lane's pair
    int kt = dt + 64;                 // C_t row (wave-uniform)
    // lane l holds C_t[v=l] (one ds_read_b32, conflict-free)
    int rti = __float_as_int(CL[(kt << 6) + (((lane >> 2) ^ (kt & 15)) << 2) + (lane & 3)]);
    int ksm = ks & 15;
    const float* rs = &CL[ks << 6];
    float bv = bw[j];
    int bi = ba[j];
#pragma unroll
    for (int g = 0; g < 16; ++g) {
      float4 a = *(const float4*)&rs[(g ^ ksm) << 2];
      int v0 = g << 2;
      float t0 = __int_as_float(__builtin_amdgcn_readlane(rti, v0));
      float t1v = __int_as_float(__builtin_amdgcn_readlane(rti, v0 + 1));
      float t2 = __int_as_float(__builtin_amdgcn_readlane(rti, v0 + 2));
      float t3 = __int_as_float(__builtin_amdgcn_readlane(rti, v0 + 3));
      float s0 = t0 - a.x;  if (s0 < bv) { bv = s0; bi = v0; }
      float s1 = t1v - a.y; if (s1 < bv) { bv = s1; bi = v0 + 1; }
      float s2 = t2 - a.z;  if (s2 < bv) { bv = s2; bi = v0 + 2; }
      float s3 = t3 - a.w;  if (s3 < bv) { bv = s3; bi = v0 + 3; }
    }
    bw[j] = bv; ba[j] = bi;
  }

  // ---- Phase 3: pack + restage (reuse CL as ST[jcol 0..63][srow 0..126]) ----
  __syncthreads();
  float* ST = CL;
#pragma unroll
  for (int j = 0; j < 16; ++j) {
    int dt = (j << 2) + wv;
    int srow = dt + lane;             // 0..126
    int key = (__float_as_int(bw[j]) & 0xFFFFFF00) | (q << 6) | ba[j];
    ST[(63 - lane) * 127 + srow] = __int_as_float(key);
  }
  __syncthreads();
  {
    float* Wb = WQ + (size_t)b * TT * 256 + q * 64;   // + s*256 + j
    for (int qq = 0; qq < 32; ++qq) {
      int rr = wv * 32 + qq;
      if (rr > 126) break;
      int s = t1 - 64 + rr;
      if (s < 0) continue;
      int jlo = 63 - rr; if (jlo < 0) jlo = 0;
      int jhi = 126 - rr; if (jhi > 63) jhi = 63;
      int j = lane;
      if (j >= jlo && j <= jhi)
        Wb[(size_t)s * 256 + j] = ST[j * 127 + rr];
    }
  }
}

// ---------------------------------------------------------------------------
// Kernel 4a: sequential DP, scatter form; LDS ring of 64 x 1KB rows (one DMA
// per s-row = all 4 quarter-keys contiguous); fold min-of-4 in the prefetch
// (off the critical chain). Chain/step: add -> min -> readlane -> cndmask.
// ---------------------------------------------------------------------------
__global__ __launch_bounds__(64) void dp_seq(const float* __restrict__ WQ,
                                             float* __restrict__ cg) {
  __shared__ __align__(16) float ring[64 * 256];   // 64KB
  int b = blockIdx.x;
  int lane = threadIdx.x;
  const char* Wb = (const char*)(WQ + (size_t)b * TT * 256);
  float* cgb = cg + (size_t)b * (TT + 1);
  if (lane == 0) cgb[0] = 0.f;

  auto stage = [&](int r) {    // 1KB: row r, all quarters
    const char* g = Wb + ((size_t)r << 10) + (lane << 4);
    __builtin_amdgcn_global_load_lds((const unsigned int*)g,
                                     (unsigned int*)&ring[(r & 63) << 8], 16, 0, 0);
  };
  auto ldring = [&](int r) -> float {
    int rc = (r > TT - 1) ? (TT - 1) : r;
    int base = ((rc & 63) << 8) | ((lane - rc) & 63);
    float k0 = ring[base], k1 = ring[base + 64];
    float k2 = ring[base + 128], k3 = ring[base + 192];
    return fminf(fminf(k0, k1), fminf(k2, k3));
  };

  for (int k = 0; k < 56; ++k) stage(k);
  asm volatile("s_waitcnt vmcnt(48)" ::: "memory");   // rows 0..7 ready
  float p0 = ldring(0), p1 = ldring(1), p2 = ldring(2), p3 = ldring(3);
  float p4 = ldring(4), p5 = ldring(5), p6 = ldring(6), p7 = ldring(7);

  float c = 0.f;
  float acc = DPINF;
  float ckeep = 0.f;

#define STEP(TAU, P) { \
    float cand = c + (P); \
    acc = fminf(acc, cand); \
    int fl = (TAU) & 63; \
    float cnew = __int_as_float(__builtin_amdgcn_readlane(__float_as_int(acc), fl)); \
    bool me = (lane == fl); \
    ckeep = me ? cnew : ckeep; \
    acc = me ? DPINF : acc; \
    c = cnew; }

  for (int gg = 0; gg < 16; ++gg) {
#pragma unroll
    for (int ii = 0; ii < 8; ++ii) {
      int tb = gg * 64 + ii * 8;
      if (tb <= 960) {
        // issued = 56+tb; need rows <= tb+15 -> completed >= tb+16 -> vmcnt(40)
        asm volatile("s_waitcnt vmcnt(40)" ::: "memory");
        stage(tb + 56); stage(tb + 57); stage(tb + 58); stage(tb + 59);
        stage(tb + 60); stage(tb + 61); stage(tb + 62); stage(tb + 63);
      } else if (tb == 968) {
        asm volatile("s_waitcnt vmcnt(0)" ::: "memory");
      }
      STEP(tb + 0, p0); p0 = ldring(tb + 8);
      STEP(tb + 1, p1); p1 = ldring(tb + 9);
      STEP(tb + 2, p2); p2 = ldring(tb + 10);
      STEP(tb + 3, p3); p3 = ldring(tb + 11);
      STEP(tb + 4, p4); p4 = ldring(tb + 12);
      STEP(tb + 5, p5); p5 = ldring(tb + 13);
      STEP(tb + 6, p6); p6 = ldring(tb + 14);
      STEP(tb + 7, p7); p7 = ldring(tb + 15);
    }
    cgb[gg * 64 + 1 + lane] = ckeep;
  }
#undef STEP
}

// ---------------------------------------------------------------------------
// Kernel 4b: parallel argmin, chunked+staged. Block = (b, 64-t chunk):
// stage+fold 127 coalesced key-rows into WL, then per t: lane i -> antidiag
// cell, total = cg[s]+key (bit-identical to dp_seq), DPP min + ballot.
// token = key & 255 (global v). prev = smallest-s achiever.
// ---------------------------------------------------------------------------
__global__ __launch_bounds__(256) void prev_k(const float* __restrict__ WQ,
                                              const float* __restrict__ cg,
                                              int* __restrict__ pk) {
  __shared__ float WL[127 * 64];   // 32KB folded keys
  int bx = blockIdx.x;
  int b = bx >> 4;
  int chunk = bx & 15;
  int t0 = chunk << 6;
  int tid = threadIdx.x;
  int wv = tid >> 6, lane = tid & 63;

  const float* Wb = WQ + (size_t)b * TT * 256;
  for (int cidx = tid; cidx < 127 * 64; cidx += 256) {
    int row = cidx >> 6, j = cidx & 63;
    long s = (long)(t0 - 63 + row);            // may be <0 (garbage, masked later)
    const float* cell = Wb + s * 256 + j;
    float k0 = cell[0], k1 = cell[64], k2 = cell[128], k3 = cell[192];
    WL[cidx] = fminf(fminf(k0, k1), fminf(k2, k3));
  }
  __syncthreads();

  const float* cgb = cg + (size_t)b * (TT + 1);
#pragma unroll
  for (int u = 0; u < 16; ++u) {
    int tt = wv * 16 + u;
    int t = t0 + 1 + tt;
    int i = lane;
    int s = t - 64 + i;
    float wkey = WL[(tt + i) * 64 + (63 - i)];
    int sc = (s < 0) ? 0 : s;
    float total = (s >= 0) ? (cgb[sc] + wkey) : DPINF;
    float m = total;
    DPP_MIN_REDUCE(m);
    float mf = __int_as_float(__builtin_amdgcn_readlane(__float_as_int(m), 63));
    unsigned long long msk = __ballot(total == mf);
    int iwin = __builtin_ctzll(msk);            // smallest i = smallest s
    int tok = __builtin_amdgcn_readlane(__float_as_int(wkey), iwin) & 255;
    int prev = t - 64 + iwin;
    if (lane == 0) pk[(size_t)b * (TT + 1) + t] = (prev << 8) | tok;
  }
}

// ---------------------------------------------------------------------------
// Kernel 4c: backtrack via binary lifting (unchanged from round 9).
// ---------------------------------------------------------------------------
__global__ __launch_bounds__(64) void bt_k(const int* __restrict__ pk,
                                           const float* __restrict__ cg,
                                           const int* __restrict__ lengths,
                                           float* __restrict__ out) {
  __shared__ ushort J[10][TT + 1];
  __shared__ unsigned char tk[TT + 1];
  int b = blockIdx.x;
  int lane = threadIdx.x;
  const int* pb = pk + (size_t)b * (TT + 1);

  for (int t = lane; t <= TT; t += 64) {
    int e = (t == 0) ? 0 : pb[t];
    J[0][t] = (ushort)(e >> 8);
    tk[t] = (unsigned char)(e & 255);
  }
  __syncthreads();
#pragma unroll
  for (int k = 0; k < 9; ++k) {
    for (int t = lane; t <= TT; t += 64)
      J[k + 1][t] = J[k][J[k][t]];
    __syncthreads();
  }

  int len = lengths[b];
  len = (len > TT) ? TT : (len < 0 ? 0 : len);

  int cnt = 0;
  if (len > 0) {
    int cur = len, m = 0;
#pragma unroll
    for (int k = 9; k >= 0; --k) {
      int nxt = J[k][cur];
      if (nxt != 0) { cur = nxt; m += (1 << k); }
    }
    cnt = m + 1;
  }

  float* bout = out + b * TT;
  float* tout = out + MM + b * TT;
#pragma unroll 4
  for (int j0 = 0; j0 < TT; j0 += 64) {
    int j = j0 + lane;
    int node = 0;
    if (j < cnt) {
      int steps = cnt - 1 - j;
      int cur = len;
#pragma unroll
      for (int k = 9; k >= 0; --k)
        if ((steps >> k) & 1) cur = J[k][cur];
      node = cur;
    }
    bout[j] = (float)node;
    tout[j] = (j < cnt) ? (float)tk[node] : 0.f;
  }
  if (lane == 0) {
    out[2 * MM + b] = (float)cnt;
    out[2 * MM + BB + b] = cg[(size_t)b * (TT + 1) + len];
  }
}

// ---------------------------------------------------------------------------
extern "C" void kernel_launch(void* const* d_in, const int* in_sizes, int n_in,
                              void* d_out, int out_size, void* d_ws, size_t ws_size,
                              hipStream_t stream) {
  const float* reps = (const float*)d_in[0];
  const float* cb   = (const float*)d_in[1];
  const int* lengths = (const int*)d_in[2];
  float* out = (float*)d_out;

  char* ws = (char*)d_ws;
  float* r2 = (float*)ws;                                    // 64 KB
  float* c2 = (float*)(ws + 65536);                          // 4 KB slot
  char* p = ws + 69632;
  float* dmat = (float*)p;               p += (size_t)MM * VV * 4;       // 16 MB
  float* WQ   = (float*)p;               p += (size_t)MM * 256 * 4;      // 16.78 MB
  float* cg   = (float*)p;               p += (size_t)BB * (TT + 1) * 4; // 65.6 KB
  int* pk     = (int*)p;                 p += (size_t)BB * (TT + 1) * 4; // 65.6 KB
  ushort* cbb = (ushort*)p;                                              // 256 KB
  // repsb (16.78 MB) aliases WQ exactly: dead before w_k writes it
  ushort* repsb = (ushort*)WQ;

  norms_k<<<(MM + VV) / 4, 256, 0, stream>>>(reps, cb, r2, c2, repsb, cbb);
  gemm_k<<<dim3(MM / 64, VV / 64), 256, 0, stream>>>(repsb, cbb, r2, c2, dmat);
  w_k<<<BB * 16 * 4, 256, 0, stream>>>(dmat, WQ);
  dp_seq<<<BB, 64, 0, stream>>>(WQ, cg);
  prev_k<<<BB * 16, 256, 0, stream>>>(WQ, cg, pk);
  bt_k<<<BB, 64, 0, stream>>>(pk, cg, lengths, out);
}

// Round 11
// 143.480 us; speedup vs baseline: 3.2973x; 1.0940x over previous
//
#include <hip/hip_runtime.h>

#define BB 16
#define TT 1024
#define DD 512
#define VV 256
#define MM (BB*TT)

#define DPINF 1e30f

typedef __attribute__((ext_vector_type(8))) short bf16x8;
typedef __attribute__((ext_vector_type(4))) float f32x4;

// DPP min-reduce step; old = same reg -> identity for lanes with no source
#define DPP_MIN_STEP(m, CTRL) { \
  int _t = __builtin_amdgcn_update_dpp(__float_as_int(m), __float_as_int(m), CTRL, 0xF, 0xF, false); \
  m = fminf(m, __int_as_float(_t)); }

// full 64-lane min into lane 63: row_shr 1,2,4,8 then row_bcast15, row_bcast31
#define DPP_MIN_REDUCE(m) \
  DPP_MIN_STEP(m, 0x111); DPP_MIN_STEP(m, 0x112); DPP_MIN_STEP(m, 0x114); \
  DPP_MIN_STEP(m, 0x118); DPP_MIN_STEP(m, 0x142); DPP_MIN_STEP(m, 0x143);

// ---------------------------------------------------------------------------
// Kernel 1: row norms + RNE fp32->bf16 conversion (repsb aliases WQ region).
// ---------------------------------------------------------------------------
__global__ __launch_bounds__(256) void norms_k(const float* __restrict__ reps,
                                               const float* __restrict__ cb,
                                               float* __restrict__ r2,
                                               float* __restrict__ c2,
                                               ushort* __restrict__ repsb,
                                               ushort* __restrict__ cbb) {
  int row = blockIdx.x * 4 + (threadIdx.x >> 6);
  int lane = threadIdx.x & 63;
  const float* src;
  float* dst;
  ushort* bdst;
  if (row < MM) {
    src = reps + (size_t)row * DD;
    dst = r2 + row;
    bdst = repsb + (size_t)row * DD;
  } else {
    int r = row - MM;
    if (r >= VV) return;
    src = cb + (size_t)r * DD;
    dst = c2 + r;
    bdst = cbb + (size_t)r * DD;
  }
  const float4* s4 = (const float4*)src;
  float4 a = s4[lane];
  float4 b = s4[lane + 64];

  auto cvt = [](float x) -> ushort {
    unsigned u = __float_as_uint(x);
    return (ushort)((u + 0x7FFFu + ((u >> 16) & 1u)) >> 16);   // RNE
  };
  ushort4 ua = make_ushort4(cvt(a.x), cvt(a.y), cvt(a.z), cvt(a.w));
  ushort4 ub = make_ushort4(cvt(b.x), cvt(b.y), cvt(b.z), cvt(b.w));
  *(ushort4*)&bdst[lane * 4] = ua;
  *(ushort4*)&bdst[256 + lane * 4] = ub;

  float s = a.x*a.x + a.y*a.y + a.z*a.z + a.w*a.w
          + b.x*b.x + b.y*b.y + b.z*b.z + b.w*b.w;
#pragma unroll
  for (int off = 1; off < 64; off <<= 1) s += __shfl_xor(s, off);
  if (lane == 0) *dst = s;
}

// ---------------------------------------------------------------------------
// Kernel 2: d[m][v] via bf16 MFMA (unchanged).
// ---------------------------------------------------------------------------
__global__ __launch_bounds__(256) void gemm_k(const ushort* __restrict__ repsb,
                                              const ushort* __restrict__ cbb,
                                              const float* __restrict__ r2,
                                              const float* __restrict__ c2,
                                              float* __restrict__ dmat) {
  __shared__ short Ab[2][4096];
  __shared__ short Bb[2][4096];
  int tid = threadIdx.x;
  int w = tid >> 6, l = tid & 63;
  int m0 = blockIdx.x * 64, v0 = blockIdx.y * 64;

  int srow = l >> 3;
  int scol = ((l & 7) << 4) ^ (srow << 4);

  auto stage = [&](int buf, int kc) {
#pragma unroll
    for (int ii = 0; ii < 2; ++ii) {
      int instr = w + ii * 4;
      int row = instr * 8 + srow;
      const char* ga = (const char*)repsb + ((size_t)(m0 + row) * DD + kc * 64) * 2 + scol;
      __builtin_amdgcn_global_load_lds((const unsigned int*)ga,
                                       (unsigned int*)&Ab[buf][instr * 512], 16, 0, 0);
      const char* gb = (const char*)cbb + ((size_t)(v0 + row) * DD + kc * 64) * 2 + scol;
      __builtin_amdgcn_global_load_lds((const unsigned int*)gb,
                                       (unsigned int*)&Bb[buf][instr * 512], 16, 0, 0);
    }
  };

  int fr = l & 15;
  int fq = l >> 4;
  int swz = (fr & 7) << 3;

  f32x4 acc0 = {0.f,0.f,0.f,0.f}, acc1 = {0.f,0.f,0.f,0.f};
  f32x4 acc2 = {0.f,0.f,0.f,0.f}, acc3 = {0.f,0.f,0.f,0.f};

  stage(0, 0);
  int cur = 0;
  for (int kc = 0; kc < 8; ++kc) {
    if (kc < 7) {
      stage(cur ^ 1, kc + 1);
      asm volatile("s_waitcnt vmcnt(4)" ::: "memory");
    } else {
      asm volatile("s_waitcnt vmcnt(0)" ::: "memory");
    }
    __syncthreads();
#pragma unroll
    for (int ks = 0; ks < 2; ++ks) {
      int koff = (ks * 32 + fq * 8) ^ swz;
      bf16x8 av = *(const bf16x8*)&Ab[cur][(w * 16 + fr) * 64 + koff];
      bf16x8 b0 = *(const bf16x8*)&Bb[cur][(0 * 16 + fr) * 64 + koff];
      bf16x8 b1 = *(const bf16x8*)&Bb[cur][(1 * 16 + fr) * 64 + koff];
      bf16x8 b2 = *(const bf16x8*)&Bb[cur][(2 * 16 + fr) * 64 + koff];
      bf16x8 b3 = *(const bf16x8*)&Bb[cur][(3 * 16 + fr) * 64 + koff];
      acc0 = __builtin_amdgcn_mfma_f32_16x16x32_bf16(av, b0, acc0, 0, 0, 0);
      acc1 = __builtin_amdgcn_mfma_f32_16x16x32_bf16(av, b1, acc1, 0, 0, 0);
      acc2 = __builtin_amdgcn_mfma_f32_16x16x32_bf16(av, b2, acc2, 0, 0, 0);
      acc3 = __builtin_amdgcn_mfma_f32_16x16x32_bf16(av, b3, acc3, 0, 0, 0);
    }
    __syncthreads();
    cur ^= 1;
  }

  float rv[4];
#pragma unroll
  for (int r = 0; r < 4; ++r) rv[r] = r2[m0 + w * 16 + fq * 4 + r];
#pragma unroll
  for (int vt = 0; vt < 4; ++vt) {
    f32x4 a = (vt == 0) ? acc0 : (vt == 1) ? acc1 : (vt == 2) ? acc2 : acc3;
    int v = v0 + vt * 16 + fr;
    float cc = c2[v];
#pragma unroll
    for (int r = 0; r < 4; ++r) {
      int m = m0 + w * 16 + fq * 4 + r;
      dmat[(size_t)m * VV + v] = fmaf(-2.f, a[r], rv[r] + cc);
    }
  }
}

// ---------------------------------------------------------------------------
// Kernel 3: W values only (NO argmin tracking — tokens recovered by tok_k).
// v-quarter blocks (64 v), 4 blocks/CU. Phase 2 inner: 4 readlane + 4 sub +
// 4 fmin per float4 (was +cmp+dual-select). Phase 3: raw float restage.
// ---------------------------------------------------------------------------
__global__ __launch_bounds__(256, 4) void w_k(const float* __restrict__ dmat,
                                              float* __restrict__ WQ) {
  __shared__ __align__(16) float CL[128 * 64];   // 32KB
  __shared__ __align__(16) float TOT[16 * 64];   // 4KB
  int bx = blockIdx.x;
  int b = bx >> 6;
  int chunk = (bx >> 2) & 15;
  int q = bx & 3;
  int t1 = 1 + (chunk << 6);
  int tid = threadIdx.x;
  int wv = tid >> 6, lane = tid & 63;

  // ---- Phase 1: parallel window cumsum ----
  {
    int c = tid >> 4;          // 0..15 (8 frames each)
    int g = tid & 15;          // f4-group within quarter
    const float* base = dmat + (size_t)b * TT * VV + q * 64 + (g << 2);
    float4 rr[8];
    float4 run = make_float4(0.f, 0.f, 0.f, 0.f);
#pragma unroll
    for (int jj = 1; jj <= 8; ++jj) {
      int k = (c << 3) + jj;
      int f = t1 - 64 + k;
      bool valid = (k <= 127) && (f >= 1) && (f <= TT);
      int fc = valid ? f : 1;
      float4 dv = *(const float4*)(base + (size_t)(fc - 1) * VV);
      if (!valid) dv = make_float4(0.f, 0.f, 0.f, 0.f);
      run.x += dv.x; run.y += dv.y; run.z += dv.z; run.w += dv.w;
      rr[jj - 1] = run;
    }
    *(float4*)&TOT[(c << 6) + (g << 2)] = run;
    if (c == 0) *(float4*)&CL[(g << 2)] = make_float4(0.f, 0.f, 0.f, 0.f);
    __syncthreads();
    float4 off = make_float4(0.f, 0.f, 0.f, 0.f);
#pragma unroll
    for (int cc = 0; cc < 15; ++cc) {
      if (cc < c) {
        float4 tv = *(const float4*)&TOT[(cc << 6) + (g << 2)];
        off.x += tv.x; off.y += tv.y; off.z += tv.z; off.w += tv.w;
      }
    }
#pragma unroll
    for (int jj = 1; jj <= 8; ++jj) {
      int k = (c << 3) + jj;
      if (k <= 127) {
        float4 s = rr[jj - 1];
        s.x += off.x; s.y += off.y; s.z += off.z; s.w += off.w;
        *(float4*)&CL[(k << 6) + ((g ^ (k & 15)) << 2)] = s;
      }
    }
  }
  __syncthreads();

  // ---- Phase 2: value-only diagonal scan ----
  float bw[16];
#pragma unroll
  for (int j = 0; j < 16; ++j) {
    int dt = (j << 2) + wv;
    int ks = dt + lane;               // C_s row (per-lane)
    int kt = dt + 64;                 // C_t row (wave-uniform)
    int rti = __float_as_int(CL[(kt << 6) + (((lane >> 2) ^ (kt & 15)) << 2) + (lane & 3)]);
    int ksm = ks & 15;
    const float* rs = &CL[ks << 6];
    float bv = 1e38f;
#pragma unroll
    for (int g = 0; g < 16; ++g) {
      float4 a = *(const float4*)&rs[(g ^ ksm) << 2];
      int v0 = g << 2;
      float t0 = __int_as_float(__builtin_amdgcn_readlane(rti, v0));
      float t1v = __int_as_float(__builtin_amdgcn_readlane(rti, v0 + 1));
      float t2 = __int_as_float(__builtin_amdgcn_readlane(rti, v0 + 2));
      float t3 = __int_as_float(__builtin_amdgcn_readlane(rti, v0 + 3));
      float m01 = fminf(t0 - a.x, t1v - a.y);
      float m23 = fminf(t2 - a.z, t3 - a.w);
      bv = fminf(bv, fminf(m01, m23));
    }
    bw[j] = bv;
  }

  // ---- Phase 3: restage (reuse CL as ST[jcol 0..63][srow 0..126]) ----
  __syncthreads();
  float* ST = CL;
#pragma unroll
  for (int j = 0; j < 16; ++j) {
    int dt = (j << 2) + wv;
    int srow = dt + lane;             // 0..126
    ST[(63 - lane) * 127 + srow] = bw[j];
  }
  __syncthreads();
  {
    float* Wb = WQ + (size_t)b * TT * 256 + q * 64;   // + s*256 + j
    for (int qq = 0; qq < 32; ++qq) {
      int rr = wv * 32 + qq;
      if (rr > 126) break;
      int s = t1 - 64 + rr;
      if (s < 0) continue;
      int jlo = 63 - rr; if (jlo < 0) jlo = 0;
      int jhi = 126 - rr; if (jhi > 63) jhi = 63;
      int j = lane;
      if (j >= jlo && j <= jhi)
        Wb[(size_t)s * 256 + j] = ST[j * 127 + rr];
    }
  }
}

// ---------------------------------------------------------------------------
// Kernel 4a: sequential DP, scatter form; LDS ring of 64 x 1KB rows, DMA
// staged, fold min-of-4 quarters in the prefetch (unchanged structure).
// ---------------------------------------------------------------------------
__global__ __launch_bounds__(64) void dp_seq(const float* __restrict__ WQ,
                                             float* __restrict__ cg) {
  __shared__ __align__(16) float ring[64 * 256];   // 64KB
  int b = blockIdx.x;
  int lane = threadIdx.x;
  const char* Wb = (const char*)(WQ + (size_t)b * TT * 256);
  float* cgb = cg + (size_t)b * (TT + 1);
  if (lane == 0) cgb[0] = 0.f;

  auto stage = [&](int r) {
    const char* g = Wb + ((size_t)r << 10) + (lane << 4);
    __builtin_amdgcn_global_load_lds((const unsigned int*)g,
                                     (unsigned int*)&ring[(r & 63) << 8], 16, 0, 0);
  };
  auto ldring = [&](int r) -> float {
    int rc = (r > TT - 1) ? (TT - 1) : r;
    int base = ((rc & 63) << 8) | ((lane - rc) & 63);
    float k0 = ring[base], k1 = ring[base + 64];
    float k2 = ring[base + 128], k3 = ring[base + 192];
    return fminf(fminf(k0, k1), fminf(k2, k3));
  };

  for (int k = 0; k < 56; ++k) stage(k);
  asm volatile("s_waitcnt vmcnt(48)" ::: "memory");
  float p0 = ldring(0), p1 = ldring(1), p2 = ldring(2), p3 = ldring(3);
  float p4 = ldring(4), p5 = ldring(5), p6 = ldring(6), p7 = ldring(7);

  float c = 0.f;
  float acc = DPINF;
  float ckeep = 0.f;

#define STEP(TAU, P) { \
    float cand = c + (P); \
    acc = fminf(acc, cand); \
    int fl = (TAU) & 63; \
    float cnew = __int_as_float(__builtin_amdgcn_readlane(__float_as_int(acc), fl)); \
    bool me = (lane == fl); \
    ckeep = me ? cnew : ckeep; \
    acc = me ? DPINF : acc; \
    c = cnew; }

  for (int gg = 0; gg < 16; ++gg) {
#pragma unroll
    for (int ii = 0; ii < 8; ++ii) {
      int tb = gg * 64 + ii * 8;
      if (tb <= 960) {
        asm volatile("s_waitcnt vmcnt(40)" ::: "memory");
        stage(tb + 56); stage(tb + 57); stage(tb + 58); stage(tb + 59);
        stage(tb + 60); stage(tb + 61); stage(tb + 62); stage(tb + 63);
      } else if (tb == 968) {
        asm volatile("s_waitcnt vmcnt(0)" ::: "memory");
      }
      STEP(tb + 0, p0); p0 = ldring(tb + 8);
      STEP(tb + 1, p1); p1 = ldring(tb + 9);
      STEP(tb + 2, p2); p2 = ldring(tb + 10);
      STEP(tb + 3, p3); p3 = ldring(tb + 11);
      STEP(tb + 4, p4); p4 = ldring(tb + 12);
      STEP(tb + 5, p5); p5 = ldring(tb + 13);
      STEP(tb + 6, p6); p6 = ldring(tb + 14);
      STEP(tb + 7, p7); p7 = ldring(tb + 15);
    }
    cgb[gg * 64 + 1 + lane] = ckeep;
  }
#undef STEP
}

// ---------------------------------------------------------------------------
// Kernel 4b: parallel arg-prev (no token). Stage+fold 127 rows, antidiag
// reduce; totals bit-identical to dp_seq -> exact-ballot consistent.
// ---------------------------------------------------------------------------
__global__ __launch_bounds__(256) void prev_k(const float* __restrict__ WQ,
                                              const float* __restrict__ cg,
                                              int* __restrict__ pk) {
  __shared__ float WL[127 * 64];   // 32KB folded values
  int bx = blockIdx.x;
  int b = bx >> 4;
  int chunk = bx & 15;
  int t0 = chunk << 6;
  int tid = threadIdx.x;
  int wv = tid >> 6, lane = tid & 63;

  const float* Wb = WQ + (size_t)b * TT * 256;
  for (int cidx = tid; cidx < 127 * 64; cidx += 256) {
    int row = cidx >> 6, j = cidx & 63;
    long s = (long)(t0 - 63 + row);            // may be <0 (garbage, masked later)
    const float* cell = Wb + s * 256 + j;
    float k0 = cell[0], k1 = cell[64], k2 = cell[128], k3 = cell[192];
    WL[cidx] = fminf(fminf(k0, k1), fminf(k2, k3));
  }
  __syncthreads();

  const float* cgb = cg + (size_t)b * (TT + 1);
#pragma unroll
  for (int u = 0; u < 16; ++u) {
    int tt = wv * 16 + u;
    int t = t0 + 1 + tt;
    int i = lane;
    int s = t - 64 + i;
    float wval = WL[(tt + i) * 64 + (63 - i)];
    int sc = (s < 0) ? 0 : s;
    float total = (s >= 0) ? (cgb[sc] + wval) : DPINF;
    float m = total;
    DPP_MIN_REDUCE(m);
    float mf = __int_as_float(__builtin_amdgcn_readlane(__float_as_int(m), 63));
    unsigned long long msk = __ballot(total == mf);
    int iwin = __builtin_ctzll(msk);            // smallest i = smallest s
    int prev = t - 64 + iwin;
    if (lane == 0) pk[(size_t)b * (TT + 1) + t] = prev;
  }
}

// ---------------------------------------------------------------------------
// Kernel 4c: backtrack via binary lifting. Boundaries/counts/final cost;
// tout zeroed here, filled by tok_k.
// ---------------------------------------------------------------------------
__global__ __launch_bounds__(64) void bt_k(const int* __restrict__ pk,
                                           const float* __restrict__ cg,
                                           const int* __restrict__ lengths,
                                           float* __restrict__ out) {
  __shared__ ushort J[10][TT + 1];
  int b = blockIdx.x;
  int lane = threadIdx.x;
  const int* pb = pk + (size_t)b * (TT + 1);

  for (int t = lane; t <= TT; t += 64)
    J[0][t] = (ushort)((t == 0) ? 0 : pb[t]);
  __syncthreads();
#pragma unroll
  for (int k = 0; k < 9; ++k) {
    for (int t = lane; t <= TT; t += 64)
      J[k + 1][t] = J[k][J[k][t]];
    __syncthreads();
  }

  int len = lengths[b];
  len = (len > TT) ? TT : (len < 0 ? 0 : len);

  int cnt = 0;
  if (len > 0) {
    int cur = len, m = 0;
#pragma unroll
    for (int k = 9; k >= 0; --k) {
      int nxt = J[k][cur];
      if (nxt != 0) { cur = nxt; m += (1 << k); }
    }
    cnt = m + 1;
  }

  float* bout = out + b * TT;
  float* tout = out + MM + b * TT;
#pragma unroll 4
  for (int j0 = 0; j0 < TT; j0 += 64) {
    int j = j0 + lane;
    int node = 0;
    if (j < cnt) {
      int steps = cnt - 1 - j;
      int cur = len;
#pragma unroll
      for (int k = 9; k >= 0; --k)
        if ((steps >> k) & 1) cur = J[k][cur];
      node = cur;
    }
    bout[j] = (float)node;
    tout[j] = 0.f;
  }
  if (lane == 0) {
    out[2 * MM + b] = (float)cnt;
    out[2 * MM + BB + b] = cg[(size_t)b * (TT + 1) + len];
  }
}

// ---------------------------------------------------------------------------
// Kernel 4d: token recovery. One wave per winning segment j: (s,t] from
// boundaries; sum d rows (coalesced float4), lane-local lowest-v argmin,
// DPP reduce + ballot (lowest lane = lowest v, matches ref first-min).
// ---------------------------------------------------------------------------
__global__ __launch_bounds__(256) void tok_k(const float* __restrict__ dmat,
                                             float* __restrict__ out) {
  int bx = blockIdx.x;
  int b = bx >> 8;
  int wv = threadIdx.x >> 6, lane = threadIdx.x & 63;
  int j = ((bx & 255) << 2) + wv;
  int cnt = (int)out[2 * MM + b];
  if (j >= cnt) return;
  const float* bout = out + b * TT;
  int t = (int)bout[j];
  int s = (j == 0) ? 0 : (int)bout[j - 1];

  const float4* base = (const float4*)(dmat + (size_t)b * TT * VV);
  float4 acc = make_float4(0.f, 0.f, 0.f, 0.f);
  for (int f = s; f < t; ++f) {                 // frame rows s+1..t (0-indexed f)
    float4 dv = base[(size_t)f * 64 + lane];
    acc.x += dv.x; acc.y += dv.y; acc.z += dv.z; acc.w += dv.w;
  }
  // lane-local argmin, lowest v wins ties
  float bv = acc.x; int be = 0;
  if (acc.y < bv) { bv = acc.y; be = 1; }
  if (acc.z < bv) { bv = acc.z; be = 2; }
  if (acc.w < bv) { bv = acc.w; be = 3; }
  float m = bv;
  DPP_MIN_REDUCE(m);
  float mf = __int_as_float(__builtin_amdgcn_readlane(__float_as_int(m), 63));
  unsigned long long msk = __ballot(bv == mf);
  int iwin = __builtin_ctzll(msk);              // lowest lane = lowest v
  int vloc = (lane << 2) + be;
  int v = __builtin_amdgcn_readlane(vloc, iwin);
  if (lane == 0) out[MM + b * TT + j] = (float)v;
}

// ---------------------------------------------------------------------------
extern "C" void kernel_launch(void* const* d_in, const int* in_sizes, int n_in,
                              void* d_out, int out_size, void* d_ws, size_t ws_size,
                              hipStream_t stream) {
  const float* reps = (const float*)d_in[0];
  const float* cb   = (const float*)d_in[1];
  const int* lengths = (const int*)d_in[2];
  float* out = (float*)d_out;

  char* ws = (char*)d_ws;
  float* r2 = (float*)ws;                                    // 64 KB
  float* c2 = (float*)(ws + 65536);                          // 4 KB slot
  char* p = ws + 69632;
  float* dmat = (float*)p;               p += (size_t)MM * VV * 4;       // 16 MB
  float* WQ   = (float*)p;               p += (size_t)MM * 256 * 4;      // 16.78 MB
  float* cg   = (float*)p;               p += (size_t)BB * (TT + 1) * 4; // 65.6 KB
  int* pk     = (int*)p;                 p += (size_t)BB * (TT + 1) * 4; // 65.6 KB
  ushort* cbb = (ushort*)p;                                              // 256 KB
  // repsb (16.78 MB) aliases WQ exactly: dead before w_k writes it
  ushort* repsb = (ushort*)WQ;

  norms_k<<<(MM + VV) / 4, 256, 0, stream>>>(reps, cb, r2, c2, repsb, cbb);
  gemm_k<<<dim3(MM / 64, VV / 64), 256, 0, stream>>>(repsb, cbb, r2, c2, dmat);
  w_k<<<BB * 16 * 4, 256, 0, stream>>>(dmat, WQ);
  dp_seq<<<BB, 64, 0, stream>>>(WQ, cg);
  prev_k<<<BB * 16, 256, 0, stream>>>(WQ, cg, pk);
  bt_k<<<BB, 64, 0, stream>>>(pk, cg, lengths, out);
  tok_k<<<BB * 256, 256, 0, stream>>>(dmat, out);
}

// Round 12
// 125.194 us; speedup vs baseline: 3.7789x; 1.1461x over previous
//
#include <hip/hip_runtime.h>

#define BB 16
#define TT 1024
#define DD 512
#define VV 256
#define MM (BB*TT)

#define DPINF 1e30f

typedef __attribute__((ext_vector_type(8))) short bf16x8;
typedef __attribute__((ext_vector_type(4))) float f32x4;

// DPP min-reduce step; old = same reg -> identity for lanes with no source
#define DPP_MIN_STEP(m, CTRL) { \
  int _t = __builtin_amdgcn_update_dpp(__float_as_int(m), __float_as_int(m), CTRL, 0xF, 0xF, false); \
  m = fminf(m, __int_as_float(_t)); }

// full 64-lane min into lane 63: row_shr 1,2,4,8 then row_bcast15, row_bcast31
#define DPP_MIN_REDUCE(m) \
  DPP_MIN_STEP(m, 0x111); DPP_MIN_STEP(m, 0x112); DPP_MIN_STEP(m, 0x114); \
  DPP_MIN_STEP(m, 0x118); DPP_MIN_STEP(m, 0x142); DPP_MIN_STEP(m, 0x143);

// ---------------------------------------------------------------------------
// Kernel 1: row norms + RNE fp32->bf16 conversion.
// ---------------------------------------------------------------------------
__global__ __launch_bounds__(256) void norms_k(const float* __restrict__ reps,
                                               const float* __restrict__ cb,
                                               float* __restrict__ r2,
                                               float* __restrict__ c2,
                                               ushort* __restrict__ repsb,
                                               ushort* __restrict__ cbb) {
  int row = blockIdx.x * 4 + (threadIdx.x >> 6);
  int lane = threadIdx.x & 63;
  const float* src;
  float* dst;
  ushort* bdst;
  if (row < MM) {
    src = reps + (size_t)row * DD;
    dst = r2 + row;
    bdst = repsb + (size_t)row * DD;
  } else {
    int r = row - MM;
    if (r >= VV) return;
    src = cb + (size_t)r * DD;
    dst = c2 + r;
    bdst = cbb + (size_t)r * DD;
  }
  const float4* s4 = (const float4*)src;
  float4 a = s4[lane];
  float4 b = s4[lane + 64];

  auto cvt = [](float x) -> ushort {
    unsigned u = __float_as_uint(x);
    return (ushort)((u + 0x7FFFu + ((u >> 16) & 1u)) >> 16);   // RNE
  };
  ushort4 ua = make_ushort4(cvt(a.x), cvt(a.y), cvt(a.z), cvt(a.w));
  ushort4 ub = make_ushort4(cvt(b.x), cvt(b.y), cvt(b.z), cvt(b.w));
  *(ushort4*)&bdst[lane * 4] = ua;
  *(ushort4*)&bdst[256 + lane * 4] = ub;

  float s = a.x*a.x + a.y*a.y + a.z*a.z + a.w*a.w
          + b.x*b.x + b.y*b.y + b.z*b.z + b.w*b.w;
#pragma unroll
  for (int off = 1; off < 64; off <<= 1) s += __shfl_xor(s, off);
  if (lane == 0) *dst = s;
}

// ---------------------------------------------------------------------------
// Kernel 2: d[m][v] via bf16 MFMA (unchanged).
// ---------------------------------------------------------------------------
__global__ __launch_bounds__(256) void gemm_k(const ushort* __restrict__ repsb,
                                              const ushort* __restrict__ cbb,
                                              const float* __restrict__ r2,
                                              const float* __restrict__ c2,
                                              float* __restrict__ dmat) {
  __shared__ short Ab[2][4096];
  __shared__ short Bb[2][4096];
  int tid = threadIdx.x;
  int w = tid >> 6, l = tid & 63;
  int m0 = blockIdx.x * 64, v0 = blockIdx.y * 64;

  int srow = l >> 3;
  int scol = ((l & 7) << 4) ^ (srow << 4);

  auto stage = [&](int buf, int kc) {
#pragma unroll
    for (int ii = 0; ii < 2; ++ii) {
      int instr = w + ii * 4;
      int row = instr * 8 + srow;
      const char* ga = (const char*)repsb + ((size_t)(m0 + row) * DD + kc * 64) * 2 + scol;
      __builtin_amdgcn_global_load_lds((const unsigned int*)ga,
                                       (unsigned int*)&Ab[buf][instr * 512], 16, 0, 0);
      const char* gb = (const char*)cbb + ((size_t)(v0 + row) * DD + kc * 64) * 2 + scol;
      __builtin_amdgcn_global_load_lds((const unsigned int*)gb,
                                       (unsigned int*)&Bb[buf][instr * 512], 16, 0, 0);
    }
  };

  int fr = l & 15;
  int fq = l >> 4;
  int swz = (fr & 7) << 3;

  f32x4 acc0 = {0.f,0.f,0.f,0.f}, acc1 = {0.f,0.f,0.f,0.f};
  f32x4 acc2 = {0.f,0.f,0.f,0.f}, acc3 = {0.f,0.f,0.f,0.f};

  stage(0, 0);
  int cur = 0;
  for (int kc = 0; kc < 8; ++kc) {
    if (kc < 7) {
      stage(cur ^ 1, kc + 1);
      asm volatile("s_waitcnt vmcnt(4)" ::: "memory");
    } else {
      asm volatile("s_waitcnt vmcnt(0)" ::: "memory");
    }
    __syncthreads();
#pragma unroll
    for (int ks = 0; ks < 2; ++ks) {
      int koff = (ks * 32 + fq * 8) ^ swz;
      bf16x8 av = *(const bf16x8*)&Ab[cur][(w * 16 + fr) * 64 + koff];
      bf16x8 b0 = *(const bf16x8*)&Bb[cur][(0 * 16 + fr) * 64 + koff];
      bf16x8 b1 = *(const bf16x8*)&Bb[cur][(1 * 16 + fr) * 64 + koff];
      bf16x8 b2 = *(const bf16x8*)&Bb[cur][(2 * 16 + fr) * 64 + koff];
      bf16x8 b3 = *(const bf16x8*)&Bb[cur][(3 * 16 + fr) * 64 + koff];
      acc0 = __builtin_amdgcn_mfma_f32_16x16x32_bf16(av, b0, acc0, 0, 0, 0);
      acc1 = __builtin_amdgcn_mfma_f32_16x16x32_bf16(av, b1, acc1, 0, 0, 0);
      acc2 = __builtin_amdgcn_mfma_f32_16x16x32_bf16(av, b2, acc2, 0, 0, 0);
      acc3 = __builtin_amdgcn_mfma_f32_16x16x32_bf16(av, b3, acc3, 0, 0, 0);
    }
    __syncthreads();
    cur ^= 1;
  }

  float rv[4];
#pragma unroll
  for (int r = 0; r < 4; ++r) rv[r] = r2[m0 + w * 16 + fq * 4 + r];
#pragma unroll
  for (int vt = 0; vt < 4; ++vt) {
    f32x4 a = (vt == 0) ? acc0 : (vt == 1) ? acc1 : (vt == 2) ? acc2 : acc3;
    int v = v0 + vt * 16 + fr;
    float cc = c2[v];
#pragma unroll
    for (int r = 0; r < 4; ++r) {
      int m = m0 + w * 16 + fq * 4 + r;
      dmat[(size_t)m * VV + v] = fmaf(-2.f, a[r], rv[r] + cc);
    }
  }
}

// ---------------------------------------------------------------------------
// Kernel 3: W values, v-quarter blocks. Phase 3 now folds across quarters
// via global atomicMin (int-cast; W>0 so bit ordering == float ordering,
// bit-identical to fminf fold, order-independent => deterministic) into
// Wf[s][j] pre-initialized to 0x7F7F7F7F (3.39e38) by hipMemsetAsync.
// ---------------------------------------------------------------------------
__global__ __launch_bounds__(256, 4) void w_k(const float* __restrict__ dmat,
                                              int* __restrict__ Wf) {
  __shared__ __align__(16) float CL[128 * 64];   // 32KB
  __shared__ __align__(16) float TOT[16 * 64];   // 4KB
  int bx = blockIdx.x;
  int b = bx >> 6;
  int chunk = (bx >> 2) & 15;
  int q = bx & 3;
  int t1 = 1 + (chunk << 6);
  int tid = threadIdx.x;
  int wv = tid >> 6, lane = tid & 63;

  // ---- Phase 1: parallel window cumsum ----
  {
    int c = tid >> 4;          // 0..15 (8 frames each)
    int g = tid & 15;          // f4-group within quarter
    const float* base = dmat + (size_t)b * TT * VV + q * 64 + (g << 2);
    float4 rr[8];
    float4 run = make_float4(0.f, 0.f, 0.f, 0.f);
#pragma unroll
    for (int jj = 1; jj <= 8; ++jj) {
      int k = (c << 3) + jj;
      int f = t1 - 64 + k;
      bool valid = (k <= 127) && (f >= 1) && (f <= TT);
      int fc = valid ? f : 1;
      float4 dv = *(const float4*)(base + (size_t)(fc - 1) * VV);
      if (!valid) dv = make_float4(0.f, 0.f, 0.f, 0.f);
      run.x += dv.x; run.y += dv.y; run.z += dv.z; run.w += dv.w;
      rr[jj - 1] = run;
    }
    *(float4*)&TOT[(c << 6) + (g << 2)] = run;
    if (c == 0) *(float4*)&CL[(g << 2)] = make_float4(0.f, 0.f, 0.f, 0.f);
    __syncthreads();
    float4 off = make_float4(0.f, 0.f, 0.f, 0.f);
#pragma unroll
    for (int cc = 0; cc < 15; ++cc) {
      if (cc < c) {
        float4 tv = *(const float4*)&TOT[(cc << 6) + (g << 2)];
        off.x += tv.x; off.y += tv.y; off.z += tv.z; off.w += tv.w;
      }
    }
#pragma unroll
    for (int jj = 1; jj <= 8; ++jj) {
      int k = (c << 3) + jj;
      if (k <= 127) {
        float4 s = rr[jj - 1];
        s.x += off.x; s.y += off.y; s.z += off.z; s.w += off.w;
        *(float4*)&CL[(k << 6) + ((g ^ (k & 15)) << 2)] = s;
      }
    }
  }
  __syncthreads();

  // ---- Phase 2: value-only diagonal scan ----
  float bw[16];
#pragma unroll
  for (int j = 0; j < 16; ++j) {
    int dt = (j << 2) + wv;
    int ks = dt + lane;               // C_s row (per-lane)
    int kt = dt + 64;                 // C_t row (wave-uniform)
    int rti = __float_as_int(CL[(kt << 6) + (((lane >> 2) ^ (kt & 15)) << 2) + (lane & 3)]);
    int ksm = ks & 15;
    const float* rs = &CL[ks << 6];
    float bv = 1e38f;
#pragma unroll
    for (int g = 0; g < 16; ++g) {
      float4 a = *(const float4*)&rs[(g ^ ksm) << 2];
      int v0 = g << 2;
      float t0 = __int_as_float(__builtin_amdgcn_readlane(rti, v0));
      float t1v = __int_as_float(__builtin_amdgcn_readlane(rti, v0 + 1));
      float t2 = __int_as_float(__builtin_amdgcn_readlane(rti, v0 + 2));
      float t3 = __int_as_float(__builtin_amdgcn_readlane(rti, v0 + 3));
      float m01 = fminf(t0 - a.x, t1v - a.y);
      float m23 = fminf(t2 - a.z, t3 - a.w);
      bv = fminf(bv, fminf(m01, m23));
    }
    bw[j] = bv;
  }

  // ---- Phase 3: restage + atomicMin fold into Wf[s][j] ----
  __syncthreads();
  float* ST = CL;
#pragma unroll
  for (int j = 0; j < 16; ++j) {
    int dt = (j << 2) + wv;
    int srow = dt + lane;             // 0..126
    ST[(63 - lane) * 127 + srow] = bw[j];
  }
  __syncthreads();
  {
    int* Wfb = Wf + (size_t)b * TT * 64;
    for (int qq = 0; qq < 32; ++qq) {
      int rr = wv * 32 + qq;
      if (rr > 126) break;
      int s = t1 - 64 + rr;
      if (s < 0) continue;
      int jlo = 63 - rr; if (jlo < 0) jlo = 0;
      int jhi = 126 - rr; if (jhi > 63) jhi = 63;
      int j = lane;
      if (j >= jlo && j <= jhi)
        atomicMin(&Wfb[(size_t)s * 64 + j], __float_as_int(ST[j * 127 + rr]));
    }
  }
}

// ---------------------------------------------------------------------------
// Kernel 4a: sequential DP, scatter form, pre-folded Wf. 256-row x 256B LDS
// ring; one 1KB DMA = 4 rows; 240-row lead, vmcnt(56) steady; per step:
// one ds_read_b32 + {add, min, readlane(imm), cmp, 2 cndmask}.
// ---------------------------------------------------------------------------
__global__ __launch_bounds__(64) void dp_seq(const float* __restrict__ Wf,
                                             float* __restrict__ cg) {
  __shared__ __align__(16) float ring[256 * 64];   // 64 KB
  int b = blockIdx.x;
  int lane = threadIdx.x;
  const char* Wb = (const char*)(Wf + (size_t)b * TT * 64);
  float* cgb = cg + (size_t)b * (TT + 1);
  if (lane == 0) cgb[0] = 0.f;

  auto stage4 = [&](int d) {        // DMA d stages rows 4d..4d+3 (1KB linear)
    const char* g = Wb + ((size_t)d << 10) + (lane << 4);
    __builtin_amdgcn_global_load_lds((const unsigned int*)g,
                                     (unsigned int*)&ring[((d << 2) & 255) << 6], 16, 0, 0);
  };
  auto ldring = [&](int r) -> float {
    int rc = (r > TT - 1) ? (TT - 1) : r;
    return ring[((rc & 255) << 6) | ((lane - rc) & 63)];
  };

  for (int d = 0; d < 60; ++d) stage4(d);            // rows 0..239
  asm volatile("s_waitcnt vmcnt(56)" ::: "memory");  // DMAs 0..3 -> rows 0..15
  float p0 = ldring(0), p1 = ldring(1), p2 = ldring(2), p3 = ldring(3);
  float p4 = ldring(4), p5 = ldring(5), p6 = ldring(6), p7 = ldring(7);

  float c = 0.f;
  float acc = DPINF;
  float ckeep = 0.f;

#define STEP(TAU, P) { \
    float cand = c + (P); \
    acc = fminf(acc, cand); \
    int fl = (TAU) & 63; \
    float cnew = __int_as_float(__builtin_amdgcn_readlane(__float_as_int(acc), fl)); \
    bool me = (lane == fl); \
    ckeep = me ? cnew : ckeep; \
    acc = me ? DPINF : acc; \
    c = cnew; }

  for (int gg = 0; gg < 16; ++gg) {
#pragma unroll
    for (int ii = 0; ii < 8; ++ii) {
      int tb = gg * 64 + ii * 8;
      if (tb <= 776) {
        // issued = 60 + tb/4; vmcnt(56) -> completed >= tb/4+4 -> rows <= tb+15
        asm volatile("s_waitcnt vmcnt(56)" ::: "memory");
        stage4(60 + (tb >> 2)); stage4(61 + (tb >> 2));   // rows 240+tb..247+tb
      } else if (tb == 784) {
        asm volatile("s_waitcnt vmcnt(0)" ::: "memory");  // all 256 DMAs done
      }
      STEP(tb + 0, p0); p0 = ldring(tb + 8);
      STEP(tb + 1, p1); p1 = ldring(tb + 9);
      STEP(tb + 2, p2); p2 = ldring(tb + 10);
      STEP(tb + 3, p3); p3 = ldring(tb + 11);
      STEP(tb + 4, p4); p4 = ldring(tb + 12);
      STEP(tb + 5, p5); p5 = ldring(tb + 13);
      STEP(tb + 6, p6); p6 = ldring(tb + 14);
      STEP(tb + 7, p7); p7 = ldring(tb + 15);
    }
    cgb[gg * 64 + 1 + lane] = ckeep;
  }
#undef STEP
}

// ---------------------------------------------------------------------------
// Kernel 4b: parallel arg-prev from folded Wf. Stage 127 rows (float4 copy),
// antidiag reduce; totals bit-identical to dp_seq.
// ---------------------------------------------------------------------------
__global__ __launch_bounds__(256) void prev_k(const float* __restrict__ Wf,
                                              const float* __restrict__ cg,
                                              int* __restrict__ pk) {
  __shared__ float WL[127 * 64];   // 32KB
  int bx = blockIdx.x;
  int b = bx >> 4;
  int chunk = bx & 15;
  int t0 = chunk << 6;
  int tid = threadIdx.x;
  int wv = tid >> 6, lane = tid & 63;

  const float* Wfb = Wf + (size_t)b * TT * 64;
  for (int ci = tid; ci < 127 * 16; ci += 256) {
    int row = ci >> 4, c4 = ci & 15;
    long s = (long)(t0 - 63 + row);            // may be <0 (garbage, masked later)
    float4 v = *(const float4*)(Wfb + s * 64 + (c4 << 2));
    *(float4*)&WL[(row << 6) + (c4 << 2)] = v;
  }
  __syncthreads();

  const float* cgb = cg + (size_t)b * (TT + 1);
#pragma unroll
  for (int u = 0; u < 16; ++u) {
    int tt = wv * 16 + u;
    int t = t0 + 1 + tt;
    int i = lane;
    int s = t - 64 + i;
    float wval = WL[(tt + i) * 64 + (63 - i)];
    int sc = (s < 0) ? 0 : s;
    float total = (s >= 0) ? (cgb[sc] + wval) : DPINF;
    float m = total;
    DPP_MIN_REDUCE(m);
    float mf = __int_as_float(__builtin_amdgcn_readlane(__float_as_int(m), 63));
    unsigned long long msk = __ballot(total == mf);
    int iwin = __builtin_ctzll(msk);            // smallest i = smallest s
    int prev = t - 64 + iwin;
    if (lane == 0) pk[(size_t)b * (TT + 1) + t] = prev;
  }
}

// ---------------------------------------------------------------------------
// Kernel 4c: backtrack via binary lifting (tokens filled by tok_k).
// ---------------------------------------------------------------------------
__global__ __launch_bounds__(64) void bt_k(const int* __restrict__ pk,
                                           const float* __restrict__ cg,
                                           const int* __restrict__ lengths,
                                           float* __restrict__ out) {
  __shared__ ushort J[10][TT + 1];
  int b = blockIdx.x;
  int lane = threadIdx.x;
  const int* pb = pk + (size_t)b * (TT + 1);

  for (int t = lane; t <= TT; t += 64)
    J[0][t] = (ushort)((t == 0) ? 0 : pb[t]);
  __syncthreads();
#pragma unroll
  for (int k = 0; k < 9; ++k) {
    for (int t = lane; t <= TT; t += 64)
      J[k + 1][t] = J[k][J[k][t]];
    __syncthreads();
  }

  int len = lengths[b];
  len = (len > TT) ? TT : (len < 0 ? 0 : len);

  int cnt = 0;
  if (len > 0) {
    int cur = len, m = 0;
#pragma unroll
    for (int k = 9; k >= 0; --k) {
      int nxt = J[k][cur];
      if (nxt != 0) { cur = nxt; m += (1 << k); }
    }
    cnt = m + 1;
  }

  float* bout = out + b * TT;
  float* tout = out + MM + b * TT;
#pragma unroll 4
  for (int j0 = 0; j0 < TT; j0 += 64) {
    int j = j0 + lane;
    int node = 0;
    if (j < cnt) {
      int steps = cnt - 1 - j;
      int cur = len;
#pragma unroll
      for (int k = 9; k >= 0; --k)
        if ((steps >> k) & 1) cur = J[k][cur];
      node = cur;
    }
    bout[j] = (float)node;
    tout[j] = 0.f;
  }
  if (lane == 0) {
    out[2 * MM + b] = (float)cnt;
    out[2 * MM + BB + b] = cg[(size_t)b * (TT + 1) + len];
  }
}

// ---------------------------------------------------------------------------
// Kernel 4d: token recovery per winning segment (unchanged).
// ---------------------------------------------------------------------------
__global__ __launch_bounds__(256) void tok_k(const float* __restrict__ dmat,
                                             float* __restrict__ out) {
  int bx = blockIdx.x;
  int b = bx >> 8;
  int wv = threadIdx.x >> 6, lane = threadIdx.x & 63;
  int j = ((bx & 255) << 2) + wv;
  int cnt = (int)out[2 * MM + b];
  if (j >= cnt) return;
  const float* bout = out + b * TT;
  int t = (int)bout[j];
  int s = (j == 0) ? 0 : (int)bout[j - 1];

  const float4* base = (const float4*)(dmat + (size_t)b * TT * VV);
  float4 acc = make_float4(0.f, 0.f, 0.f, 0.f);
  for (int f = s; f < t; ++f) {
    float4 dv = base[(size_t)f * 64 + lane];
    acc.x += dv.x; acc.y += dv.y; acc.z += dv.z; acc.w += dv.w;
  }
  float bv = acc.x; int be = 0;
  if (acc.y < bv) { bv = acc.y; be = 1; }
  if (acc.z < bv) { bv = acc.z; be = 2; }
  if (acc.w < bv) { bv = acc.w; be = 3; }
  float m = bv;
  DPP_MIN_REDUCE(m);
  float mf = __int_as_float(__builtin_amdgcn_readlane(__float_as_int(m), 63));
  unsigned long long msk = __ballot(bv == mf);
  int iwin = __builtin_ctzll(msk);              // lowest lane = lowest v
  int vloc = (lane << 2) + be;
  int v = __builtin_amdgcn_readlane(vloc, iwin);
  if (lane == 0) out[MM + b * TT + j] = (float)v;
}

// ---------------------------------------------------------------------------
extern "C" void kernel_launch(void* const* d_in, const int* in_sizes, int n_in,
                              void* d_out, int out_size, void* d_ws, size_t ws_size,
                              hipStream_t stream) {
  const float* reps = (const float*)d_in[0];
  const float* cb   = (const float*)d_in[1];
  const int* lengths = (const int*)d_in[2];
  float* out = (float*)d_out;

  char* ws = (char*)d_ws;
  float* r2 = (float*)ws;                                    // 64 KB
  float* c2 = (float*)(ws + 65536);                          // 4 KB slot
  char* p = ws + 69632;
  float* dmat = (float*)p;               p += (size_t)MM * VV * 4;       // 16 MB
  ushort* repsb = (ushort*)p;            p += (size_t)MM * DD * 2;       // 16.78 MB
  float* cg   = (float*)p;               p += (size_t)BB * (TT + 1) * 4; // 65.6 KB
  int* pk     = (int*)p;                 p += (size_t)BB * (TT + 1) * 4; // 65.6 KB
  ushort* cbb = (ushort*)p;                                              // 256 KB
  // Wf (4MB) aliases repsb: repsb dead after gemm_k; memset ordered after it
  int* Wf = (int*)repsb;

  norms_k<<<(MM + VV) / 4, 256, 0, stream>>>(reps, cb, r2, c2, repsb, cbb);
  gemm_k<<<dim3(MM / 64, VV / 64), 256, 0, stream>>>(repsb, cbb, r2, c2, dmat);
  hipMemsetAsync(Wf, 0x7F, (size_t)MM * 64 * 4, stream);     // +3.39e38 fill
  w_k<<<BB * 16 * 4, 256, 0, stream>>>(dmat, Wf);
  dp_seq<<<BB, 64, 0, stream>>>((const float*)Wf, cg);
  prev_k<<<BB * 16, 256, 0, stream>>>((const float*)Wf, cg, pk);
  bt_k<<<BB, 64, 0, stream>>>(pk, cg, lengths, out);
  tok_k<<<BB * 256, 256, 0, stream>>>(dmat, out);
}

// Round 13
// 124.818 us; speedup vs baseline: 3.7903x; 1.0030x over previous
//
#include <hip/hip_runtime.h>

#define BB 16
#define TT 1024
#define DD 512
#define VV 256
#define MM (BB*TT)

#define DPINF 1e30f

typedef __attribute__((ext_vector_type(8))) short bf16x8;
typedef __attribute__((ext_vector_type(4))) float f32x4;

// DPP min-reduce step; old = same reg -> identity for lanes with no source
#define DPP_MIN_STEP(m, CTRL) { \
  int _t = __builtin_amdgcn_update_dpp(__float_as_int(m), __float_as_int(m), CTRL, 0xF, 0xF, false); \
  m = fminf(m, __int_as_float(_t)); }

// full 64-lane min into lane 63: row_shr 1,2,4,8 then row_bcast15, row_bcast31
#define DPP_MIN_REDUCE(m) \
  DPP_MIN_STEP(m, 0x111); DPP_MIN_STEP(m, 0x112); DPP_MIN_STEP(m, 0x114); \
  DPP_MIN_STEP(m, 0x118); DPP_MIN_STEP(m, 0x142); DPP_MIN_STEP(m, 0x143);

// ---------------------------------------------------------------------------
// Kernel 0: fill Wf with 0x7F7F7F7F (+3.39e38). Replaces hipMemsetAsync,
// whose rocclr fill kernel ran at 96 GB/s and cost 42us (round-12 #1).
// ---------------------------------------------------------------------------
__global__ __launch_bounds__(256) void fill_k(int4* __restrict__ Wf) {
  size_t i = (size_t)blockIdx.x * 256 + threadIdx.x;
  Wf[i] = make_int4(0x7F7F7F7F, 0x7F7F7F7F, 0x7F7F7F7F, 0x7F7F7F7F);
}

// ---------------------------------------------------------------------------
// Kernel 1: row norms + RNE fp32->bf16 conversion.
// ---------------------------------------------------------------------------
__global__ __launch_bounds__(256) void norms_k(const float* __restrict__ reps,
                                               const float* __restrict__ cb,
                                               float* __restrict__ r2,
                                               float* __restrict__ c2,
                                               ushort* __restrict__ repsb,
                                               ushort* __restrict__ cbb) {
  int row = blockIdx.x * 4 + (threadIdx.x >> 6);
  int lane = threadIdx.x & 63;
  const float* src;
  float* dst;
  ushort* bdst;
  if (row < MM) {
    src = reps + (size_t)row * DD;
    dst = r2 + row;
    bdst = repsb + (size_t)row * DD;
  } else {
    int r = row - MM;
    if (r >= VV) return;
    src = cb + (size_t)r * DD;
    dst = c2 + r;
    bdst = cbb + (size_t)r * DD;
  }
  const float4* s4 = (const float4*)src;
  float4 a = s4[lane];
  float4 b = s4[lane + 64];

  auto cvt = [](float x) -> ushort {
    unsigned u = __float_as_uint(x);
    return (ushort)((u + 0x7FFFu + ((u >> 16) & 1u)) >> 16);   // RNE
  };
  ushort4 ua = make_ushort4(cvt(a.x), cvt(a.y), cvt(a.z), cvt(a.w));
  ushort4 ub = make_ushort4(cvt(b.x), cvt(b.y), cvt(b.z), cvt(b.w));
  *(ushort4*)&bdst[lane * 4] = ua;
  *(ushort4*)&bdst[256 + lane * 4] = ub;

  float s = a.x*a.x + a.y*a.y + a.z*a.z + a.w*a.w
          + b.x*b.x + b.y*b.y + b.z*b.z + b.w*b.w;
#pragma unroll
  for (int off = 1; off < 64; off <<= 1) s += __shfl_xor(s, off);
  if (lane == 0) *dst = s;
}

// ---------------------------------------------------------------------------
// Kernel 2: d[m][v] via bf16 MFMA (unchanged).
// ---------------------------------------------------------------------------
__global__ __launch_bounds__(256) void gemm_k(const ushort* __restrict__ repsb,
                                              const ushort* __restrict__ cbb,
                                              const float* __restrict__ r2,
                                              const float* __restrict__ c2,
                                              float* __restrict__ dmat) {
  __shared__ short Ab[2][4096];
  __shared__ short Bb[2][4096];
  int tid = threadIdx.x;
  int w = tid >> 6, l = tid & 63;
  int m0 = blockIdx.x * 64, v0 = blockIdx.y * 64;

  int srow = l >> 3;
  int scol = ((l & 7) << 4) ^ (srow << 4);

  auto stage = [&](int buf, int kc) {
#pragma unroll
    for (int ii = 0; ii < 2; ++ii) {
      int instr = w + ii * 4;
      int row = instr * 8 + srow;
      const char* ga = (const char*)repsb + ((size_t)(m0 + row) * DD + kc * 64) * 2 + scol;
      __builtin_amdgcn_global_load_lds((const unsigned int*)ga,
                                       (unsigned int*)&Ab[buf][instr * 512], 16, 0, 0);
      const char* gb = (const char*)cbb + ((size_t)(v0 + row) * DD + kc * 64) * 2 + scol;
      __builtin_amdgcn_global_load_lds((const unsigned int*)gb,
                                       (unsigned int*)&Bb[buf][instr * 512], 16, 0, 0);
    }
  };

  int fr = l & 15;
  int fq = l >> 4;
  int swz = (fr & 7) << 3;

  f32x4 acc0 = {0.f,0.f,0.f,0.f}, acc1 = {0.f,0.f,0.f,0.f};
  f32x4 acc2 = {0.f,0.f,0.f,0.f}, acc3 = {0.f,0.f,0.f,0.f};

  stage(0, 0);
  int cur = 0;
  for (int kc = 0; kc < 8; ++kc) {
    if (kc < 7) {
      stage(cur ^ 1, kc + 1);
      asm volatile("s_waitcnt vmcnt(4)" ::: "memory");
    } else {
      asm volatile("s_waitcnt vmcnt(0)" ::: "memory");
    }
    __syncthreads();
#pragma unroll
    for (int ks = 0; ks < 2; ++ks) {
      int koff = (ks * 32 + fq * 8) ^ swz;
      bf16x8 av = *(const bf16x8*)&Ab[cur][(w * 16 + fr) * 64 + koff];
      bf16x8 b0 = *(const bf16x8*)&Bb[cur][(0 * 16 + fr) * 64 + koff];
      bf16x8 b1 = *(const bf16x8*)&Bb[cur][(1 * 16 + fr) * 64 + koff];
      bf16x8 b2 = *(const bf16x8*)&Bb[cur][(2 * 16 + fr) * 64 + koff];
      bf16x8 b3 = *(const bf16x8*)&Bb[cur][(3 * 16 + fr) * 64 + koff];
      acc0 = __builtin_amdgcn_mfma_f32_16x16x32_bf16(av, b0, acc0, 0, 0, 0);
      acc1 = __builtin_amdgcn_mfma_f32_16x16x32_bf16(av, b1, acc1, 0, 0, 0);
      acc2 = __builtin_amdgcn_mfma_f32_16x16x32_bf16(av, b2, acc2, 0, 0, 0);
      acc3 = __builtin_amdgcn_mfma_f32_16x16x32_bf16(av, b3, acc3, 0, 0, 0);
    }
    __syncthreads();
    cur ^= 1;
  }

  float rv[4];
#pragma unroll
  for (int r = 0; r < 4; ++r) rv[r] = r2[m0 + w * 16 + fq * 4 + r];
#pragma unroll
  for (int vt = 0; vt < 4; ++vt) {
    f32x4 a = (vt == 0) ? acc0 : (vt == 1) ? acc1 : (vt == 2) ? acc2 : acc3;
    int v = v0 + vt * 16 + fr;
    float cc = c2[v];
#pragma unroll
    for (int r = 0; r < 4; ++r) {
      int m = m0 + w * 16 + fq * 4 + r;
      dmat[(size_t)m * VV + v] = fmaf(-2.f, a[r], rv[r] + cc);
    }
  }
}

// ---------------------------------------------------------------------------
// Kernel 3: W values, v-quarter blocks; atomicMin fold into Wf (unchanged).
// ---------------------------------------------------------------------------
__global__ __launch_bounds__(256, 4) void w_k(const float* __restrict__ dmat,
                                              int* __restrict__ Wf) {
  __shared__ __align__(16) float CL[128 * 64];   // 32KB
  __shared__ __align__(16) float TOT[16 * 64];   // 4KB
  int bx = blockIdx.x;
  int b = bx >> 6;
  int chunk = (bx >> 2) & 15;
  int q = bx & 3;
  int t1 = 1 + (chunk << 6);
  int tid = threadIdx.x;
  int wv = tid >> 6, lane = tid & 63;

  // ---- Phase 1: parallel window cumsum ----
  {
    int c = tid >> 4;          // 0..15 (8 frames each)
    int g = tid & 15;          // f4-group within quarter
    const float* base = dmat + (size_t)b * TT * VV + q * 64 + (g << 2);
    float4 rr[8];
    float4 run = make_float4(0.f, 0.f, 0.f, 0.f);
#pragma unroll
    for (int jj = 1; jj <= 8; ++jj) {
      int k = (c << 3) + jj;
      int f = t1 - 64 + k;
      bool valid = (k <= 127) && (f >= 1) && (f <= TT);
      int fc = valid ? f : 1;
      float4 dv = *(const float4*)(base + (size_t)(fc - 1) * VV);
      if (!valid) dv = make_float4(0.f, 0.f, 0.f, 0.f);
      run.x += dv.x; run.y += dv.y; run.z += dv.z; run.w += dv.w;
      rr[jj - 1] = run;
    }
    *(float4*)&TOT[(c << 6) + (g << 2)] = run;
    if (c == 0) *(float4*)&CL[(g << 2)] = make_float4(0.f, 0.f, 0.f, 0.f);
    __syncthreads();
    float4 off = make_float4(0.f, 0.f, 0.f, 0.f);
#pragma unroll
    for (int cc = 0; cc < 15; ++cc) {
      if (cc < c) {
        float4 tv = *(const float4*)&TOT[(cc << 6) + (g << 2)];
        off.x += tv.x; off.y += tv.y; off.z += tv.z; off.w += tv.w;
      }
    }
#pragma unroll
    for (int jj = 1; jj <= 8; ++jj) {
      int k = (c << 3) + jj;
      if (k <= 127) {
        float4 s = rr[jj - 1];
        s.x += off.x; s.y += off.y; s.z += off.z; s.w += off.w;
        *(float4*)&CL[(k << 6) + ((g ^ (k & 15)) << 2)] = s;
      }
    }
  }
  __syncthreads();

  // ---- Phase 2: value-only diagonal scan ----
  float bw[16];
#pragma unroll
  for (int j = 0; j < 16; ++j) {
    int dt = (j << 2) + wv;
    int ks = dt + lane;               // C_s row (per-lane)
    int kt = dt + 64;                 // C_t row (wave-uniform)
    int rti = __float_as_int(CL[(kt << 6) + (((lane >> 2) ^ (kt & 15)) << 2) + (lane & 3)]);
    int ksm = ks & 15;
    const float* rs = &CL[ks << 6];
    float bv = 1e38f;
#pragma unroll
    for (int g = 0; g < 16; ++g) {
      float4 a = *(const float4*)&rs[(g ^ ksm) << 2];
      int v0 = g << 2;
      float t0 = __int_as_float(__builtin_amdgcn_readlane(rti, v0));
      float t1v = __int_as_float(__builtin_amdgcn_readlane(rti, v0 + 1));
      float t2 = __int_as_float(__builtin_amdgcn_readlane(rti, v0 + 2));
      float t3 = __int_as_float(__builtin_amdgcn_readlane(rti, v0 + 3));
      float m01 = fminf(t0 - a.x, t1v - a.y);
      float m23 = fminf(t2 - a.z, t3 - a.w);
      bv = fminf(bv, fminf(m01, m23));
    }
    bw[j] = bv;
  }

  // ---- Phase 3: restage + atomicMin fold into Wf[s][j] ----
  __syncthreads();
  float* ST = CL;
#pragma unroll
  for (int j = 0; j < 16; ++j) {
    int dt = (j << 2) + wv;
    int srow = dt + lane;             // 0..126
    ST[(63 - lane) * 127 + srow] = bw[j];
  }
  __syncthreads();
  {
    int* Wfb = Wf + (size_t)b * TT * 64;
    for (int qq = 0; qq < 32; ++qq) {
      int rr = wv * 32 + qq;
      if (rr > 126) break;
      int s = t1 - 64 + rr;
      if (s < 0) continue;
      int jlo = 63 - rr; if (jlo < 0) jlo = 0;
      int jhi = 126 - rr; if (jhi > 63) jhi = 63;
      int j = lane;
      if (j >= jlo && j <= jhi)
        atomicMin(&Wfb[(size_t)s * 64 + j], __float_as_int(ST[j * 127 + rr]));
    }
  }
}

// ---------------------------------------------------------------------------
// Kernel 4a: sequential DP, scatter form, pre-folded Wf (unchanged).
// ---------------------------------------------------------------------------
__global__ __launch_bounds__(64) void dp_seq(const float* __restrict__ Wf,
                                             float* __restrict__ cg) {
  __shared__ __align__(16) float ring[256 * 64];   // 64 KB
  int b = blockIdx.x;
  int lane = threadIdx.x;
  const char* Wb = (const char*)(Wf + (size_t)b * TT * 64);
  float* cgb = cg + (size_t)b * (TT + 1);
  if (lane == 0) cgb[0] = 0.f;

  auto stage4 = [&](int d) {        // DMA d stages rows 4d..4d+3 (1KB linear)
    const char* g = Wb + ((size_t)d << 10) + (lane << 4);
    __builtin_amdgcn_global_load_lds((const unsigned int*)g,
                                     (unsigned int*)&ring[((d << 2) & 255) << 6], 16, 0, 0);
  };
  auto ldring = [&](int r) -> float {
    int rc = (r > TT - 1) ? (TT - 1) : r;
    return ring[((rc & 255) << 6) | ((lane - rc) & 63)];
  };

  for (int d = 0; d < 60; ++d) stage4(d);            // rows 0..239
  asm volatile("s_waitcnt vmcnt(56)" ::: "memory");  // DMAs 0..3 -> rows 0..15
  float p0 = ldring(0), p1 = ldring(1), p2 = ldring(2), p3 = ldring(3);
  float p4 = ldring(4), p5 = ldring(5), p6 = ldring(6), p7 = ldring(7);

  float c = 0.f;
  float acc = DPINF;
  float ckeep = 0.f;

#define STEP(TAU, P) { \
    float cand = c + (P); \
    acc = fminf(acc, cand); \
    int fl = (TAU) & 63; \
    float cnew = __int_as_float(__builtin_amdgcn_readlane(__float_as_int(acc), fl)); \
    bool me = (lane == fl); \
    ckeep = me ? cnew : ckeep; \
    acc = me ? DPINF : acc; \
    c = cnew; }

  for (int gg = 0; gg < 16; ++gg) {
#pragma unroll
    for (int ii = 0; ii < 8; ++ii) {
      int tb = gg * 64 + ii * 8;
      if (tb <= 776) {
        asm volatile("s_waitcnt vmcnt(56)" ::: "memory");
        stage4(60 + (tb >> 2)); stage4(61 + (tb >> 2));   // rows 240+tb..247+tb
      } else if (tb == 784) {
        asm volatile("s_waitcnt vmcnt(0)" ::: "memory");  // all 256 DMAs done
      }
      STEP(tb + 0, p0); p0 = ldring(tb + 8);
      STEP(tb + 1, p1); p1 = ldring(tb + 9);
      STEP(tb + 2, p2); p2 = ldring(tb + 10);
      STEP(tb + 3, p3); p3 = ldring(tb + 11);
      STEP(tb + 4, p4); p4 = ldring(tb + 12);
      STEP(tb + 5, p5); p5 = ldring(tb + 13);
      STEP(tb + 6, p6); p6 = ldring(tb + 14);
      STEP(tb + 7, p7); p7 = ldring(tb + 15);
    }
    cgb[gg * 64 + 1 + lane] = ckeep;
  }
#undef STEP
}

// ---------------------------------------------------------------------------
// Kernel 4b: parallel arg-prev from folded Wf (unchanged).
// ---------------------------------------------------------------------------
__global__ __launch_bounds__(256) void prev_k(const float* __restrict__ Wf,
                                              const float* __restrict__ cg,
                                              int* __restrict__ pk) {
  __shared__ float WL[127 * 64];   // 32KB
  int bx = blockIdx.x;
  int b = bx >> 4;
  int chunk = bx & 15;
  int t0 = chunk << 6;
  int tid = threadIdx.x;
  int wv = tid >> 6, lane = tid & 63;

  const float* Wfb = Wf + (size_t)b * TT * 64;
  for (int ci = tid; ci < 127 * 16; ci += 256) {
    int row = ci >> 4, c4 = ci & 15;
    long s = (long)(t0 - 63 + row);            // may be <0 (garbage, masked later)
    float4 v = *(const float4*)(Wfb + s * 64 + (c4 << 2));
    *(float4*)&WL[(row << 6) + (c4 << 2)] = v;
  }
  __syncthreads();

  const float* cgb = cg + (size_t)b * (TT + 1);
#pragma unroll
  for (int u = 0; u < 16; ++u) {
    int tt = wv * 16 + u;
    int t = t0 + 1 + tt;
    int i = lane;
    int s = t - 64 + i;
    float wval = WL[(tt + i) * 64 + (63 - i)];
    int sc = (s < 0) ? 0 : s;
    float total = (s >= 0) ? (cgb[sc] + wval) : DPINF;
    float m = total;
    DPP_MIN_REDUCE(m);
    float mf = __int_as_float(__builtin_amdgcn_readlane(__float_as_int(m), 63));
    unsigned long long msk = __ballot(total == mf);
    int iwin = __builtin_ctzll(msk);            // smallest i = smallest s
    int prev = t - 64 + iwin;
    if (lane == 0) pk[(size_t)b * (TT + 1) + t] = prev;
  }
}

// ---------------------------------------------------------------------------
// Kernel 4c: backtrack via binary lifting (tokens filled by tok_k).
// ---------------------------------------------------------------------------
__global__ __launch_bounds__(64) void bt_k(const int* __restrict__ pk,
                                           const float* __restrict__ cg,
                                           const int* __restrict__ lengths,
                                           float* __restrict__ out) {
  __shared__ ushort J[10][TT + 1];
  int b = blockIdx.x;
  int lane = threadIdx.x;
  const int* pb = pk + (size_t)b * (TT + 1);

  for (int t = lane; t <= TT; t += 64)
    J[0][t] = (ushort)((t == 0) ? 0 : pb[t]);
  __syncthreads();
#pragma unroll
  for (int k = 0; k < 9; ++k) {
    for (int t = lane; t <= TT; t += 64)
      J[k + 1][t] = J[k][J[k][t]];
    __syncthreads();
  }

  int len = lengths[b];
  len = (len > TT) ? TT : (len < 0 ? 0 : len);

  int cnt = 0;
  if (len > 0) {
    int cur = len, m = 0;
#pragma unroll
    for (int k = 9; k >= 0; --k) {
      int nxt = J[k][cur];
      if (nxt != 0) { cur = nxt; m += (1 << k); }
    }
    cnt = m + 1;
  }

  float* bout = out + b * TT;
  float* tout = out + MM + b * TT;
#pragma unroll 4
  for (int j0 = 0; j0 < TT; j0 += 64) {
    int j = j0 + lane;
    int node = 0;
    if (j < cnt) {
      int steps = cnt - 1 - j;
      int cur = len;
#pragma unroll
      for (int k = 9; k >= 0; --k)
        if ((steps >> k) & 1) cur = J[k][cur];
      node = cur;
    }
    bout[j] = (float)node;
    tout[j] = 0.f;
  }
  if (lane == 0) {
    out[2 * MM + b] = (float)cnt;
    out[2 * MM + BB + b] = cg[(size_t)b * (TT + 1) + len];
  }
}

// ---------------------------------------------------------------------------
// Kernel 4d: token recovery per winning segment (unchanged).
// ---------------------------------------------------------------------------
__global__ __launch_bounds__(256) void tok_k(const float* __restrict__ dmat,
                                             float* __restrict__ out) {
  int bx = blockIdx.x;
  int b = bx >> 8;
  int wv = threadIdx.x >> 6, lane = threadIdx.x & 63;
  int j = ((bx & 255) << 2) + wv;
  int cnt = (int)out[2 * MM + b];
  if (j >= cnt) return;
  const float* bout = out + b * TT;
  int t = (int)bout[j];
  int s = (j == 0) ? 0 : (int)bout[j - 1];

  const float4* base = (const float4*)(dmat + (size_t)b * TT * VV);
  float4 acc = make_float4(0.f, 0.f, 0.f, 0.f);
  for (int f = s; f < t; ++f) {
    float4 dv = base[(size_t)f * 64 + lane];
    acc.x += dv.x; acc.y += dv.y; acc.z += dv.z; acc.w += dv.w;
  }
  float bv = acc.x; int be = 0;
  if (acc.y < bv) { bv = acc.y; be = 1; }
  if (acc.z < bv) { bv = acc.z; be = 2; }
  if (acc.w < bv) { bv = acc.w; be = 3; }
  float m = bv;
  DPP_MIN_REDUCE(m);
  float mf = __int_as_float(__builtin_amdgcn_readlane(__float_as_int(m), 63));
  unsigned long long msk = __ballot(bv == mf);
  int iwin = __builtin_ctzll(msk);              // lowest lane = lowest v
  int vloc = (lane << 2) + be;
  int v = __builtin_amdgcn_readlane(vloc, iwin);
  if (lane == 0) out[MM + b * TT + j] = (float)v;
}

// ---------------------------------------------------------------------------
extern "C" void kernel_launch(void* const* d_in, const int* in_sizes, int n_in,
                              void* d_out, int out_size, void* d_ws, size_t ws_size,
                              hipStream_t stream) {
  const float* reps = (const float*)d_in[0];
  const float* cb   = (const float*)d_in[1];
  const int* lengths = (const int*)d_in[2];
  float* out = (float*)d_out;

  char* ws = (char*)d_ws;
  float* r2 = (float*)ws;                                    // 64 KB
  float* c2 = (float*)(ws + 65536);                          // 4 KB slot
  char* p = ws + 69632;
  float* dmat = (float*)p;               p += (size_t)MM * VV * 4;       // 16 MB
  ushort* repsb = (ushort*)p;            p += (size_t)MM * DD * 2;       // 16.78 MB
  float* cg   = (float*)p;               p += (size_t)BB * (TT + 1) * 4; // 65.6 KB
  int* pk     = (int*)p;                 p += (size_t)BB * (TT + 1) * 4; // 65.6 KB
  ushort* cbb = (ushort*)p;                                              // 256 KB
  // Wf (4MB) aliases repsb: repsb dead after gemm_k; fill ordered after it
  int* Wf = (int*)repsb;

  norms_k<<<(MM + VV) / 4, 256, 0, stream>>>(reps, cb, r2, c2, repsb, cbb);
  gemm_k<<<dim3(MM / 64, VV / 64), 256, 0, stream>>>(repsb, cbb, r2, c2, dmat);
  fill_k<<<(MM * 64 / 4) / 256, 256, 0, stream>>>((int4*)Wf);   // 4MB +inf fill
  w_k<<<BB * 16 * 4, 256, 0, stream>>>(dmat, Wf);
  dp_seq<<<BB, 64, 0, stream>>>((const float*)Wf, cg);
  prev_k<<<BB * 16, 256, 0, stream>>>((const float*)Wf, cg, pk);
  bt_k<<<BB, 64, 0, stream>>>(pk, cg, lengths, out);
  tok_k<<<BB * 256, 256, 0, stream>>>(dmat, out);
}

// Round 14
// 106.642 us; speedup vs baseline: 4.4363x; 1.1704x over previous
//
#include <hip/hip_runtime.h>

#define BB 16
#define TT 1024
#define DD 512
#define VV 256
#define MM (BB*TT)

#define DPINF 1e30f
#define NORM_BLOCKS ((MM + VV) / 4)
#define FILL_BLOCKS 1024           // 4MB / (256 thr * 16B)

typedef __attribute__((ext_vector_type(8))) short bf16x8;
typedef __attribute__((ext_vector_type(4))) float f32x4;

__device__ __forceinline__ ushort f2bf(float x) {
  unsigned u = __float_as_uint(x);
  return (ushort)((u + 0x7FFFu + ((u >> 16) & 1u)) >> 16);   // RNE
}
__device__ __forceinline__ float bf2f(ushort u) {
  return __uint_as_float((unsigned)u << 16);
}

// DPP min-reduce step; old = same reg -> identity for lanes with no source
#define DPP_MIN_STEP(m, CTRL) { \
  int _t = __builtin_amdgcn_update_dpp(__float_as_int(m), __float_as_int(m), CTRL, 0xF, 0xF, false); \
  m = fminf(m, __int_as_float(_t)); }

// full 64-lane min into lane 63
#define DPP_MIN_REDUCE(m) \
  DPP_MIN_STEP(m, 0x111); DPP_MIN_STEP(m, 0x112); DPP_MIN_STEP(m, 0x114); \
  DPP_MIN_STEP(m, 0x118); DPP_MIN_STEP(m, 0x142); DPP_MIN_STEP(m, 0x143);

// ---------------------------------------------------------------------------
// Kernel 1: row norms + RNE fp32->bf16 conversion; tail blocks fill Wf with
// 0x7F7F7F7F (+3.39e38) -- fill fused here to drop one dispatch.
// ---------------------------------------------------------------------------
__global__ __launch_bounds__(256) void norms_k(const float* __restrict__ reps,
                                               const float* __restrict__ cb,
                                               float* __restrict__ r2,
                                               float* __restrict__ c2,
                                               ushort* __restrict__ repsb,
                                               ushort* __restrict__ cbb,
                                               int4* __restrict__ Wf) {
  if (blockIdx.x >= NORM_BLOCKS) {
    size_t i = (size_t)(blockIdx.x - NORM_BLOCKS) * 256 + threadIdx.x;
    Wf[i] = make_int4(0x7F7F7F7F, 0x7F7F7F7F, 0x7F7F7F7F, 0x7F7F7F7F);
    return;
  }
  int row = blockIdx.x * 4 + (threadIdx.x >> 6);
  int lane = threadIdx.x & 63;
  const float* src;
  float* dst;
  ushort* bdst;
  if (row < MM) {
    src = reps + (size_t)row * DD;
    dst = r2 + row;
    bdst = repsb + (size_t)row * DD;
  } else {
    int r = row - MM;
    if (r >= VV) return;
    src = cb + (size_t)r * DD;
    dst = c2 + r;
    bdst = cbb + (size_t)r * DD;
  }
  const float4* s4 = (const float4*)src;
  float4 a = s4[lane];
  float4 b = s4[lane + 64];

  ushort4 ua = make_ushort4(f2bf(a.x), f2bf(a.y), f2bf(a.z), f2bf(a.w));
  ushort4 ub = make_ushort4(f2bf(b.x), f2bf(b.y), f2bf(b.z), f2bf(b.w));
  *(ushort4*)&bdst[lane * 4] = ua;
  *(ushort4*)&bdst[256 + lane * 4] = ub;

  float s = a.x*a.x + a.y*a.y + a.z*a.z + a.w*a.w
          + b.x*b.x + b.y*b.y + b.z*b.z + b.w*b.w;
#pragma unroll
  for (int off = 1; off < 64; off <<= 1) s += __shfl_xor(s, off);
  if (lane == 0) *dst = s;
}

// ---------------------------------------------------------------------------
// Kernel 2: d[m][v] via bf16 MFMA; OUTPUT NOW bf16 (RNE) -- halves dmat
// traffic for w_k/tok_k. All consumers see identical rounded values.
// ---------------------------------------------------------------------------
__global__ __launch_bounds__(256) void gemm_k(const ushort* __restrict__ repsb,
                                              const ushort* __restrict__ cbb,
                                              const float* __restrict__ r2,
                                              const float* __restrict__ c2,
                                              ushort* __restrict__ dmatb) {
  __shared__ short Ab[2][4096];
  __shared__ short Bb[2][4096];
  int tid = threadIdx.x;
  int w = tid >> 6, l = tid & 63;
  int m0 = blockIdx.x * 64, v0 = blockIdx.y * 64;

  int srow = l >> 3;
  int scol = ((l & 7) << 4) ^ (srow << 4);

  auto stage = [&](int buf, int kc) {
#pragma unroll
    for (int ii = 0; ii < 2; ++ii) {
      int instr = w + ii * 4;
      int row = instr * 8 + srow;
      const char* ga = (const char*)repsb + ((size_t)(m0 + row) * DD + kc * 64) * 2 + scol;
      __builtin_amdgcn_global_load_lds((const unsigned int*)ga,
                                       (unsigned int*)&Ab[buf][instr * 512], 16, 0, 0);
      const char* gb = (const char*)cbb + ((size_t)(v0 + row) * DD + kc * 64) * 2 + scol;
      __builtin_amdgcn_global_load_lds((const unsigned int*)gb,
                                       (unsigned int*)&Bb[buf][instr * 512], 16, 0, 0);
    }
  };

  int fr = l & 15;
  int fq = l >> 4;
  int swz = (fr & 7) << 3;

  f32x4 acc0 = {0.f,0.f,0.f,0.f}, acc1 = {0.f,0.f,0.f,0.f};
  f32x4 acc2 = {0.f,0.f,0.f,0.f}, acc3 = {0.f,0.f,0.f,0.f};

  stage(0, 0);
  int cur = 0;
  for (int kc = 0; kc < 8; ++kc) {
    if (kc < 7) {
      stage(cur ^ 1, kc + 1);
      asm volatile("s_waitcnt vmcnt(4)" ::: "memory");
    } else {
      asm volatile("s_waitcnt vmcnt(0)" ::: "memory");
    }
    __syncthreads();
#pragma unroll
    for (int ks = 0; ks < 2; ++ks) {
      int koff = (ks * 32 + fq * 8) ^ swz;
      bf16x8 av = *(const bf16x8*)&Ab[cur][(w * 16 + fr) * 64 + koff];
      bf16x8 b0 = *(const bf16x8*)&Bb[cur][(0 * 16 + fr) * 64 + koff];
      bf16x8 b1 = *(const bf16x8*)&Bb[cur][(1 * 16 + fr) * 64 + koff];
      bf16x8 b2 = *(const bf16x8*)&Bb[cur][(2 * 16 + fr) * 64 + koff];
      bf16x8 b3 = *(const bf16x8*)&Bb[cur][(3 * 16 + fr) * 64 + koff];
      acc0 = __builtin_amdgcn_mfma_f32_16x16x32_bf16(av, b0, acc0, 0, 0, 0);
      acc1 = __builtin_amdgcn_mfma_f32_16x16x32_bf16(av, b1, acc1, 0, 0, 0);
      acc2 = __builtin_amdgcn_mfma_f32_16x16x32_bf16(av, b2, acc2, 0, 0, 0);
      acc3 = __builtin_amdgcn_mfma_f32_16x16x32_bf16(av, b3, acc3, 0, 0, 0);
    }
    __syncthreads();
    cur ^= 1;
  }

  float rv[4];
#pragma unroll
  for (int r = 0; r < 4; ++r) rv[r] = r2[m0 + w * 16 + fq * 4 + r];
#pragma unroll
  for (int vt = 0; vt < 4; ++vt) {
    f32x4 a = (vt == 0) ? acc0 : (vt == 1) ? acc1 : (vt == 2) ? acc2 : acc3;
    int v = v0 + vt * 16 + fr;
    float cc = c2[v];
#pragma unroll
    for (int r = 0; r < 4; ++r) {
      int m = m0 + w * 16 + fq * 4 + r;
      dmatb[(size_t)m * VV + v] = f2bf(fmaf(-2.f, a[r], rv[r] + cc));
    }
  }
}

// ---------------------------------------------------------------------------
// Kernel 3: W values, v-quarter blocks; bf16 dmat input; atomicMin fold.
// ---------------------------------------------------------------------------
__global__ __launch_bounds__(256, 4) void w_k(const ushort* __restrict__ dmatb,
                                              int* __restrict__ Wf) {
  __shared__ __align__(16) float CL[128 * 64];   // 32KB
  __shared__ __align__(16) float TOT[16 * 64];   // 4KB
  int bx = blockIdx.x;
  int b = bx >> 6;
  int chunk = (bx >> 2) & 15;
  int q = bx & 3;
  int t1 = 1 + (chunk << 6);
  int tid = threadIdx.x;
  int wv = tid >> 6, lane = tid & 63;

  // ---- Phase 1: parallel window cumsum (bf16 loads) ----
  {
    int c = tid >> 4;          // 0..15 (8 frames each)
    int g = tid & 15;          // f4-group within quarter
    const ushort* base = dmatb + (size_t)b * TT * VV + q * 64 + (g << 2);
    float4 rr[8];
    float4 run = make_float4(0.f, 0.f, 0.f, 0.f);
#pragma unroll
    for (int jj = 1; jj <= 8; ++jj) {
      int k = (c << 3) + jj;
      int f = t1 - 64 + k;
      bool valid = (k <= 127) && (f >= 1) && (f <= TT);
      int fc = valid ? f : 1;
      ushort4 d4 = *(const ushort4*)(base + (size_t)(fc - 1) * VV);
      float4 dv = make_float4(bf2f(d4.x), bf2f(d4.y), bf2f(d4.z), bf2f(d4.w));
      if (!valid) dv = make_float4(0.f, 0.f, 0.f, 0.f);
      run.x += dv.x; run.y += dv.y; run.z += dv.z; run.w += dv.w;
      rr[jj - 1] = run;
    }
    *(float4*)&TOT[(c << 6) + (g << 2)] = run;
    if (c == 0) *(float4*)&CL[(g << 2)] = make_float4(0.f, 0.f, 0.f, 0.f);
    __syncthreads();
    float4 off = make_float4(0.f, 0.f, 0.f, 0.f);
#pragma unroll
    for (int cc = 0; cc < 15; ++cc) {
      if (cc < c) {
        float4 tv = *(const float4*)&TOT[(cc << 6) + (g << 2)];
        off.x += tv.x; off.y += tv.y; off.z += tv.z; off.w += tv.w;
      }
    }
#pragma unroll
    for (int jj = 1; jj <= 8; ++jj) {
      int k = (c << 3) + jj;
      if (k <= 127) {
        float4 s = rr[jj - 1];
        s.x += off.x; s.y += off.y; s.z += off.z; s.w += off.w;
        *(float4*)&CL[(k << 6) + ((g ^ (k & 15)) << 2)] = s;
      }
    }
  }
  __syncthreads();

  // ---- Phase 2: value-only diagonal scan ----
  float bw[16];
#pragma unroll
  for (int j = 0; j < 16; ++j) {
    int dt = (j << 2) + wv;
    int ks = dt + lane;               // C_s row (per-lane)
    int kt = dt + 64;                 // C_t row (wave-uniform)
    int rti = __float_as_int(CL[(kt << 6) + (((lane >> 2) ^ (kt & 15)) << 2) + (lane & 3)]);
    int ksm = ks & 15;
    const float* rs = &CL[ks << 6];
    float bv = 1e38f;
#pragma unroll
    for (int g = 0; g < 16; ++g) {
      float4 a = *(const float4*)&rs[(g ^ ksm) << 2];
      int v0 = g << 2;
      float t0 = __int_as_float(__builtin_amdgcn_readlane(rti, v0));
      float t1v = __int_as_float(__builtin_amdgcn_readlane(rti, v0 + 1));
      float t2 = __int_as_float(__builtin_amdgcn_readlane(rti, v0 + 2));
      float t3 = __int_as_float(__builtin_amdgcn_readlane(rti, v0 + 3));
      float m01 = fminf(t0 - a.x, t1v - a.y);
      float m23 = fminf(t2 - a.z, t3 - a.w);
      bv = fminf(bv, fminf(m01, m23));
    }
    bw[j] = bv;
  }

  // ---- Phase 3: restage + atomicMin fold into Wf[s][j] ----
  __syncthreads();
  float* ST = CL;
#pragma unroll
  for (int j = 0; j < 16; ++j) {
    int dt = (j << 2) + wv;
    int srow = dt + lane;             // 0..126
    ST[(63 - lane) * 127 + srow] = bw[j];
  }
  __syncthreads();
  {
    int* Wfb = Wf + (size_t)b * TT * 64;
    for (int qq = 0; qq < 32; ++qq) {
      int rr = wv * 32 + qq;
      if (rr > 126) break;
      int s = t1 - 64 + rr;
      if (s < 0) continue;
      int jlo = 63 - rr; if (jlo < 0) jlo = 0;
      int jhi = 126 - rr; if (jhi > 63) jhi = 63;
      int j = lane;
      if (j >= jlo && j <= jhi)
        atomicMin(&Wfb[(size_t)s * 64 + j], __float_as_int(ST[j * 127 + rr]));
    }
  }
}

// ---------------------------------------------------------------------------
// Kernel 4a: sequential DP, scatter form, pre-folded Wf (unchanged).
// ---------------------------------------------------------------------------
__global__ __launch_bounds__(64) void dp_seq(const float* __restrict__ Wf,
                                             float* __restrict__ cg) {
  __shared__ __align__(16) float ring[256 * 64];   // 64 KB
  int b = blockIdx.x;
  int lane = threadIdx.x;
  const char* Wb = (const char*)(Wf + (size_t)b * TT * 64);
  float* cgb = cg + (size_t)b * (TT + 1);
  if (lane == 0) cgb[0] = 0.f;

  auto stage4 = [&](int d) {        // DMA d stages rows 4d..4d+3 (1KB linear)
    const char* g = Wb + ((size_t)d << 10) + (lane << 4);
    __builtin_amdgcn_global_load_lds((const unsigned int*)g,
                                     (unsigned int*)&ring[((d << 2) & 255) << 6], 16, 0, 0);
  };
  auto ldring = [&](int r) -> float {
    int rc = (r > TT - 1) ? (TT - 1) : r;
    return ring[((rc & 255) << 6) | ((lane - rc) & 63)];
  };

  for (int d = 0; d < 60; ++d) stage4(d);            // rows 0..239
  asm volatile("s_waitcnt vmcnt(56)" ::: "memory");  // DMAs 0..3 -> rows 0..15
  float p0 = ldring(0), p1 = ldring(1), p2 = ldring(2), p3 = ldring(3);
  float p4 = ldring(4), p5 = ldring(5), p6 = ldring(6), p7 = ldring(7);

  float c = 0.f;
  float acc = DPINF;
  float ckeep = 0.f;

#define STEP(TAU, P) { \
    float cand = c + (P); \
    acc = fminf(acc, cand); \
    int fl = (TAU) & 63; \
    float cnew = __int_as_float(__builtin_amdgcn_readlane(__float_as_int(acc), fl)); \
    bool me = (lane == fl); \
    ckeep = me ? cnew : ckeep; \
    acc = me ? DPINF : acc; \
    c = cnew; }

  for (int gg = 0; gg < 16; ++gg) {
#pragma unroll
    for (int ii = 0; ii < 8; ++ii) {
      int tb = gg * 64 + ii * 8;
      if (tb <= 776) {
        asm volatile("s_waitcnt vmcnt(56)" ::: "memory");
        stage4(60 + (tb >> 2)); stage4(61 + (tb >> 2));   // rows 240+tb..247+tb
      } else if (tb == 784) {
        asm volatile("s_waitcnt vmcnt(0)" ::: "memory");  // all 256 DMAs done
      }
      STEP(tb + 0, p0); p0 = ldring(tb + 8);
      STEP(tb + 1, p1); p1 = ldring(tb + 9);
      STEP(tb + 2, p2); p2 = ldring(tb + 10);
      STEP(tb + 3, p3); p3 = ldring(tb + 11);
      STEP(tb + 4, p4); p4 = ldring(tb + 12);
      STEP(tb + 5, p5); p5 = ldring(tb + 13);
      STEP(tb + 6, p6); p6 = ldring(tb + 14);
      STEP(tb + 7, p7); p7 = ldring(tb + 15);
    }
    cgb[gg * 64 + 1 + lane] = ckeep;
  }
#undef STEP
}

// ---------------------------------------------------------------------------
// Kernel 4b: parallel arg-prev from folded Wf (unchanged).
// ---------------------------------------------------------------------------
__global__ __launch_bounds__(256) void prev_k(const float* __restrict__ Wf,
                                              const float* __restrict__ cg,
                                              int* __restrict__ pk) {
  __shared__ float WL[127 * 64];   // 32KB
  int bx = blockIdx.x;
  int b = bx >> 4;
  int chunk = bx & 15;
  int t0 = chunk << 6;
  int tid = threadIdx.x;
  int wv = tid >> 6, lane = tid & 63;

  const float* Wfb = Wf + (size_t)b * TT * 64;
  for (int ci = tid; ci < 127 * 16; ci += 256) {
    int row = ci >> 4, c4 = ci & 15;
    long s = (long)(t0 - 63 + row);            // may be <0 (garbage, masked later)
    float4 v = *(const float4*)(Wfb + s * 64 + (c4 << 2));
    *(float4*)&WL[(row << 6) + (c4 << 2)] = v;
  }
  __syncthreads();

  const float* cgb = cg + (size_t)b * (TT + 1);
#pragma unroll
  for (int u = 0; u < 16; ++u) {
    int tt = wv * 16 + u;
    int t = t0 + 1 + tt;
    int i = lane;
    int s = t - 64 + i;
    float wval = WL[(tt + i) * 64 + (63 - i)];
    int sc = (s < 0) ? 0 : s;
    float total = (s >= 0) ? (cgb[sc] + wval) : DPINF;
    float m = total;
    DPP_MIN_REDUCE(m);
    float mf = __int_as_float(__builtin_amdgcn_readlane(__float_as_int(m), 63));
    unsigned long long msk = __ballot(total == mf);
    int iwin = __builtin_ctzll(msk);            // smallest i = smallest s
    int prev = t - 64 + iwin;
    if (lane == 0) pk[(size_t)b * (TT + 1) + t] = prev;
  }
}

// ---------------------------------------------------------------------------
// Kernel 4c: backtrack via binary lifting; 256 threads (4x faster J-build).
// ---------------------------------------------------------------------------
__global__ __launch_bounds__(256) void bt_k(const int* __restrict__ pk,
                                            const float* __restrict__ cg,
                                            const int* __restrict__ lengths,
                                            float* __restrict__ out) {
  __shared__ ushort J[10][TT + 1];
  int b = blockIdx.x;
  int tid = threadIdx.x;
  const int* pb = pk + (size_t)b * (TT + 1);

  for (int t = tid; t <= TT; t += 256)
    J[0][t] = (ushort)((t == 0) ? 0 : pb[t]);
  __syncthreads();
#pragma unroll
  for (int k = 0; k < 9; ++k) {
    for (int t = tid; t <= TT; t += 256)
      J[k + 1][t] = J[k][J[k][t]];
    __syncthreads();
  }

  int len = lengths[b];
  len = (len > TT) ? TT : (len < 0 ? 0 : len);

  int cnt = 0;
  if (len > 0) {
    int cur = len, m = 0;
#pragma unroll
    for (int k = 9; k >= 0; --k) {
      int nxt = J[k][cur];
      if (nxt != 0) { cur = nxt; m += (1 << k); }
    }
    cnt = m + 1;
  }

  float* bout = out + b * TT;
  float* tout = out + MM + b * TT;
#pragma unroll
  for (int j0 = 0; j0 < TT; j0 += 256) {
    int j = j0 + tid;
    int node = 0;
    if (j < cnt) {
      int steps = cnt - 1 - j;
      int cur = len;
#pragma unroll
      for (int k = 9; k >= 0; --k)
        if ((steps >> k) & 1) cur = J[k][cur];
      node = cur;
    }
    bout[j] = (float)node;
    tout[j] = 0.f;
  }
  if (tid == 0) {
    out[2 * MM + b] = (float)cnt;
    out[2 * MM + BB + b] = cg[(size_t)b * (TT + 1) + len];
  }
}

// ---------------------------------------------------------------------------
// Kernel 4d: token recovery per winning segment (bf16 dmat input).
// ---------------------------------------------------------------------------
__global__ __launch_bounds__(256) void tok_k(const ushort* __restrict__ dmatb,
                                             float* __restrict__ out) {
  int bx = blockIdx.x;
  int b = bx >> 8;
  int wv = threadIdx.x >> 6, lane = threadIdx.x & 63;
  int j = ((bx & 255) << 2) + wv;
  int cnt = (int)out[2 * MM + b];
  if (j >= cnt) return;
  const float* bout = out + b * TT;
  int t = (int)bout[j];
  int s = (j == 0) ? 0 : (int)bout[j - 1];

  const ushort* base = dmatb + (size_t)b * TT * VV + lane * 4;
  float4 acc = make_float4(0.f, 0.f, 0.f, 0.f);
  for (int f = s; f < t; ++f) {
    ushort4 d4 = *(const ushort4*)(base + (size_t)f * VV);
    acc.x += bf2f(d4.x); acc.y += bf2f(d4.y);
    acc.z += bf2f(d4.z); acc.w += bf2f(d4.w);
  }
  float bv = acc.x; int be = 0;
  if (acc.y < bv) { bv = acc.y; be = 1; }
  if (acc.z < bv) { bv = acc.z; be = 2; }
  if (acc.w < bv) { bv = acc.w; be = 3; }
  float m = bv;
  DPP_MIN_REDUCE(m);
  float mf = __int_as_float(__builtin_amdgcn_readlane(__float_as_int(m), 63));
  unsigned long long msk = __ballot(bv == mf);
  int iwin = __builtin_ctzll(msk);              // lowest lane = lowest v
  int vloc = (lane << 2) + be;
  int v = __builtin_amdgcn_readlane(vloc, iwin);
  if (lane == 0) out[MM + b * TT + j] = (float)v;
}

// ---------------------------------------------------------------------------
extern "C" void kernel_launch(void* const* d_in, const int* in_sizes, int n_in,
                              void* d_out, int out_size, void* d_ws, size_t ws_size,
                              hipStream_t stream) {
  const float* reps = (const float*)d_in[0];
  const float* cb   = (const float*)d_in[1];
  const int* lengths = (const int*)d_in[2];
  float* out = (float*)d_out;

  char* ws = (char*)d_ws;
  float* r2 = (float*)ws;                                    // 64 KB
  float* c2 = (float*)(ws + 65536);                          // 4 KB slot
  char* p = ws + 69632;
  ushort* dmatb = (ushort*)p;            p += (size_t)MM * VV * 2;       // 8.4 MB
  ushort* repsb = (ushort*)p;            p += (size_t)MM * DD * 2;       // 16.78 MB
  int* Wf     = (int*)p;                 p += (size_t)MM * 64 * 4;       // 4 MB
  float* cg   = (float*)p;               p += (size_t)BB * (TT + 1) * 4; // 65.6 KB
  int* pk     = (int*)p;                 p += (size_t)BB * (TT + 1) * 4; // 65.6 KB
  ushort* cbb = (ushort*)p;                                              // 256 KB

  norms_k<<<NORM_BLOCKS + FILL_BLOCKS, 256, 0, stream>>>(reps, cb, r2, c2,
                                                         repsb, cbb, (int4*)Wf);
  gemm_k<<<dim3(MM / 64, VV / 64), 256, 0, stream>>>(repsb, cbb, r2, c2, dmatb);
  w_k<<<BB * 16 * 4, 256, 0, stream>>>(dmatb, Wf);
  dp_seq<<<BB, 64, 0, stream>>>((const float*)Wf, cg);
  prev_k<<<BB * 16, 256, 0, stream>>>((const float*)Wf, cg, pk);
  bt_k<<<BB, 256, 0, stream>>>(pk, cg, lengths, out);
  tok_k<<<BB * 256, 256, 0, stream>>>(dmatb, out);
}